// Round 2
// baseline (675.445 us; speedup 1.0000x reference)
//
#include <hip/hip_runtime.h>
#include <hip/hip_bf16.h>

typedef __bf16 bf16x8 __attribute__((ext_vector_type(8)));
typedef float f32x4 __attribute__((ext_vector_type(4)));
typedef unsigned short u16x8 __attribute__((ext_vector_type(8)));
typedef unsigned short u16x4 __attribute__((ext_vector_type(4)));

#define DEV static __device__ __forceinline__

DEV unsigned short f2bf(float f) {
    unsigned u = __builtin_bit_cast(unsigned, f);
    u += 0x7fffu + ((u >> 16) & 1u);   // round-to-nearest-even
    return (unsigned short)(u >> 16);
}
DEV float bf2f(unsigned short h) {
    unsigned u = ((unsigned)h) << 16;
    return __builtin_bit_cast(float, u);
}

// ---------------------------------------------------------------------------
// Generic GEMM: C[M,N] = A[M,K](bf16,row-major) @ BT[N,K](bf16)^T
// EPI 0: store bf16 C.  EPI 1: store fp32 (res + C).
// BM=BN=128, BK=32, 256 threads = 4 waves, each wave 64x64 (4x4 MFMA frags).
// ---------------------------------------------------------------------------
template <int EPI>
__global__ __launch_bounds__(256)
void gemm_bt(const unsigned short* __restrict__ A,
             const unsigned short* __restrict__ BT,
             unsigned short* __restrict__ outB,
             float* __restrict__ outF,
             const float* __restrict__ res,
             int M, int N, int K)
{
    __shared__ alignas(16) unsigned short As[128][40];   // +8 pad: 80B stride
    __shared__ alignas(16) unsigned short Bs[128][40];

    const int tid  = threadIdx.x;
    const int lane = tid & 63;
    const int wave = tid >> 6;
    const int bm = blockIdx.y * 128;
    const int bn = blockIdx.x * 128;
    const int wm = (wave >> 1) * 64;
    const int wn = (wave & 1) * 64;
    const int lr = lane & 15;
    const int lg = lane >> 4;
    const int srow = tid >> 2;          // 0..63
    const int scol = (tid & 3) * 8;     // 0,8,16,24

    const unsigned short* Aptr0 = A  + (size_t)(bm + srow)      * K + scol;
    const unsigned short* Aptr1 = A  + (size_t)(bm + srow + 64) * K + scol;
    const unsigned short* Bptr0 = BT + (size_t)(bn + srow)      * K + scol;
    const unsigned short* Bptr1 = BT + (size_t)(bn + srow + 64) * K + scol;

    f32x4 acc[4][4] = {};
    u16x8 ra0, ra1, rb0, rb1;

    auto gload = [&](int kt) {
        const size_t o = (size_t)kt * 32;
        ra0 = *reinterpret_cast<const u16x8*>(Aptr0 + o);
        ra1 = *reinterpret_cast<const u16x8*>(Aptr1 + o);
        rb0 = *reinterpret_cast<const u16x8*>(Bptr0 + o);
        rb1 = *reinterpret_cast<const u16x8*>(Bptr1 + o);
    };
    auto lwrite = [&]() {
        *reinterpret_cast<u16x8*>(&As[srow][scol])      = ra0;
        *reinterpret_cast<u16x8*>(&As[srow + 64][scol]) = ra1;
        *reinterpret_cast<u16x8*>(&Bs[srow][scol])      = rb0;
        *reinterpret_cast<u16x8*>(&Bs[srow + 64][scol]) = rb1;
    };

    const int NT = K >> 5;
    gload(0);
    lwrite();
    __syncthreads();

    for (int kt = 0; kt < NT; ++kt) {
        if (kt + 1 < NT) gload(kt + 1);
        bf16x8 af[4], bfr[4];
#pragma unroll
        for (int i = 0; i < 4; ++i) {
            af[i]  = *reinterpret_cast<const bf16x8*>(&As[wm + i * 16 + lr][lg * 8]);
            bfr[i] = *reinterpret_cast<const bf16x8*>(&Bs[wn + i * 16 + lr][lg * 8]);
        }
#pragma unroll
        for (int i = 0; i < 4; ++i)
#pragma unroll
            for (int j = 0; j < 4; ++j)
                acc[i][j] = __builtin_amdgcn_mfma_f32_16x16x32_bf16(af[i], bfr[j], acc[i][j], 0, 0, 0);
        __syncthreads();
        if (kt + 1 < NT) lwrite();
        __syncthreads();
    }

#pragma unroll
    for (int i = 0; i < 4; ++i) {
#pragma unroll
        for (int j = 0; j < 4; ++j) {
            const int col = bn + wn + j * 16 + lr;
#pragma unroll
            for (int r = 0; r < 4; ++r) {
                const int row = bm + wm + i * 16 + lg * 4 + r;
                const float v = acc[i][j][r];
                if constexpr (EPI == 0) {
                    outB[(size_t)row * N + col] = f2bf(v);
                } else {
                    outF[(size_t)row * N + col] = res[(size_t)row * N + col] + v;
                }
            }
        }
    }
}

// ---------------------------------------------------------------------------
// RMSNorm: fp32 in [2048][2048] -> bf16 out, weight fp32. One block per row.
// ---------------------------------------------------------------------------
__global__ __launch_bounds__(256)
void rmsnorm_kernel(const float* __restrict__ x, const float* __restrict__ w,
                    unsigned short* __restrict__ out)
{
    const int row = blockIdx.x;
    const int tid = threadIdx.x;
    const float* xr = x + (size_t)row * 2048;
    const float4 a = *reinterpret_cast<const float4*>(xr + tid * 8);
    const float4 b = *reinterpret_cast<const float4*>(xr + tid * 8 + 4);
    float ss = a.x * a.x + a.y * a.y + a.z * a.z + a.w * a.w
             + b.x * b.x + b.y * b.y + b.z * b.z + b.w * b.w;
#pragma unroll
    for (int off = 32; off; off >>= 1) ss += __shfl_xor(ss, off);
    __shared__ float red[4];
    if ((tid & 63) == 0) red[tid >> 6] = ss;
    __syncthreads();
    const float tot = red[0] + red[1] + red[2] + red[3];
    const float sc = rsqrtf(tot * (1.0f / 2048.0f) + 1e-5f);
    const float4 wa = *reinterpret_cast<const float4*>(w + tid * 8);
    const float4 wb = *reinterpret_cast<const float4*>(w + tid * 8 + 4);
    u16x8 o;
    o[0] = f2bf(a.x * sc * wa.x); o[1] = f2bf(a.y * sc * wa.y);
    o[2] = f2bf(a.z * sc * wa.z); o[3] = f2bf(a.w * sc * wa.w);
    o[4] = f2bf(b.x * sc * wb.x); o[5] = f2bf(b.y * sc * wb.y);
    o[6] = f2bf(b.z * sc * wb.z); o[7] = f2bf(b.w * sc * wb.w);
    *reinterpret_cast<u16x8*>(out + (size_t)row * 2048 + tid * 8) = o;
}

// ---------------------------------------------------------------------------
// RoPE in-place on bf16 qkv[2048][6144], first 4096 cols (q and k regions).
// cos/sin fp32 [2048][64]
// ---------------------------------------------------------------------------
__global__ __launch_bounds__(256)
void rope_kernel(unsigned short* __restrict__ t, const float* __restrict__ cs,
                 const float* __restrict__ sn)
{
    const int idx = blockIdx.x * 256 + threadIdx.x;   // S * 4096 / 8
    const int s   = idx >> 9;
    const int col = (idx & 511) * 8;
    const int i0  = (col & 127) >> 1;
    u16x8 v = *reinterpret_cast<const u16x8*>(t + (size_t)s * 6144 + col);
    const float4 c  = *reinterpret_cast<const float4*>(cs + s * 64 + i0);
    const float4 sv = *reinterpret_cast<const float4*>(sn + s * 64 + i0);
    const float cc[4] = {c.x, c.y, c.z, c.w};
    const float ns[4] = {sv.x, sv.y, sv.z, sv.w};
#pragma unroll
    for (int p = 0; p < 4; ++p) {
        const float re = bf2f(v[2 * p]), im = bf2f(v[2 * p + 1]);
        v[2 * p]     = f2bf(re * cc[p] - im * ns[p]);
        v[2 * p + 1] = f2bf(re * ns[p] + im * cc[p]);
    }
    *reinterpret_cast<u16x8*>(t + (size_t)s * 6144 + col) = v;
}

// ---------------------------------------------------------------------------
// bf16 transpose: out[N][M] = in[M][N]^T (in has row stride ldin), 64x64 tiles
// ---------------------------------------------------------------------------
__global__ __launch_bounds__(256)
void transpose_bf16(const unsigned short* __restrict__ in,
                    unsigned short* __restrict__ out, int M, int N, int ldin)
{
    __shared__ unsigned short t[64][66];
    const int bm = blockIdx.y * 64, bn = blockIdx.x * 64;
    const int tid = threadIdx.x;
    const int r = tid >> 3, c8 = (tid & 7) * 8;
#pragma unroll
    for (int i = 0; i < 2; ++i) {
        const int row = r + i * 32;
        u16x8 v = *reinterpret_cast<const u16x8*>(in + (size_t)(bm + row) * ldin + bn + c8);
#pragma unroll
        for (int e = 0; e < 8; ++e) t[row][c8 + e] = v[e];
    }
    __syncthreads();
#pragma unroll
    for (int i = 0; i < 2; ++i) {
        const int orow = r + i * 32;
        u16x8 v;
#pragma unroll
        for (int e = 0; e < 8; ++e) v[e] = t[c8 + e][orow];
        *reinterpret_cast<u16x8*>(out + (size_t)(bn + orow) * M + bm + c8) = v;
    }
}

// ---------------------------------------------------------------------------
// Weight convert + transpose: w[K][N] fp32 -> wT[N][K] bf16, 64x64 tiles
// ---------------------------------------------------------------------------
__global__ __launch_bounds__(256)
void convT_kernel(const float* __restrict__ w, unsigned short* __restrict__ wT,
                  int K, int N)
{
    __shared__ unsigned short t[64][66];
    const int bk = blockIdx.y * 64, bn = blockIdx.x * 64;
    const int tid = threadIdx.x;
    const int r = tid >> 4, c4 = (tid & 15) * 4;
#pragma unroll
    for (int i = 0; i < 4; ++i) {
        const int row = r + i * 16;
        const float4 v = *reinterpret_cast<const float4*>(w + (size_t)(bk + row) * N + bn + c4);
        t[row][c4 + 0] = f2bf(v.x); t[row][c4 + 1] = f2bf(v.y);
        t[row][c4 + 2] = f2bf(v.z); t[row][c4 + 3] = f2bf(v.w);
    }
    __syncthreads();
#pragma unroll
    for (int i = 0; i < 4; ++i) {
        const int n = r + i * 16;
        u16x4 o;
#pragma unroll
        for (int e = 0; e < 4; ++e) o[e] = t[c4 + e][n];
        *reinterpret_cast<u16x4*>(wT + (size_t)(bn + n) * K + bk + c4) = o;
    }
}

// ---------------------------------------------------------------------------
// SwiGLU: g[s][f] = silu(t13[s][f]) * t13[s][f+5632]; t13 [2048][11264]
// grid (3, 2048); g compact [2048][5632]
// ---------------------------------------------------------------------------
__global__ __launch_bounds__(256)
void silu_mul_kernel(const unsigned short* __restrict__ t13,
                     unsigned short* __restrict__ g)
{
    const int s  = blockIdx.y;
    const int c8 = (blockIdx.x * 256 + threadIdx.x) * 8;
    if (c8 >= 5632) return;
    const unsigned short* row = t13 + (size_t)s * 11264;
    const u16x8 va = *reinterpret_cast<const u16x8*>(row + c8);
    const u16x8 vb = *reinterpret_cast<const u16x8*>(row + 5632 + c8);
    u16x8 o;
#pragma unroll
    for (int e = 0; e < 8; ++e) {
        const float x = bf2f(va[e]);
        const float y = bf2f(vb[e]);
        const float sv = x / (1.0f + __expf(-x));
        o[e] = f2bf(sv * y);
    }
    *reinterpret_cast<u16x8*>(g + (size_t)s * 5632 + c8) = o;
}

// ---------------------------------------------------------------------------
// Causal flash attention, no K/V LDS staging (K/V are L2-resident per head).
// q,k bf16 rows of qkv[2048][6144] (q cols 0.., k cols 2048..);
// vT bf16 [16*128][2048]. Block = (q-block 64 rows, head); 4 waves x 16 rows.
// Per-wave P roundtrip via LDS only; NO __syncthreads anywhere.
// ---------------------------------------------------------------------------
__global__ __launch_bounds__(256)
void flash_attn(const unsigned short* __restrict__ q,
                const unsigned short* __restrict__ k,
                const unsigned short* __restrict__ vT,
                unsigned short* __restrict__ attn)
{
    __shared__ alignas(16) unsigned short Ps[4][16][72]; // per-wave [q][kv]

    const int hh = blockIdx.y;
    const int qb = 31 - blockIdx.x;        // longest blocks first
    const int tid = threadIdx.x;
    const int lane = tid & 63, wave = tid >> 6;
    const int lr = lane & 15, lg = lane >> 4;
    const int q0 = qb * 64 + wave * 16;

    bf16x8 qf[4];
#pragma unroll
    for (int c = 0; c < 4; ++c)
        qf[c] = *reinterpret_cast<const bf16x8*>(
            q + (size_t)(q0 + lr) * 6144 + hh * 128 + c * 32 + lg * 8);

    f32x4 oacc[8] = {};
    float m_r[4], l_r[4];
#pragma unroll
    for (int r = 0; r < 4; ++r) { m_r[r] = -INFINITY; l_r[r] = 0.0f; }
    const float scale = 0.08838834764831845f;   // 1/sqrt(128)

    const unsigned short* kbase = k + hh * 128 + lg * 8;
    const unsigned short* vbase = vT + (size_t)(hh * 128 + lr) * 2048 + lg * 8;

    auto tile = [&](int kv0, bool masked) {
        // S = Q K^T : B-fragments straight from global (L1/L2 hot)
        f32x4 s[4] = {};
#pragma unroll
        for (int ct = 0; ct < 4; ++ct) {
            const unsigned short* krow = kbase + (size_t)(kv0 + ct * 16 + lr) * 6144;
#pragma unroll
            for (int c = 0; c < 4; ++c) {
                const bf16x8 kf = *reinterpret_cast<const bf16x8*>(krow + c * 32);
                s[ct] = __builtin_amdgcn_mfma_f32_16x16x32_bf16(qf[c], kf, s[ct], 0, 0, 0);
            }
        }
        // scale (+ causal mask on diagonal tile only)
#pragma unroll
        for (int ct = 0; ct < 4; ++ct)
#pragma unroll
            for (int r = 0; r < 4; ++r) {
                float v = s[ct][r] * scale;
                if (masked) {
                    const int kvg = kv0 + ct * 16 + lr;
                    const int qg  = q0 + lg * 4 + r;
                    if (kvg > qg) v = -INFINITY;
                }
                s[ct][r] = v;
            }
        // online softmax (row reduce across lane&15 axis)
        float mn[4], alpha[4], rs[4];
#pragma unroll
        for (int r = 0; r < 4; ++r) {
            float v = fmaxf(fmaxf(s[0][r], s[1][r]), fmaxf(s[2][r], s[3][r]));
            v = fmaxf(v, __shfl_xor(v, 1));
            v = fmaxf(v, __shfl_xor(v, 2));
            v = fmaxf(v, __shfl_xor(v, 4));
            v = fmaxf(v, __shfl_xor(v, 8));
            mn[r] = fmaxf(m_r[r], v);
            alpha[r] = __expf(m_r[r] - mn[r]);
            m_r[r] = mn[r];
            rs[r] = 0.0f;
        }
#pragma unroll
        for (int ct = 0; ct < 4; ++ct)
#pragma unroll
            for (int r = 0; r < 4; ++r) {
                const float p = __expf(s[ct][r] - mn[r]);
                s[ct][r] = p;
                rs[r] += p;
            }
#pragma unroll
        for (int r = 0; r < 4; ++r) {
            float t2 = rs[r];
            t2 += __shfl_xor(t2, 1);
            t2 += __shfl_xor(t2, 2);
            t2 += __shfl_xor(t2, 4);
            t2 += __shfl_xor(t2, 8);
            l_r[r] = l_r[r] * alpha[r] + t2;
        }
#pragma unroll
        for (int ot = 0; ot < 8; ++ot)
#pragma unroll
            for (int r = 0; r < 4; ++r) oacc[ot][r] *= alpha[r];

        // P -> per-wave LDS (bf16); intra-wave only, no barrier
#pragma unroll
        for (int ct = 0; ct < 4; ++ct)
#pragma unroll
            for (int r = 0; r < 4; ++r)
                Ps[wave][lg * 4 + r][ct * 16 + lr] = f2bf(s[ct][r]);

        // O += P V  (A = P from LDS, B = V^T fragments from global)
#pragma unroll
        for (int c2 = 0; c2 < 2; ++c2) {
            const bf16x8 pf = *reinterpret_cast<const bf16x8*>(&Ps[wave][lr][c2 * 32 + lg * 8]);
#pragma unroll
            for (int ot = 0; ot < 8; ++ot) {
                const bf16x8 vf = *reinterpret_cast<const bf16x8*>(
                    vbase + (size_t)(ot * 16) * 2048 + kv0 + c2 * 32);
                oacc[ot] = __builtin_amdgcn_mfma_f32_16x16x32_bf16(pf, vf, oacc[ot], 0, 0, 0);
            }
        }
    };

    for (int kt = 0; kt < qb; ++kt) tile(kt * 64, false);
    tile(qb * 64, true);

#pragma unroll
    for (int ot = 0; ot < 8; ++ot)
#pragma unroll
        for (int r = 0; r < 4; ++r) {
            const float v = oacc[ot][r] / l_r[r];
            attn[(size_t)(q0 + lg * 4 + r) * 2048 + hh * 128 + ot * 16 + lr] = f2bf(v);
        }
}

// ---------------------------------------------------------------------------
extern "C" void kernel_launch(void* const* d_in, const int* in_sizes, int n_in,
                              void* d_out, int out_size, void* d_ws, size_t ws_size,
                              hipStream_t stream)
{
    const float* x    = (const float*)d_in[0];
    const float* fcos = (const float*)d_in[1];
    const float* fsin = (const float*)d_in[2];
    // d_in[3] = mask (causal, hardcoded)
    const float* wq  = (const float*)d_in[4];
    const float* wk  = (const float*)d_in[5];
    const float* wv  = (const float*)d_in[6];
    const float* wo  = (const float*)d_in[7];
    const float* w1  = (const float*)d_in[8];
    const float* w2  = (const float*)d_in[9];
    const float* w3  = (const float*)d_in[10];
    const float* anw = (const float*)d_in[11];
    const float* fnw = (const float*)d_in[12];
    float* out = (float*)d_out;

    char* ws = (char*)d_ws;
    size_t off = 0;
    auto alloc = [&](size_t bytes) { void* p = ws + off; off += bytes; return p; };
    const size_t SZ_DD = (size_t)2048 * 2048 * 2;   // 8 MiB
    const size_t SZ_DF = (size_t)2048 * 5632 * 2;   // 22 MiB

    // weights: wq/wk/wv contiguous -> qkvT [6144][2048]; w1/w3 -> w13T [11264][2048]
    unsigned short* wqT = (unsigned short*)alloc(SZ_DD);
    unsigned short* wkT = (unsigned short*)alloc(SZ_DD);
    unsigned short* wvT = (unsigned short*)alloc(SZ_DD);
    unsigned short* woT = (unsigned short*)alloc(SZ_DD);
    unsigned short* w1T = (unsigned short*)alloc(SZ_DF);
    unsigned short* w3T = (unsigned short*)alloc(SZ_DF);
    unsigned short* w2T = (unsigned short*)alloc(SZ_DF);

    // region1 (48 MiB): attn phase = xn | qkv | vT | attn ; FFN phase = t13
    char* reg1 = (char*)alloc((size_t)48 * 1024 * 1024);
    unsigned short* xn   = (unsigned short*)reg1;
    unsigned short* qkv  = (unsigned short*)(reg1 + SZ_DD);            // [2048][6144]
    unsigned short* vTb  = (unsigned short*)(reg1 + SZ_DD + 3 * SZ_DD);
    unsigned short* ab   = (unsigned short*)(reg1 + SZ_DD + 4 * SZ_DD);
    unsigned short* t13  = (unsigned short*)reg1;                      // [2048][11264]

    // hn overlapped by t1 (hn dead before silu writes t1)
    char* reg2 = (char*)alloc(SZ_DF);
    unsigned short* hn = (unsigned short*)reg2;
    unsigned short* t1 = (unsigned short*)reg2;

    // weight fp32 -> bf16 transposed
    convT_kernel<<<dim3(32, 32), 256, 0, stream>>>(wq, wqT, 2048, 2048);
    convT_kernel<<<dim3(32, 32), 256, 0, stream>>>(wk, wkT, 2048, 2048);
    convT_kernel<<<dim3(32, 32), 256, 0, stream>>>(wv, wvT, 2048, 2048);
    convT_kernel<<<dim3(32, 32), 256, 0, stream>>>(wo, woT, 2048, 2048);
    convT_kernel<<<dim3(88, 32), 256, 0, stream>>>(w1, w1T, 2048, 5632);
    convT_kernel<<<dim3(88, 32), 256, 0, stream>>>(w3, w3T, 2048, 5632);
    convT_kernel<<<dim3(32, 88), 256, 0, stream>>>(w2, w2T, 5632, 2048);

    // attention block
    rmsnorm_kernel<<<2048, 256, 0, stream>>>(x, anw, xn);
    // fused QKV: [2048][6144] = xn @ qkvT^T
    gemm_bt<0><<<dim3(48, 16), 256, 0, stream>>>(xn, wqT, qkv, nullptr, nullptr, 2048, 6144, 2048);
    rope_kernel<<<4096, 256, 0, stream>>>(qkv, fcos, fsin);   // q and k halves
    transpose_bf16<<<dim3(32, 32), 256, 0, stream>>>(qkv + 4096, vTb, 2048, 2048, 6144);
    flash_attn<<<dim3(32, 16), 256, 0, stream>>>(qkv, qkv + 2048, vTb, ab);
    gemm_bt<1><<<dim3(16, 16), 256, 0, stream>>>(ab, woT, nullptr, out, x, 2048, 2048, 2048);

    // FFN block
    rmsnorm_kernel<<<2048, 256, 0, stream>>>(out, fnw, hn);
    // fused W1|W3: [2048][11264] = hn @ w13T^T
    gemm_bt<0><<<dim3(88, 16), 256, 0, stream>>>(hn, w1T, t13, nullptr, nullptr, 2048, 11264, 2048);
    silu_mul_kernel<<<dim3(3, 2048), 256, 0, stream>>>(t13, t1);
    gemm_bt<1><<<dim3(16, 16), 256, 0, stream>>>(t1, w2T, nullptr, out, out, 2048, 2048, 5632);
}

// Round 3
// 517.019 us; speedup vs baseline: 1.3064x; 1.3064x over previous
//
#include <hip/hip_runtime.h>
#include <hip/hip_bf16.h>

typedef __bf16 bf16x8 __attribute__((ext_vector_type(8)));
typedef float f32x4 __attribute__((ext_vector_type(4)));
typedef unsigned short u16x8 __attribute__((ext_vector_type(8)));
typedef unsigned short u16x4 __attribute__((ext_vector_type(4)));

#define DEV static __device__ __forceinline__

DEV unsigned short f2bf(float f) {
    unsigned u = __builtin_bit_cast(unsigned, f);
    u += 0x7fffu + ((u >> 16) & 1u);   // round-to-nearest-even
    return (unsigned short)(u >> 16);
}
DEV float bf2f(unsigned short h) {
    unsigned u = ((unsigned)h) << 16;
    return __builtin_bit_cast(float, u);
}

DEV void gl2lds16(const void* g, void* l) {
    __builtin_amdgcn_global_load_lds(
        (const __attribute__((address_space(1))) void*)g,
        (__attribute__((address_space(3))) void*)l, 16, 0, 0);
}

// ---------------------------------------------------------------------------
// GEMM (m97 structure): C[M,N] = A[M,K](bf16) @ BT[N,K](bf16)^T
// global_load_lds width-16 staging, linear LDS, BK=32.
// BM in {128,64}; BN=128; 256 thr = 4 waves (2x2), wave tile (BM/2)x64.
// EPI 0: bf16 C.  EPI 1: fp32 res + C.
// ---------------------------------------------------------------------------
template <int EPI, int BM>
__global__ __launch_bounds__(256)
void gemm_bt(const unsigned short* __restrict__ A,
             const unsigned short* __restrict__ BT,
             unsigned short* __restrict__ outB,
             float* __restrict__ outF,
             const float* __restrict__ res,
             int M, int N, int K)
{
    constexpr int AM = BM / 32;          // A frags per wave: 128->4, 64->2
    constexpr int CAW = BM / 64;         // A 1KB-chunks per wave: 128->2, 64->1
    __shared__ alignas(16) unsigned short As[BM][32];
    __shared__ alignas(16) unsigned short Bs[128][32];

    const int tid  = threadIdx.x;
    const int lane = tid & 63;
    const int wave = tid >> 6;
    const int bm = blockIdx.y * BM;
    const int bn = blockIdx.x * 128;
    const int wm = (wave >> 1) * (BM / 2);
    const int wn = (wave & 1) * 64;
    const int lr = lane & 15;
    const int lg = lane >> 4;
    const int sub = lane >> 2;           // 0..15: row within 16-row chunk
    const int cb  = (lane & 3) * 16;     // byte col within 64B row

    f32x4 acc[AM][4] = {};

    auto stage = [&](int kt) {
#pragma unroll
        for (int ch = 0; ch < CAW; ++ch) {
            const int rb = wave * (CAW * 16) + ch * 16;
            const void* g = (const char*)(A + (size_t)(bm + rb + sub) * K + kt * 32) + cb;
            gl2lds16(g, &As[rb][0]);
        }
#pragma unroll
        for (int ch = 0; ch < 2; ++ch) {
            const int rb = wave * 32 + ch * 16;
            const void* g = (const char*)(BT + (size_t)(bn + rb + sub) * K + kt * 32) + cb;
            gl2lds16(g, &Bs[rb][0]);
        }
    };

    const int NT = K >> 5;
    for (int kt = 0; kt < NT; ++kt) {
        stage(kt);
        __syncthreads();                 // drains vmcnt -> LDS filled
        bf16x8 af[AM], bfr[4];
#pragma unroll
        for (int i = 0; i < AM; ++i)
            af[i] = *reinterpret_cast<const bf16x8*>(&As[wm + i * 16 + lr][lg * 8]);
#pragma unroll
        for (int j = 0; j < 4; ++j)
            bfr[j] = *reinterpret_cast<const bf16x8*>(&Bs[wn + j * 16 + lr][lg * 8]);
#pragma unroll
        for (int i = 0; i < AM; ++i)
#pragma unroll
            for (int j = 0; j < 4; ++j)
                acc[i][j] = __builtin_amdgcn_mfma_f32_16x16x32_bf16(af[i], bfr[j], acc[i][j], 0, 0, 0);
        __syncthreads();                 // compute done before overwrite
    }

#pragma unroll
    for (int i = 0; i < AM; ++i) {
#pragma unroll
        for (int j = 0; j < 4; ++j) {
            const int col = bn + wn + j * 16 + lr;
#pragma unroll
            for (int r = 0; r < 4; ++r) {
                const int row = bm + wm + i * 16 + lg * 4 + r;
                const float v = acc[i][j][r];
                if constexpr (EPI == 0) {
                    outB[(size_t)row * N + col] = f2bf(v);
                } else {
                    outF[(size_t)row * N + col] = res[(size_t)row * N + col] + v;
                }
            }
        }
    }
}

// ---------------------------------------------------------------------------
// RMSNorm: fp32 in [2048][2048] -> bf16 out, weight fp32. One block per row.
// ---------------------------------------------------------------------------
__global__ __launch_bounds__(256)
void rmsnorm_kernel(const float* __restrict__ x, const float* __restrict__ w,
                    unsigned short* __restrict__ out)
{
    const int row = blockIdx.x;
    const int tid = threadIdx.x;
    const float* xr = x + (size_t)row * 2048;
    const float4 a = *reinterpret_cast<const float4*>(xr + tid * 8);
    const float4 b = *reinterpret_cast<const float4*>(xr + tid * 8 + 4);
    float ss = a.x * a.x + a.y * a.y + a.z * a.z + a.w * a.w
             + b.x * b.x + b.y * b.y + b.z * b.z + b.w * b.w;
#pragma unroll
    for (int off = 32; off; off >>= 1) ss += __shfl_xor(ss, off);
    __shared__ float red[4];
    if ((tid & 63) == 0) red[tid >> 6] = ss;
    __syncthreads();
    const float tot = red[0] + red[1] + red[2] + red[3];
    const float sc = rsqrtf(tot * (1.0f / 2048.0f) + 1e-5f);
    const float4 wa = *reinterpret_cast<const float4*>(w + tid * 8);
    const float4 wb = *reinterpret_cast<const float4*>(w + tid * 8 + 4);
    u16x8 o;
    o[0] = f2bf(a.x * sc * wa.x); o[1] = f2bf(a.y * sc * wa.y);
    o[2] = f2bf(a.z * sc * wa.z); o[3] = f2bf(a.w * sc * wa.w);
    o[4] = f2bf(b.x * sc * wb.x); o[5] = f2bf(b.y * sc * wb.y);
    o[6] = f2bf(b.z * sc * wb.z); o[7] = f2bf(b.w * sc * wb.w);
    *reinterpret_cast<u16x8*>(out + (size_t)row * 2048 + tid * 8) = o;
}

// ---------------------------------------------------------------------------
// RoPE in-place on bf16 qkv[2048][6144], first 4096 cols (q and k regions).
// ---------------------------------------------------------------------------
__global__ __launch_bounds__(256)
void rope_kernel(unsigned short* __restrict__ t, const float* __restrict__ cs,
                 const float* __restrict__ sn)
{
    const int idx = blockIdx.x * 256 + threadIdx.x;   // S * 4096 / 8
    const int s   = idx >> 9;
    const int col = (idx & 511) * 8;
    const int i0  = (col & 127) >> 1;
    u16x8 v = *reinterpret_cast<const u16x8*>(t + (size_t)s * 6144 + col);
    const float4 c  = *reinterpret_cast<const float4*>(cs + s * 64 + i0);
    const float4 sv = *reinterpret_cast<const float4*>(sn + s * 64 + i0);
    const float cc[4] = {c.x, c.y, c.z, c.w};
    const float ns[4] = {sv.x, sv.y, sv.z, sv.w};
#pragma unroll
    for (int p = 0; p < 4; ++p) {
        const float re = bf2f(v[2 * p]), im = bf2f(v[2 * p + 1]);
        v[2 * p]     = f2bf(re * cc[p] - im * ns[p]);
        v[2 * p + 1] = f2bf(re * ns[p] + im * cc[p]);
    }
    *reinterpret_cast<u16x8*>(t + (size_t)s * 6144 + col) = v;
}

// ---------------------------------------------------------------------------
// bf16 transpose: out[N][M] = in[M][N]^T (row stride ldin), 64x64 tiles
// ---------------------------------------------------------------------------
__global__ __launch_bounds__(256)
void transpose_bf16(const unsigned short* __restrict__ in,
                    unsigned short* __restrict__ out, int M, int N, int ldin)
{
    __shared__ unsigned short t[64][66];
    const int bm = blockIdx.y * 64, bn = blockIdx.x * 64;
    const int tid = threadIdx.x;
    const int r = tid >> 3, c8 = (tid & 7) * 8;
#pragma unroll
    for (int i = 0; i < 2; ++i) {
        const int row = r + i * 32;
        u16x8 v = *reinterpret_cast<const u16x8*>(in + (size_t)(bm + row) * ldin + bn + c8);
#pragma unroll
        for (int e = 0; e < 8; ++e) t[row][c8 + e] = v[e];
    }
    __syncthreads();
#pragma unroll
    for (int i = 0; i < 2; ++i) {
        const int orow = r + i * 32;
        u16x8 v;
#pragma unroll
        for (int e = 0; e < 8; ++e) v[e] = t[c8 + e][orow];
        *reinterpret_cast<u16x8*>(out + (size_t)(bn + orow) * M + bm + c8) = v;
    }
}

// ---------------------------------------------------------------------------
// Weight convert + transpose: w[K][N] fp32 -> wT[N][K] bf16, 64x64 tiles
// ---------------------------------------------------------------------------
__global__ __launch_bounds__(256)
void convT_kernel(const float* __restrict__ w, unsigned short* __restrict__ wT,
                  int K, int N)
{
    __shared__ unsigned short t[64][66];
    const int bk = blockIdx.y * 64, bn = blockIdx.x * 64;
    const int tid = threadIdx.x;
    const int r = tid >> 4, c4 = (tid & 15) * 4;
#pragma unroll
    for (int i = 0; i < 4; ++i) {
        const int row = r + i * 16;
        const float4 v = *reinterpret_cast<const float4*>(w + (size_t)(bk + row) * N + bn + c4);
        t[row][c4 + 0] = f2bf(v.x); t[row][c4 + 1] = f2bf(v.y);
        t[row][c4 + 2] = f2bf(v.z); t[row][c4 + 3] = f2bf(v.w);
    }
    __syncthreads();
#pragma unroll
    for (int i = 0; i < 4; ++i) {
        const int n = r + i * 16;
        u16x4 o;
#pragma unroll
        for (int e = 0; e < 4; ++e) o[e] = t[c4 + e][n];
        *reinterpret_cast<u16x4*>(wT + (size_t)(bn + n) * K + bk + c4) = o;
    }
}

// ---------------------------------------------------------------------------
// SwiGLU: g[s][f] = silu(t13[s][f]) * t13[s][f+5632]; t13 [2048][11264]
// ---------------------------------------------------------------------------
__global__ __launch_bounds__(256)
void silu_mul_kernel(const unsigned short* __restrict__ t13,
                     unsigned short* __restrict__ g)
{
    const int s  = blockIdx.y;
    const int c8 = (blockIdx.x * 256 + threadIdx.x) * 8;
    if (c8 >= 5632) return;
    const unsigned short* row = t13 + (size_t)s * 11264;
    const u16x8 va = *reinterpret_cast<const u16x8*>(row + c8);
    const u16x8 vb = *reinterpret_cast<const u16x8*>(row + 5632 + c8);
    u16x8 o;
#pragma unroll
    for (int e = 0; e < 8; ++e) {
        const float x = bf2f(va[e]);
        const float y = bf2f(vb[e]);
        const float sv = x / (1.0f + __expf(-x));
        o[e] = f2bf(sv * y);
    }
    *reinterpret_cast<u16x8*>(g + (size_t)s * 5632 + c8) = o;
}

// ---------------------------------------------------------------------------
// Causal flash attention, paired q-tiles for balance.
// Block = (pair i, head): waves 0-3 -> q-tile i, waves 4-7 -> q-tile 31-i.
// K/V double-buffered LDS; issue-early/write-late; ONE barrier per stage.
// ---------------------------------------------------------------------------
__global__ __launch_bounds__(512)
void flash_attn(const unsigned short* __restrict__ q,
                const unsigned short* __restrict__ k,
                const unsigned short* __restrict__ vT,
                unsigned short* __restrict__ attn)
{
    __shared__ alignas(16) unsigned short Ks[2][64][136];  // [buf][kv][hd]
    __shared__ alignas(16) unsigned short Vs[2][128][72];  // [buf][hd][kv]
    __shared__ alignas(16) unsigned short Ps[8][16][72];   // per-wave P

    const int hh = blockIdx.y;
    const int pi = blockIdx.x;              // 0..15
    const int tid = threadIdx.x;
    const int lane = tid & 63, wave = tid >> 6;
    const int qt = (wave >> 2) ? (31 - pi) : pi;
    const int lr = lane & 15, lg = lane >> 4;
    const int q0 = qt * 64 + (wave & 3) * 16;
    const int myNT = qt + 1;                // this group computes kt < myNT
    const int NT   = 32 - pi;               // stages = max(myNT over groups)

    // staging assignment (512 threads, 2 chunks each of K and V)
    const int kr0 = tid >> 4, kc0 = (tid & 15) * 8;
    const int vr0 = tid >> 3, vc0 = (tid & 7) * 8;

    bf16x8 qf[4];
#pragma unroll
    for (int c = 0; c < 4; ++c)
        qf[c] = *reinterpret_cast<const bf16x8*>(
            q + (size_t)(q0 + lr) * 6144 + hh * 128 + c * 32 + lg * 8);

    f32x4 oacc[8] = {};
    float m_r[4], l_r[4];
#pragma unroll
    for (int r = 0; r < 4; ++r) { m_r[r] = -INFINITY; l_r[r] = 0.0f; }
    const float scale = 0.08838834764831845f;   // 1/sqrt(128)

    u16x8 kreg0, kreg1, vreg0, vreg1;
    auto gload = [&](int kt) {
        const int kv0 = kt * 64;
        kreg0 = *reinterpret_cast<const u16x8*>(k + (size_t)(kv0 + kr0) * 6144 + hh * 128 + kc0);
        kreg1 = *reinterpret_cast<const u16x8*>(k + (size_t)(kv0 + kr0 + 32) * 6144 + hh * 128 + kc0);
        vreg0 = *reinterpret_cast<const u16x8*>(vT + (size_t)(hh * 128 + vr0) * 2048 + kv0 + vc0);
        vreg1 = *reinterpret_cast<const u16x8*>(vT + (size_t)(hh * 128 + vr0 + 64) * 2048 + kv0 + vc0);
    };
    auto lwrite = [&](int buf) {
        *reinterpret_cast<u16x8*>(&Ks[buf][kr0][kc0])      = kreg0;
        *reinterpret_cast<u16x8*>(&Ks[buf][kr0 + 32][kc0]) = kreg1;
        *reinterpret_cast<u16x8*>(&Vs[buf][vr0][vc0])      = vreg0;
        *reinterpret_cast<u16x8*>(&Vs[buf][vr0 + 64][vc0]) = vreg1;
    };

    gload(0); lwrite(0);
    __syncthreads();

    for (int kt = 0; kt < NT; ++kt) {
        const int buf = kt & 1;
        if (kt + 1 < NT) gload(kt + 1);         // issue early

        if (kt < myNT) {
            const int kv0 = kt * 64;
            const bool masked = (kt == myNT - 1);
            // S = Q K^T
            f32x4 s[4] = {};
            __builtin_amdgcn_s_setprio(1);
#pragma unroll
            for (int ct = 0; ct < 4; ++ct)
#pragma unroll
                for (int c = 0; c < 4; ++c) {
                    const bf16x8 kf = *reinterpret_cast<const bf16x8*>(
                        &Ks[buf][ct * 16 + lr][c * 32 + lg * 8]);
                    s[ct] = __builtin_amdgcn_mfma_f32_16x16x32_bf16(qf[c], kf, s[ct], 0, 0, 0);
                }
            __builtin_amdgcn_s_setprio(0);
            // scale + causal mask (diag tile only)
#pragma unroll
            for (int ct = 0; ct < 4; ++ct)
#pragma unroll
                for (int r = 0; r < 4; ++r) {
                    float v = s[ct][r] * scale;
                    if (masked) {
                        const int kvg = kv0 + ct * 16 + lr;
                        const int qg  = q0 + lg * 4 + r;
                        if (kvg > qg) v = -INFINITY;
                    }
                    s[ct][r] = v;
                }
            // online softmax
            float mn[4], alpha[4], rs[4];
#pragma unroll
            for (int r = 0; r < 4; ++r) {
                float v = fmaxf(fmaxf(s[0][r], s[1][r]), fmaxf(s[2][r], s[3][r]));
                v = fmaxf(v, __shfl_xor(v, 1));
                v = fmaxf(v, __shfl_xor(v, 2));
                v = fmaxf(v, __shfl_xor(v, 4));
                v = fmaxf(v, __shfl_xor(v, 8));
                mn[r] = fmaxf(m_r[r], v);
                alpha[r] = __expf(m_r[r] - mn[r]);
                m_r[r] = mn[r];
                rs[r] = 0.0f;
            }
#pragma unroll
            for (int ct = 0; ct < 4; ++ct)
#pragma unroll
                for (int r = 0; r < 4; ++r) {
                    const float p = __expf(s[ct][r] - mn[r]);
                    s[ct][r] = p;
                    rs[r] += p;
                }
#pragma unroll
            for (int r = 0; r < 4; ++r) {
                float t2 = rs[r];
                t2 += __shfl_xor(t2, 1);
                t2 += __shfl_xor(t2, 2);
                t2 += __shfl_xor(t2, 4);
                t2 += __shfl_xor(t2, 8);
                l_r[r] = l_r[r] * alpha[r] + t2;
            }
#pragma unroll
            for (int ot = 0; ot < 8; ++ot)
#pragma unroll
                for (int r = 0; r < 4; ++r) oacc[ot][r] *= alpha[r];

            // P -> per-wave LDS (intra-wave only)
#pragma unroll
            for (int ct = 0; ct < 4; ++ct)
#pragma unroll
                for (int r = 0; r < 4; ++r)
                    Ps[wave][lg * 4 + r][ct * 16 + lr] = f2bf(s[ct][r]);

            // O += P V
            __builtin_amdgcn_s_setprio(1);
#pragma unroll
            for (int c2 = 0; c2 < 2; ++c2) {
                const bf16x8 pf = *reinterpret_cast<const bf16x8*>(
                    &Ps[wave][lr][c2 * 32 + lg * 8]);
#pragma unroll
                for (int ot = 0; ot < 8; ++ot) {
                    const bf16x8 vf = *reinterpret_cast<const bf16x8*>(
                        &Vs[buf][ot * 16 + lr][c2 * 32 + lg * 8]);
                    oacc[ot] = __builtin_amdgcn_mfma_f32_16x16x32_bf16(pf, vf, oacc[ot], 0, 0, 0);
                }
            }
            __builtin_amdgcn_s_setprio(0);
        }

        if (kt + 1 < NT) lwrite(buf ^ 1);       // write late (other buffer)
        __syncthreads();
    }

#pragma unroll
    for (int ot = 0; ot < 8; ++ot)
#pragma unroll
        for (int r = 0; r < 4; ++r) {
            const float v = oacc[ot][r] / l_r[r];
            attn[(size_t)(q0 + lg * 4 + r) * 2048 + hh * 128 + ot * 16 + lr] = f2bf(v);
        }
}

// ---------------------------------------------------------------------------
extern "C" void kernel_launch(void* const* d_in, const int* in_sizes, int n_in,
                              void* d_out, int out_size, void* d_ws, size_t ws_size,
                              hipStream_t stream)
{
    const float* x    = (const float*)d_in[0];
    const float* fcos = (const float*)d_in[1];
    const float* fsin = (const float*)d_in[2];
    // d_in[3] = mask (causal, hardcoded)
    const float* wq  = (const float*)d_in[4];
    const float* wk  = (const float*)d_in[5];
    const float* wv  = (const float*)d_in[6];
    const float* wo  = (const float*)d_in[7];
    const float* w1  = (const float*)d_in[8];
    const float* w2  = (const float*)d_in[9];
    const float* w3  = (const float*)d_in[10];
    const float* anw = (const float*)d_in[11];
    const float* fnw = (const float*)d_in[12];
    float* out = (float*)d_out;

    char* ws = (char*)d_ws;
    size_t off = 0;
    auto alloc = [&](size_t bytes) { void* p = ws + off; off += bytes; return p; };
    const size_t SZ_DD = (size_t)2048 * 2048 * 2;   // 8 MiB
    const size_t SZ_DF = (size_t)2048 * 5632 * 2;   // 22 MiB

    unsigned short* wqT = (unsigned short*)alloc(SZ_DD);
    unsigned short* wkT = (unsigned short*)alloc(SZ_DD);
    unsigned short* wvT = (unsigned short*)alloc(SZ_DD);
    unsigned short* woT = (unsigned short*)alloc(SZ_DD);
    unsigned short* w1T = (unsigned short*)alloc(SZ_DF);
    unsigned short* w3T = (unsigned short*)alloc(SZ_DF);
    unsigned short* w2T = (unsigned short*)alloc(SZ_DF);

    // region1 (48 MiB): attn phase = xn | qkv | vT | attn ; FFN phase = t13
    char* reg1 = (char*)alloc((size_t)48 * 1024 * 1024);
    unsigned short* xn   = (unsigned short*)reg1;
    unsigned short* qkv  = (unsigned short*)(reg1 + SZ_DD);            // [2048][6144]
    unsigned short* vTb  = (unsigned short*)(reg1 + SZ_DD + 3 * SZ_DD);
    unsigned short* ab   = (unsigned short*)(reg1 + SZ_DD + 4 * SZ_DD);
    unsigned short* t13  = (unsigned short*)reg1;                      // [2048][11264]

    char* reg2 = (char*)alloc(SZ_DF);
    unsigned short* hn = (unsigned short*)reg2;
    unsigned short* t1 = (unsigned short*)reg2;

    // weight fp32 -> bf16 transposed
    convT_kernel<<<dim3(32, 32), 256, 0, stream>>>(wq, wqT, 2048, 2048);
    convT_kernel<<<dim3(32, 32), 256, 0, stream>>>(wk, wkT, 2048, 2048);
    convT_kernel<<<dim3(32, 32), 256, 0, stream>>>(wv, wvT, 2048, 2048);
    convT_kernel<<<dim3(32, 32), 256, 0, stream>>>(wo, woT, 2048, 2048);
    convT_kernel<<<dim3(88, 32), 256, 0, stream>>>(w1, w1T, 2048, 5632);
    convT_kernel<<<dim3(88, 32), 256, 0, stream>>>(w3, w3T, 2048, 5632);
    convT_kernel<<<dim3(32, 88), 256, 0, stream>>>(w2, w2T, 5632, 2048);

    // attention block
    rmsnorm_kernel<<<2048, 256, 0, stream>>>(x, anw, xn);
    gemm_bt<0, 128><<<dim3(48, 16), 256, 0, stream>>>(xn, wqT, qkv, nullptr, nullptr, 2048, 6144, 2048);
    rope_kernel<<<4096, 256, 0, stream>>>(qkv, fcos, fsin);
    transpose_bf16<<<dim3(32, 32), 256, 0, stream>>>(qkv + 4096, vTb, 2048, 2048, 6144);
    flash_attn<<<dim3(16, 16), 512, 0, stream>>>(qkv, qkv + 2048, vTb, ab);
    gemm_bt<1, 64><<<dim3(16, 32), 256, 0, stream>>>(ab, woT, nullptr, out, x, 2048, 2048, 2048);

    // FFN block
    rmsnorm_kernel<<<2048, 256, 0, stream>>>(out, fnw, hn);
    gemm_bt<0, 128><<<dim3(88, 16), 256, 0, stream>>>(hn, w1T, t13, nullptr, nullptr, 2048, 11264, 2048);
    silu_mul_kernel<<<dim3(3, 2048), 256, 0, stream>>>(t13, t1);
    gemm_bt<1, 64><<<dim3(16, 32), 256, 0, stream>>>(t1, w2T, nullptr, out, out, 2048, 2048, 5632);
}

// Round 4
// 488.328 us; speedup vs baseline: 1.3832x; 1.0588x over previous
//
#include <hip/hip_runtime.h>
#include <hip/hip_bf16.h>

typedef __bf16 bf16x8 __attribute__((ext_vector_type(8)));
typedef float f32x4 __attribute__((ext_vector_type(4)));
typedef unsigned short u16x8 __attribute__((ext_vector_type(8)));
typedef unsigned short u16x4 __attribute__((ext_vector_type(4)));

#define DEV static __device__ __forceinline__

DEV unsigned short f2bf(float f) {
    unsigned u = __builtin_bit_cast(unsigned, f);
    u += 0x7fffu + ((u >> 16) & 1u);   // round-to-nearest-even
    return (unsigned short)(u >> 16);
}
DEV float bf2f(unsigned short h) {
    unsigned u = ((unsigned)h) << 16;
    return __builtin_bit_cast(float, u);
}

DEV void gl2lds16(const void* g, void* l) {
    __builtin_amdgcn_global_load_lds(
        (const __attribute__((address_space(1))) void*)g,
        (__attribute__((address_space(3))) void*)l, 16, 0, 0);
}

// ===========================================================================
// gemm256_bt: 256x256 tile, 8-phase counted-vmcnt schedule (T2+T3+T4+T5).
// C[M,N](bf16) = A[M,K](bf16) @ BT[N,K](bf16)^T
// 512 thr = 8 waves (2M x 4N); per-wave 128x64 C (acc[8][4]); BK=64.
// LDS 128KB: 2 dbuf x 4 slots [A0,B0,A1,B1] x 16KB ([128 rows][64 bf16]).
// Swizzle: phys_byte = log_byte ^ ((row&7)<<4)  (both-sides: pre-swizzled
// global source for global_load_lds + swizzled ds_read).
// vmcnt(6) at p0/p1/p2 (3 half-tiles in flight), none at p3; raw s_barrier.
// ===========================================================================
#define STAGE256(KT, SLOT, BUF)                                               \
    {                                                                         \
        const unsigned short* sbase = ((SLOT) & 1)                            \
            ? BT + (size_t)(bn + ((SLOT) >> 1) * 128) * K                     \
            : A  + (size_t)(bm + ((SLOT) >> 1) * 128) * K;                    \
        _Pragma("unroll")                                                     \
        for (int j = 0; j < 2; ++j) {                                         \
            const unsigned short* g = sbase + (size_t)(srow + j * 64) * K     \
                                      + (KT) * 64 + lc;                       \
            gl2lds16(g, &lds[BUF][SLOT][wave * 512 + j * 4096]);              \
        }                                                                     \
    }

#define COMPUTE256(BUF, MH, NH)                                               \
    {                                                                         \
        const char* Ab = (const char*)&lds[BUF][(MH) * 2][0];                 \
        const char* Bb = (const char*)&lds[BUF][(NH) * 2 + 1][0];             \
        bf16x8 a_[4][2], b_[2][2];                                            \
        _Pragma("unroll")                                                     \
        for (int m4 = 0; m4 < 4; ++m4) {                                      \
            _Pragma("unroll")                                                 \
            for (int kk = 0; kk < 2; ++kk)                                    \
                a_[m4][kk] = *(const bf16x8*)(Ab +                            \
                    (wm * 64 + m4 * 16 + lr) * 128 +                          \
                    ((kk * 64 + lg * 16) ^ xsw));                             \
        }                                                                     \
        _Pragma("unroll")                                                     \
        for (int n2 = 0; n2 < 2; ++n2) {                                      \
            _Pragma("unroll")                                                 \
            for (int kk = 0; kk < 2; ++kk)                                    \
                b_[n2][kk] = *(const bf16x8*)(Bb +                            \
                    (wn * 32 + n2 * 16 + lr) * 128 +                          \
                    ((kk * 64 + lg * 16) ^ xsw));                             \
        }                                                                     \
        __builtin_amdgcn_s_setprio(1);                                        \
        _Pragma("unroll")                                                     \
        for (int m4 = 0; m4 < 4; ++m4)                                        \
            _Pragma("unroll")                                                 \
            for (int n2 = 0; n2 < 2; ++n2)                                    \
                _Pragma("unroll")                                             \
                for (int kk = 0; kk < 2; ++kk)                                \
                    acc[(MH) * 4 + m4][(NH) * 2 + n2] =                       \
                        __builtin_amdgcn_mfma_f32_16x16x32_bf16(              \
                            a_[m4][kk], b_[n2][kk],                           \
                            acc[(MH) * 4 + m4][(NH) * 2 + n2], 0, 0, 0);      \
        __builtin_amdgcn_s_setprio(0);                                        \
    }

#define WAITV(N) asm volatile("s_waitcnt vmcnt(" #N ")" ::: "memory")
#define SBAR()   asm volatile("s_barrier" ::: "memory")

__global__ __launch_bounds__(512, 2)
void gemm256_bt(const unsigned short* __restrict__ A,
                const unsigned short* __restrict__ BT,
                unsigned short* __restrict__ outB,
                int M, int N, int K)
{
    __shared__ alignas(16) unsigned short lds[2][4][8192];   // 128 KiB

    const int tid  = threadIdx.x;
    const int lane = tid & 63;
    const int wave = tid >> 6;
    const int wm = wave >> 2;            // 0..1
    const int wn = wave & 3;             // 0..3
    const int lr = lane & 15;
    const int lg = lane >> 4;
    const int bm = blockIdx.y * 256;
    const int bn = blockIdx.x * 256;
    const int xsw  = (lr & 7) << 4;                      // read-side swizzle
    const int srow = tid >> 3;                           // staging row (j=0)
    const int lc   = ((tid & 7) ^ (srow & 7)) * 8;       // pre-swizzled src col

    f32x4 acc[8][4] = {};

    const int NT = K >> 6;               // BK = 64

    // prologue: stage tile 0 (4 half-tiles, 8 loads/thread)
    STAGE256(0, 0, 0); STAGE256(0, 1, 0); STAGE256(0, 2, 0); STAGE256(0, 3, 0);

    for (int kt = 0; kt < NT - 1; ++kt) {
        const int buf = kt & 1, nbuf = buf ^ 1;
        // p0: quadrant (A0,B0)
        STAGE256(kt + 1, 0, nbuf);
        WAITV(6); SBAR();
        COMPUTE256(buf, 0, 0);
        // p1: (A1,B0)
        STAGE256(kt + 1, 1, nbuf);
        WAITV(6); SBAR();
        COMPUTE256(buf, 1, 0);
        // p2: (A1,B1)
        STAGE256(kt + 1, 2, nbuf);
        WAITV(6); SBAR();
        COMPUTE256(buf, 1, 1);
        // p3: (A0,B1) — all halves already landed; tile-boundary barrier after
        STAGE256(kt + 1, 3, nbuf);
        COMPUTE256(buf, 0, 1);
        SBAR();
    }
    {   // last tile: drain 4 -> 2 -> 0
        const int buf = (NT - 1) & 1;
        WAITV(4); SBAR();
        COMPUTE256(buf, 0, 0);
        WAITV(2); SBAR();
        COMPUTE256(buf, 1, 0);
        WAITV(0); SBAR();
        COMPUTE256(buf, 1, 1);
        COMPUTE256(buf, 0, 1);
    }

#pragma unroll
    for (int m = 0; m < 8; ++m) {
        const int row = bm + (m >> 2) * 128 + wm * 64 + (m & 3) * 16 + lg * 4;
#pragma unroll
        for (int n = 0; n < 4; ++n) {
            const int col = bn + (n >> 1) * 128 + wn * 32 + (n & 1) * 16 + lr;
#pragma unroll
            for (int r = 0; r < 4; ++r)
                outB[(size_t)(row + r) * N + col] = f2bf(acc[m][n][r]);
        }
    }
}

// ---------------------------------------------------------------------------
// GEMM (m97 structure) for the N=2048 GEMMs: C = A @ BT^T
// EPI 0: bf16 C.  EPI 1: fp32 res + C.
// ---------------------------------------------------------------------------
template <int EPI, int BM>
__global__ __launch_bounds__(256)
void gemm_bt(const unsigned short* __restrict__ A,
             const unsigned short* __restrict__ BT,
             unsigned short* __restrict__ outB,
             float* __restrict__ outF,
             const float* __restrict__ res,
             int M, int N, int K)
{
    constexpr int AM = BM / 32;
    constexpr int CAW = BM / 64;
    __shared__ alignas(16) unsigned short As[BM][32];
    __shared__ alignas(16) unsigned short Bs[128][32];

    const int tid  = threadIdx.x;
    const int lane = tid & 63;
    const int wave = tid >> 6;
    const int bm = blockIdx.y * BM;
    const int bn = blockIdx.x * 128;
    const int wm = (wave >> 1) * (BM / 2);
    const int wn = (wave & 1) * 64;
    const int lr = lane & 15;
    const int lg = lane >> 4;
    const int sub = lane >> 2;
    const int cb  = (lane & 3) * 16;

    f32x4 acc[AM][4] = {};

    auto stage = [&](int kt) {
#pragma unroll
        for (int ch = 0; ch < CAW; ++ch) {
            const int rb = wave * (CAW * 16) + ch * 16;
            const void* g = (const char*)(A + (size_t)(bm + rb + sub) * K + kt * 32) + cb;
            gl2lds16(g, &As[rb][0]);
        }
#pragma unroll
        for (int ch = 0; ch < 2; ++ch) {
            const int rb = wave * 32 + ch * 16;
            const void* g = (const char*)(BT + (size_t)(bn + rb + sub) * K + kt * 32) + cb;
            gl2lds16(g, &Bs[rb][0]);
        }
    };

    const int NT = K >> 5;
    for (int kt = 0; kt < NT; ++kt) {
        stage(kt);
        __syncthreads();
        bf16x8 af[AM], bfr[4];
#pragma unroll
        for (int i = 0; i < AM; ++i)
            af[i] = *reinterpret_cast<const bf16x8*>(&As[wm + i * 16 + lr][lg * 8]);
#pragma unroll
        for (int j = 0; j < 4; ++j)
            bfr[j] = *reinterpret_cast<const bf16x8*>(&Bs[wn + j * 16 + lr][lg * 8]);
#pragma unroll
        for (int i = 0; i < AM; ++i)
#pragma unroll
            for (int j = 0; j < 4; ++j)
                acc[i][j] = __builtin_amdgcn_mfma_f32_16x16x32_bf16(af[i], bfr[j], acc[i][j], 0, 0, 0);
        __syncthreads();
    }

#pragma unroll
    for (int i = 0; i < AM; ++i) {
#pragma unroll
        for (int j = 0; j < 4; ++j) {
            const int col = bn + wn + j * 16 + lr;
#pragma unroll
            for (int r = 0; r < 4; ++r) {
                const int row = bm + wm + i * 16 + lg * 4 + r;
                const float v = acc[i][j][r];
                if constexpr (EPI == 0) {
                    outB[(size_t)row * N + col] = f2bf(v);
                } else {
                    outF[(size_t)row * N + col] = res[(size_t)row * N + col] + v;
                }
            }
        }
    }
}

// ---------------------------------------------------------------------------
// RMSNorm: fp32 in [2048][2048] -> bf16 out, weight fp32. One block per row.
// ---------------------------------------------------------------------------
__global__ __launch_bounds__(256)
void rmsnorm_kernel(const float* __restrict__ x, const float* __restrict__ w,
                    unsigned short* __restrict__ out)
{
    const int row = blockIdx.x;
    const int tid = threadIdx.x;
    const float* xr = x + (size_t)row * 2048;
    const float4 a = *reinterpret_cast<const float4*>(xr + tid * 8);
    const float4 b = *reinterpret_cast<const float4*>(xr + tid * 8 + 4);
    float ss = a.x * a.x + a.y * a.y + a.z * a.z + a.w * a.w
             + b.x * b.x + b.y * b.y + b.z * b.z + b.w * b.w;
#pragma unroll
    for (int off = 32; off; off >>= 1) ss += __shfl_xor(ss, off);
    __shared__ float red[4];
    if ((tid & 63) == 0) red[tid >> 6] = ss;
    __syncthreads();
    const float tot = red[0] + red[1] + red[2] + red[3];
    const float sc = rsqrtf(tot * (1.0f / 2048.0f) + 1e-5f);
    const float4 wa = *reinterpret_cast<const float4*>(w + tid * 8);
    const float4 wb = *reinterpret_cast<const float4*>(w + tid * 8 + 4);
    u16x8 o;
    o[0] = f2bf(a.x * sc * wa.x); o[1] = f2bf(a.y * sc * wa.y);
    o[2] = f2bf(a.z * sc * wa.z); o[3] = f2bf(a.w * sc * wa.w);
    o[4] = f2bf(b.x * sc * wb.x); o[5] = f2bf(b.y * sc * wb.y);
    o[6] = f2bf(b.z * sc * wb.z); o[7] = f2bf(b.w * sc * wb.w);
    *reinterpret_cast<u16x8*>(out + (size_t)row * 2048 + tid * 8) = o;
}

// ---------------------------------------------------------------------------
// RoPE in-place on bf16 qkv[2048][6144], first 4096 cols (q and k regions).
// ---------------------------------------------------------------------------
__global__ __launch_bounds__(256)
void rope_kernel(unsigned short* __restrict__ t, const float* __restrict__ cs,
                 const float* __restrict__ sn)
{
    const int idx = blockIdx.x * 256 + threadIdx.x;   // S * 4096 / 8
    const int s   = idx >> 9;
    const int col = (idx & 511) * 8;
    const int i0  = (col & 127) >> 1;
    u16x8 v = *reinterpret_cast<const u16x8*>(t + (size_t)s * 6144 + col);
    const float4 c  = *reinterpret_cast<const float4*>(cs + s * 64 + i0);
    const float4 sv = *reinterpret_cast<const float4*>(sn + s * 64 + i0);
    const float cc[4] = {c.x, c.y, c.z, c.w};
    const float ns[4] = {sv.x, sv.y, sv.z, sv.w};
#pragma unroll
    for (int p = 0; p < 4; ++p) {
        const float re = bf2f(v[2 * p]), im = bf2f(v[2 * p + 1]);
        v[2 * p]     = f2bf(re * cc[p] - im * ns[p]);
        v[2 * p + 1] = f2bf(re * ns[p] + im * cc[p]);
    }
    *reinterpret_cast<u16x8*>(t + (size_t)s * 6144 + col) = v;
}

// ---------------------------------------------------------------------------
// bf16 transpose: out[N][M] = in[M][N]^T (row stride ldin), 64x64 tiles
// ---------------------------------------------------------------------------
__global__ __launch_bounds__(256)
void transpose_bf16(const unsigned short* __restrict__ in,
                    unsigned short* __restrict__ out, int M, int N, int ldin)
{
    __shared__ unsigned short t[64][66];
    const int bm = blockIdx.y * 64, bn = blockIdx.x * 64;
    const int tid = threadIdx.x;
    const int r = tid >> 3, c8 = (tid & 7) * 8;
#pragma unroll
    for (int i = 0; i < 2; ++i) {
        const int row = r + i * 32;
        u16x8 v = *reinterpret_cast<const u16x8*>(in + (size_t)(bm + row) * ldin + bn + c8);
#pragma unroll
        for (int e = 0; e < 8; ++e) t[row][c8 + e] = v[e];
    }
    __syncthreads();
#pragma unroll
    for (int i = 0; i < 2; ++i) {
        const int orow = r + i * 32;
        u16x8 v;
#pragma unroll
        for (int e = 0; e < 8; ++e) v[e] = t[c8 + e][orow];
        *reinterpret_cast<u16x8*>(out + (size_t)(bn + orow) * M + bm + c8) = v;
    }
}

// ---------------------------------------------------------------------------
// Weight convert + transpose: w[K][N] fp32 -> wT[N][K] bf16, 64x64 tiles
// ---------------------------------------------------------------------------
__global__ __launch_bounds__(256)
void convT_kernel(const float* __restrict__ w, unsigned short* __restrict__ wT,
                  int K, int N)
{
    __shared__ unsigned short t[64][66];
    const int bk = blockIdx.y * 64, bn = blockIdx.x * 64;
    const int tid = threadIdx.x;
    const int r = tid >> 4, c4 = (tid & 15) * 4;
#pragma unroll
    for (int i = 0; i < 4; ++i) {
        const int row = r + i * 16;
        const float4 v = *reinterpret_cast<const float4*>(w + (size_t)(bk + row) * N + bn + c4);
        t[row][c4 + 0] = f2bf(v.x); t[row][c4 + 1] = f2bf(v.y);
        t[row][c4 + 2] = f2bf(v.z); t[row][c4 + 3] = f2bf(v.w);
    }
    __syncthreads();
#pragma unroll
    for (int i = 0; i < 4; ++i) {
        const int n = r + i * 16;
        u16x4 o;
#pragma unroll
        for (int e = 0; e < 4; ++e) o[e] = t[c4 + e][n];
        *reinterpret_cast<u16x4*>(wT + (size_t)(bn + n) * K + bk + c4) = o;
    }
}

// ---------------------------------------------------------------------------
// SwiGLU: g[s][f] = silu(t13[s][f]) * t13[s][f+5632]; t13 [2048][11264]
// ---------------------------------------------------------------------------
__global__ __launch_bounds__(256)
void silu_mul_kernel(const unsigned short* __restrict__ t13,
                     unsigned short* __restrict__ g)
{
    const int s  = blockIdx.y;
    const int c8 = (blockIdx.x * 256 + threadIdx.x) * 8;
    if (c8 >= 5632) return;
    const unsigned short* row = t13 + (size_t)s * 11264;
    const u16x8 va = *reinterpret_cast<const u16x8*>(row + c8);
    const u16x8 vb = *reinterpret_cast<const u16x8*>(row + 5632 + c8);
    u16x8 o;
#pragma unroll
    for (int e = 0; e < 8; ++e) {
        const float x = bf2f(va[e]);
        const float y = bf2f(vb[e]);
        const float sv = x / (1.0f + __expf(-x));
        o[e] = f2bf(sv * y);
    }
    *reinterpret_cast<u16x8*>(g + (size_t)s * 5632 + c8) = o;
}

// ---------------------------------------------------------------------------
// Causal flash attention, paired q-tiles for balance.
// Block = (pair i, head): waves 0-3 -> q-tile i, waves 4-7 -> q-tile 31-i.
// K/V double-buffered LDS; issue-early/write-late; ONE barrier per stage.
// ---------------------------------------------------------------------------
__global__ __launch_bounds__(512)
void flash_attn(const unsigned short* __restrict__ q,
                const unsigned short* __restrict__ k,
                const unsigned short* __restrict__ vT,
                unsigned short* __restrict__ attn)
{
    __shared__ alignas(16) unsigned short Ks[2][64][136];  // [buf][kv][hd]
    __shared__ alignas(16) unsigned short Vs[2][128][72];  // [buf][hd][kv]
    __shared__ alignas(16) unsigned short Ps[8][16][72];   // per-wave P

    const int hh = blockIdx.y;
    const int pi = blockIdx.x;              // 0..15
    const int tid = threadIdx.x;
    const int lane = tid & 63, wave = tid >> 6;
    const int qt = (wave >> 2) ? (31 - pi) : pi;
    const int lr = lane & 15, lg = lane >> 4;
    const int q0 = qt * 64 + (wave & 3) * 16;
    const int myNT = qt + 1;                // this group computes kt < myNT
    const int NT   = 32 - pi;               // stages = max(myNT over groups)

    const int kr0 = tid >> 4, kc0 = (tid & 15) * 8;
    const int vr0 = tid >> 3, vc0 = (tid & 7) * 8;

    bf16x8 qf[4];
#pragma unroll
    for (int c = 0; c < 4; ++c)
        qf[c] = *reinterpret_cast<const bf16x8*>(
            q + (size_t)(q0 + lr) * 6144 + hh * 128 + c * 32 + lg * 8);

    f32x4 oacc[8] = {};
    float m_r[4], l_r[4];
#pragma unroll
    for (int r = 0; r < 4; ++r) { m_r[r] = -INFINITY; l_r[r] = 0.0f; }
    const float scale = 0.08838834764831845f;   // 1/sqrt(128)

    u16x8 kreg0, kreg1, vreg0, vreg1;
    auto gload = [&](int kt) {
        const int kv0 = kt * 64;
        kreg0 = *reinterpret_cast<const u16x8*>(k + (size_t)(kv0 + kr0) * 6144 + hh * 128 + kc0);
        kreg1 = *reinterpret_cast<const u16x8*>(k + (size_t)(kv0 + kr0 + 32) * 6144 + hh * 128 + kc0);
        vreg0 = *reinterpret_cast<const u16x8*>(vT + (size_t)(hh * 128 + vr0) * 2048 + kv0 + vc0);
        vreg1 = *reinterpret_cast<const u16x8*>(vT + (size_t)(hh * 128 + vr0 + 64) * 2048 + kv0 + vc0);
    };
    auto lwrite = [&](int buf) {
        *reinterpret_cast<u16x8*>(&Ks[buf][kr0][kc0])      = kreg0;
        *reinterpret_cast<u16x8*>(&Ks[buf][kr0 + 32][kc0]) = kreg1;
        *reinterpret_cast<u16x8*>(&Vs[buf][vr0][vc0])      = vreg0;
        *reinterpret_cast<u16x8*>(&Vs[buf][vr0 + 64][vc0]) = vreg1;
    };

    gload(0); lwrite(0);
    __syncthreads();

    for (int kt = 0; kt < NT; ++kt) {
        const int buf = kt & 1;
        if (kt + 1 < NT) gload(kt + 1);         // issue early

        if (kt < myNT) {
            const int kv0 = kt * 64;
            const bool masked = (kt == myNT - 1);
            f32x4 s[4] = {};
            __builtin_amdgcn_s_setprio(1);
#pragma unroll
            for (int ct = 0; ct < 4; ++ct)
#pragma unroll
                for (int c = 0; c < 4; ++c) {
                    const bf16x8 kf = *reinterpret_cast<const bf16x8*>(
                        &Ks[buf][ct * 16 + lr][c * 32 + lg * 8]);
                    s[ct] = __builtin_amdgcn_mfma_f32_16x16x32_bf16(qf[c], kf, s[ct], 0, 0, 0);
                }
            __builtin_amdgcn_s_setprio(0);
#pragma unroll
            for (int ct = 0; ct < 4; ++ct)
#pragma unroll
                for (int r = 0; r < 4; ++r) {
                    float v = s[ct][r] * scale;
                    if (masked) {
                        const int kvg = kv0 + ct * 16 + lr;
                        const int qg  = q0 + lg * 4 + r;
                        if (kvg > qg) v = -INFINITY;
                    }
                    s[ct][r] = v;
                }
            float mn[4], alpha[4], rs[4];
#pragma unroll
            for (int r = 0; r < 4; ++r) {
                float v = fmaxf(fmaxf(s[0][r], s[1][r]), fmaxf(s[2][r], s[3][r]));
                v = fmaxf(v, __shfl_xor(v, 1));
                v = fmaxf(v, __shfl_xor(v, 2));
                v = fmaxf(v, __shfl_xor(v, 4));
                v = fmaxf(v, __shfl_xor(v, 8));
                mn[r] = fmaxf(m_r[r], v);
                alpha[r] = __expf(m_r[r] - mn[r]);
                m_r[r] = mn[r];
                rs[r] = 0.0f;
            }
#pragma unroll
            for (int ct = 0; ct < 4; ++ct)
#pragma unroll
                for (int r = 0; r < 4; ++r) {
                    const float p = __expf(s[ct][r] - mn[r]);
                    s[ct][r] = p;
                    rs[r] += p;
                }
#pragma unroll
            for (int r = 0; r < 4; ++r) {
                float t2 = rs[r];
                t2 += __shfl_xor(t2, 1);
                t2 += __shfl_xor(t2, 2);
                t2 += __shfl_xor(t2, 4);
                t2 += __shfl_xor(t2, 8);
                l_r[r] = l_r[r] * alpha[r] + t2;
            }
#pragma unroll
            for (int ot = 0; ot < 8; ++ot)
#pragma unroll
                for (int r = 0; r < 4; ++r) oacc[ot][r] *= alpha[r];

#pragma unroll
            for (int ct = 0; ct < 4; ++ct)
#pragma unroll
                for (int r = 0; r < 4; ++r)
                    Ps[wave][lg * 4 + r][ct * 16 + lr] = f2bf(s[ct][r]);

            __builtin_amdgcn_s_setprio(1);
#pragma unroll
            for (int c2 = 0; c2 < 2; ++c2) {
                const bf16x8 pf = *reinterpret_cast<const bf16x8*>(
                    &Ps[wave][lr][c2 * 32 + lg * 8]);
#pragma unroll
                for (int ot = 0; ot < 8; ++ot) {
                    const bf16x8 vf = *reinterpret_cast<const bf16x8*>(
                        &Vs[buf][ot * 16 + lr][c2 * 32 + lg * 8]);
                    oacc[ot] = __builtin_amdgcn_mfma_f32_16x16x32_bf16(pf, vf, oacc[ot], 0, 0, 0);
                }
            }
            __builtin_amdgcn_s_setprio(0);
        }

        if (kt + 1 < NT) lwrite(buf ^ 1);       // write late (other buffer)
        __syncthreads();
    }

#pragma unroll
    for (int ot = 0; ot < 8; ++ot)
#pragma unroll
        for (int r = 0; r < 4; ++r) {
            const float v = oacc[ot][r] / l_r[r];
            attn[(size_t)(q0 + lg * 4 + r) * 2048 + hh * 128 + ot * 16 + lr] = f2bf(v);
        }
}

// ---------------------------------------------------------------------------
extern "C" void kernel_launch(void* const* d_in, const int* in_sizes, int n_in,
                              void* d_out, int out_size, void* d_ws, size_t ws_size,
                              hipStream_t stream)
{
    const float* x    = (const float*)d_in[0];
    const float* fcos = (const float*)d_in[1];
    const float* fsin = (const float*)d_in[2];
    // d_in[3] = mask (causal, hardcoded)
    const float* wq  = (const float*)d_in[4];
    const float* wk  = (const float*)d_in[5];
    const float* wv  = (const float*)d_in[6];
    const float* wo  = (const float*)d_in[7];
    const float* w1  = (const float*)d_in[8];
    const float* w2  = (const float*)d_in[9];
    const float* w3  = (const float*)d_in[10];
    const float* anw = (const float*)d_in[11];
    const float* fnw = (const float*)d_in[12];
    float* out = (float*)d_out;

    char* ws = (char*)d_ws;
    size_t off = 0;
    auto alloc = [&](size_t bytes) { void* p = ws + off; off += bytes; return p; };
    const size_t SZ_DD = (size_t)2048 * 2048 * 2;   // 8 MiB
    const size_t SZ_DF = (size_t)2048 * 5632 * 2;   // 22 MiB

    unsigned short* wqT = (unsigned short*)alloc(SZ_DD);
    unsigned short* wkT = (unsigned short*)alloc(SZ_DD);
    unsigned short* wvT = (unsigned short*)alloc(SZ_DD);
    unsigned short* woT = (unsigned short*)alloc(SZ_DD);
    unsigned short* w1T = (unsigned short*)alloc(SZ_DF);
    unsigned short* w3T = (unsigned short*)alloc(SZ_DF);
    unsigned short* w2T = (unsigned short*)alloc(SZ_DF);

    // region1 (48 MiB): attn phase = xn | qkv | vT | attn ; FFN phase = t13
    char* reg1 = (char*)alloc((size_t)48 * 1024 * 1024);
    unsigned short* xn   = (unsigned short*)reg1;
    unsigned short* qkv  = (unsigned short*)(reg1 + SZ_DD);            // [2048][6144]
    unsigned short* vTb  = (unsigned short*)(reg1 + SZ_DD + 3 * SZ_DD);
    unsigned short* ab   = (unsigned short*)(reg1 + SZ_DD + 4 * SZ_DD);
    unsigned short* t13  = (unsigned short*)reg1;                      // [2048][11264]

    char* reg2 = (char*)alloc(SZ_DF);
    unsigned short* hn = (unsigned short*)reg2;
    unsigned short* t1 = (unsigned short*)reg2;

    // weight fp32 -> bf16 transposed
    convT_kernel<<<dim3(32, 32), 256, 0, stream>>>(wq, wqT, 2048, 2048);
    convT_kernel<<<dim3(32, 32), 256, 0, stream>>>(wk, wkT, 2048, 2048);
    convT_kernel<<<dim3(32, 32), 256, 0, stream>>>(wv, wvT, 2048, 2048);
    convT_kernel<<<dim3(32, 32), 256, 0, stream>>>(wo, woT, 2048, 2048);
    convT_kernel<<<dim3(88, 32), 256, 0, stream>>>(w1, w1T, 2048, 5632);
    convT_kernel<<<dim3(88, 32), 256, 0, stream>>>(w3, w3T, 2048, 5632);
    convT_kernel<<<dim3(32, 88), 256, 0, stream>>>(w2, w2T, 5632, 2048);

    // attention block
    rmsnorm_kernel<<<2048, 256, 0, stream>>>(x, anw, xn);
    gemm256_bt<<<dim3(24, 8), 512, 0, stream>>>(xn, wqT, qkv, 2048, 6144, 2048);
    rope_kernel<<<4096, 256, 0, stream>>>(qkv, fcos, fsin);
    transpose_bf16<<<dim3(32, 32), 256, 0, stream>>>(qkv + 4096, vTb, 2048, 2048, 6144);
    flash_attn<<<dim3(16, 16), 512, 0, stream>>>(qkv, qkv + 2048, vTb, ab);
    gemm_bt<1, 64><<<dim3(16, 32), 256, 0, stream>>>(ab, woT, nullptr, out, x, 2048, 2048, 2048);

    // FFN block
    rmsnorm_kernel<<<2048, 256, 0, stream>>>(out, fnw, hn);
    gemm256_bt<<<dim3(44, 8), 512, 0, stream>>>(hn, w1T, t13, 2048, 11264, 2048);
    silu_mul_kernel<<<dim3(3, 2048), 256, 0, stream>>>(t13, t1);
    gemm_bt<1, 64><<<dim3(16, 32), 256, 0, stream>>>(t1, w2T, nullptr, out, out, 2048, 2048, 5632);
}

// Round 5
// 474.513 us; speedup vs baseline: 1.4234x; 1.0291x over previous
//
#include <hip/hip_runtime.h>
#include <hip/hip_bf16.h>

typedef __bf16 bf16x8 __attribute__((ext_vector_type(8)));
typedef float f32x4 __attribute__((ext_vector_type(4)));
typedef unsigned short u16x8 __attribute__((ext_vector_type(8)));
typedef unsigned short u16x4 __attribute__((ext_vector_type(4)));

#define DEV static __device__ __forceinline__

DEV unsigned short f2bf(float f) {
    unsigned u = __builtin_bit_cast(unsigned, f);
    u += 0x7fffu + ((u >> 16) & 1u);   // round-to-nearest-even
    return (unsigned short)(u >> 16);
}
DEV float bf2f(unsigned short h) {
    unsigned u = ((unsigned)h) << 16;
    return __builtin_bit_cast(float, u);
}

DEV void gl2lds16(const void* g, void* l) {
    __builtin_amdgcn_global_load_lds(
        (const __attribute__((address_space(1))) void*)g,
        (__attribute__((address_space(3))) void*)l, 16, 0, 0);
}

// ===========================================================================
// 256x256 8-phase counted-vmcnt GEMM (T1+T2+T3+T4+T5).
// C[M,N] = A[M,K](bf16) @ BT[N,K](bf16)^T
// 512 thr = 8 waves (2M x 4N); per-wave 128x64 C (acc[8][4]); BK=64.
// LDS 128KB: 2 dbuf x 4 slots [A0,B0,A1,B1] x 16KB ([128 rows][64 bf16]).
// Swizzle: phys_byte = log_byte ^ ((row&7)<<4), both-sides (pre-swizzled
// global source for global_load_lds + swizzled ds_read).
// vmcnt(6) at p0/p1/p2, none at p3; raw s_barrier (never drain vmcnt to 0).
// XCD swizzle: bn-major chunked, requires nwg%8==0 and gridDim.y==8 (M=2048).
// `koff` = K-offset (0 for full-K; kz*Ksplit for split-K).
// ===========================================================================
#define STAGE256(KT, SLOT, BUF)                                               \
    {                                                                         \
        const unsigned short* sbase = ((SLOT) & 1)                            \
            ? BT + (size_t)(bn + ((SLOT) >> 1) * 128) * K                     \
            : A  + (size_t)(bm + ((SLOT) >> 1) * 128) * K;                    \
        _Pragma("unroll")                                                     \
        for (int j = 0; j < 2; ++j) {                                         \
            const unsigned short* g = sbase + (size_t)(srow + j * 64) * K     \
                                      + koff + (KT) * 64 + lc;                \
            gl2lds16(g, &lds[BUF][SLOT][wave * 512 + j * 4096]);              \
        }                                                                     \
    }

#define COMPUTE256(BUF, MH, NH)                                               \
    {                                                                         \
        const char* Ab = (const char*)&lds[BUF][(MH) * 2][0];                 \
        const char* Bb = (const char*)&lds[BUF][(NH) * 2 + 1][0];             \
        bf16x8 a_[4][2], b_[2][2];                                            \
        _Pragma("unroll")                                                     \
        for (int m4 = 0; m4 < 4; ++m4) {                                      \
            _Pragma("unroll")                                                 \
            for (int kk = 0; kk < 2; ++kk)                                    \
                a_[m4][kk] = *(const bf16x8*)(Ab +                            \
                    (wm * 64 + m4 * 16 + lr) * 128 +                          \
                    ((kk * 64 + lg * 16) ^ xsw));                             \
        }                                                                     \
        _Pragma("unroll")                                                     \
        for (int n2 = 0; n2 < 2; ++n2) {                                      \
            _Pragma("unroll")                                                 \
            for (int kk = 0; kk < 2; ++kk)                                    \
                b_[n2][kk] = *(const bf16x8*)(Bb +                            \
                    (wn * 32 + n2 * 16 + lr) * 128 +                          \
                    ((kk * 64 + lg * 16) ^ xsw));                             \
        }                                                                     \
        __builtin_amdgcn_s_setprio(1);                                        \
        _Pragma("unroll")                                                     \
        for (int m4 = 0; m4 < 4; ++m4)                                        \
            _Pragma("unroll")                                                 \
            for (int n2 = 0; n2 < 2; ++n2)                                    \
                _Pragma("unroll")                                             \
                for (int kk = 0; kk < 2; ++kk)                                \
                    acc[(MH) * 4 + m4][(NH) * 2 + n2] =                       \
                        __builtin_amdgcn_mfma_f32_16x16x32_bf16(              \
                            a_[m4][kk], b_[n2][kk],                           \
                            acc[(MH) * 4 + m4][(NH) * 2 + n2], 0, 0, 0);      \
        __builtin_amdgcn_s_setprio(0);                                        \
    }

#define WAITV(N) asm volatile("s_waitcnt vmcnt(" #N ")" ::: "memory")
#define SBAR()   asm volatile("s_barrier" ::: "memory")

#define GEMM256_PREAMBLE                                                      \
    const int tid  = threadIdx.x;                                             \
    const int lane = tid & 63;                                                \
    const int wave = tid >> 6;                                                \
    const int wm = wave >> 2;                                                 \
    const int wn = wave & 3;                                                  \
    const int lr = lane & 15;                                                 \
    const int lg = lane >> 4;                                                 \
    const int lin = blockIdx.y * gridDim.x + blockIdx.x;                      \
    const int cpx = (gridDim.x * gridDim.y) >> 3;                             \
    const int swz = (lin & 7) * cpx + (lin >> 3);                             \
    const int bm = (swz & 7) * 256;      /* gridDim.y == 8 (M = 2048) */      \
    const int bn = (swz >> 3) * 256;                                          \
    const int xsw  = (lr & 7) << 4;                                           \
    const int srow = tid >> 3;                                                \
    const int lc   = ((tid & 7) ^ (srow & 7)) * 8;

#define GEMM256_MAINLOOP                                                      \
    STAGE256(0, 0, 0); STAGE256(0, 1, 0); STAGE256(0, 2, 0); STAGE256(0, 3, 0);\
    for (int kt = 0; kt < NT - 1; ++kt) {                                     \
        const int buf = kt & 1, nbuf = buf ^ 1;                               \
        STAGE256(kt + 1, 0, nbuf);                                            \
        WAITV(6); SBAR();                                                     \
        COMPUTE256(buf, 0, 0);                                                \
        STAGE256(kt + 1, 1, nbuf);                                            \
        WAITV(6); SBAR();                                                     \
        COMPUTE256(buf, 1, 0);                                                \
        STAGE256(kt + 1, 2, nbuf);                                            \
        WAITV(6); SBAR();                                                     \
        COMPUTE256(buf, 1, 1);                                                \
        STAGE256(kt + 1, 3, nbuf);                                            \
        COMPUTE256(buf, 0, 1);                                                \
        SBAR();                                                               \
    }                                                                         \
    {                                                                         \
        const int buf = (NT - 1) & 1;                                         \
        WAITV(4); SBAR();                                                     \
        COMPUTE256(buf, 0, 0);                                                \
        WAITV(2); SBAR();                                                     \
        COMPUTE256(buf, 1, 0);                                                \
        WAITV(0); SBAR();                                                     \
        COMPUTE256(buf, 1, 1);                                                \
        COMPUTE256(buf, 0, 1);                                                \
    }

__global__ __launch_bounds__(512, 2)
void gemm256_bt(const unsigned short* __restrict__ A,
                const unsigned short* __restrict__ BT,
                unsigned short* __restrict__ outB,
                int M, int N, int K)
{
    __shared__ alignas(16) unsigned short lds[2][4][8192];   // 128 KiB
    GEMM256_PREAMBLE
    const int koff = 0;
    f32x4 acc[8][4] = {};
    const int NT = K >> 6;

    GEMM256_MAINLOOP

#pragma unroll
    for (int m = 0; m < 8; ++m) {
        const int row = bm + (m >> 2) * 128 + wm * 64 + (m & 3) * 16 + lg * 4;
#pragma unroll
        for (int n = 0; n < 4; ++n) {
            const int col = bn + (n >> 1) * 128 + wn * 32 + (n & 1) * 16 + lr;
#pragma unroll
            for (int r = 0; r < 4; ++r)
                outB[(size_t)(row + r) * N + col] = f2bf(acc[m][n][r]);
        }
    }
}

// Split-K=2 variant: blockIdx.z = kz; writes fp32 partials outP[kz][M][N].
__global__ __launch_bounds__(512, 2)
void gemm256_splitk(const unsigned short* __restrict__ A,
                    const unsigned short* __restrict__ BT,
                    float* __restrict__ outP,
                    int M, int N, int K)
{
    __shared__ alignas(16) unsigned short lds[2][4][8192];   // 128 KiB
    GEMM256_PREAMBLE
    const int Kh = K >> 1;
    const int koff = blockIdx.z * Kh;
    f32x4 acc[8][4] = {};
    const int NT = Kh >> 6;

    GEMM256_MAINLOOP

    float* P = outP + (size_t)blockIdx.z * M * N;
#pragma unroll
    for (int m = 0; m < 8; ++m) {
        const int row = bm + (m >> 2) * 128 + wm * 64 + (m & 3) * 16 + lg * 4;
#pragma unroll
        for (int n = 0; n < 4; ++n) {
            const int col = bn + (n >> 1) * 128 + wn * 32 + (n & 1) * 16 + lr;
#pragma unroll
            for (int r = 0; r < 4; ++r)
                P[(size_t)(row + r) * N + col] = acc[m][n][r];
        }
    }
}

// out = res + p[0] + p[1]   (all fp32, n4 float4 elements)
__global__ __launch_bounds__(256)
void reduce2_add(const float* res, const float* p, float* out, int n4)
{
    const float4* r4 = (const float4*)res;
    const float4* a4 = (const float4*)p;
    const float4* b4 = (const float4*)(p + (size_t)2048 * 2048);
    float4* o4 = (float4*)out;
    for (int i = blockIdx.x * 256 + threadIdx.x; i < n4; i += gridDim.x * 256) {
        const float4 r = r4[i], a = a4[i], b = b4[i];
        o4[i] = make_float4(r.x + a.x + b.x, r.y + a.y + b.y,
                            r.z + a.z + b.z, r.w + a.w + b.w);
    }
}

// ---------------------------------------------------------------------------
// RMSNorm: fp32 in [2048][2048] -> bf16 out, weight fp32. One block per row.
// ---------------------------------------------------------------------------
__global__ __launch_bounds__(256)
void rmsnorm_kernel(const float* __restrict__ x, const float* __restrict__ w,
                    unsigned short* __restrict__ out)
{
    const int row = blockIdx.x;
    const int tid = threadIdx.x;
    const float* xr = x + (size_t)row * 2048;
    const float4 a = *reinterpret_cast<const float4*>(xr + tid * 8);
    const float4 b = *reinterpret_cast<const float4*>(xr + tid * 8 + 4);
    float ss = a.x * a.x + a.y * a.y + a.z * a.z + a.w * a.w
             + b.x * b.x + b.y * b.y + b.z * b.z + b.w * b.w;
#pragma unroll
    for (int off = 32; off; off >>= 1) ss += __shfl_xor(ss, off);
    __shared__ float red[4];
    if ((tid & 63) == 0) red[tid >> 6] = ss;
    __syncthreads();
    const float tot = red[0] + red[1] + red[2] + red[3];
    const float sc = rsqrtf(tot * (1.0f / 2048.0f) + 1e-5f);
    const float4 wa = *reinterpret_cast<const float4*>(w + tid * 8);
    const float4 wb = *reinterpret_cast<const float4*>(w + tid * 8 + 4);
    u16x8 o;
    o[0] = f2bf(a.x * sc * wa.x); o[1] = f2bf(a.y * sc * wa.y);
    o[2] = f2bf(a.z * sc * wa.z); o[3] = f2bf(a.w * sc * wa.w);
    o[4] = f2bf(b.x * sc * wb.x); o[5] = f2bf(b.y * sc * wb.y);
    o[6] = f2bf(b.z * sc * wb.z); o[7] = f2bf(b.w * sc * wb.w);
    *reinterpret_cast<u16x8*>(out + (size_t)row * 2048 + tid * 8) = o;
}

// ---------------------------------------------------------------------------
// RoPE in-place on bf16 qkv[2048][6144], first 4096 cols (q and k regions).
// ---------------------------------------------------------------------------
__global__ __launch_bounds__(256)
void rope_kernel(unsigned short* __restrict__ t, const float* __restrict__ cs,
                 const float* __restrict__ sn)
{
    const int idx = blockIdx.x * 256 + threadIdx.x;   // S * 4096 / 8
    const int s   = idx >> 9;
    const int col = (idx & 511) * 8;
    const int i0  = (col & 127) >> 1;
    u16x8 v = *reinterpret_cast<const u16x8*>(t + (size_t)s * 6144 + col);
    const float4 c  = *reinterpret_cast<const float4*>(cs + s * 64 + i0);
    const float4 sv = *reinterpret_cast<const float4*>(sn + s * 64 + i0);
    const float cc[4] = {c.x, c.y, c.z, c.w};
    const float ns[4] = {sv.x, sv.y, sv.z, sv.w};
#pragma unroll
    for (int p = 0; p < 4; ++p) {
        const float re = bf2f(v[2 * p]), im = bf2f(v[2 * p + 1]);
        v[2 * p]     = f2bf(re * cc[p] - im * ns[p]);
        v[2 * p + 1] = f2bf(re * ns[p] + im * cc[p]);
    }
    *reinterpret_cast<u16x8*>(t + (size_t)s * 6144 + col) = v;
}

// ---------------------------------------------------------------------------
// bf16 transpose: out[N][M] = in[M][N]^T (row stride ldin), 64x64 tiles
// ---------------------------------------------------------------------------
__global__ __launch_bounds__(256)
void transpose_bf16(const unsigned short* __restrict__ in,
                    unsigned short* __restrict__ out, int M, int N, int ldin)
{
    __shared__ unsigned short t[64][66];
    const int bm = blockIdx.y * 64, bn = blockIdx.x * 64;
    const int tid = threadIdx.x;
    const int r = tid >> 3, c8 = (tid & 7) * 8;
#pragma unroll
    for (int i = 0; i < 2; ++i) {
        const int row = r + i * 32;
        u16x8 v = *reinterpret_cast<const u16x8*>(in + (size_t)(bm + row) * ldin + bn + c8);
#pragma unroll
        for (int e = 0; e < 8; ++e) t[row][c8 + e] = v[e];
    }
    __syncthreads();
#pragma unroll
    for (int i = 0; i < 2; ++i) {
        const int orow = r + i * 32;
        u16x8 v;
#pragma unroll
        for (int e = 0; e < 8; ++e) v[e] = t[c8 + e][orow];
        *reinterpret_cast<u16x8*>(out + (size_t)(bn + orow) * M + bm + c8) = v;
    }
}

// ---------------------------------------------------------------------------
// Weight convert + transpose: w[K][N] fp32 -> wT[N][K] bf16, 64x64 tiles
// ---------------------------------------------------------------------------
__global__ __launch_bounds__(256)
void convT_kernel(const float* __restrict__ w, unsigned short* __restrict__ wT,
                  int K, int N)
{
    __shared__ unsigned short t[64][66];
    const int bk = blockIdx.y * 64, bn = blockIdx.x * 64;
    const int tid = threadIdx.x;
    const int r = tid >> 4, c4 = (tid & 15) * 4;
#pragma unroll
    for (int i = 0; i < 4; ++i) {
        const int row = r + i * 16;
        const float4 v = *reinterpret_cast<const float4*>(w + (size_t)(bk + row) * N + bn + c4);
        t[row][c4 + 0] = f2bf(v.x); t[row][c4 + 1] = f2bf(v.y);
        t[row][c4 + 2] = f2bf(v.z); t[row][c4 + 3] = f2bf(v.w);
    }
    __syncthreads();
#pragma unroll
    for (int i = 0; i < 4; ++i) {
        const int n = r + i * 16;
        u16x4 o;
#pragma unroll
        for (int e = 0; e < 4; ++e) o[e] = t[c4 + e][n];
        *reinterpret_cast<u16x4*>(wT + (size_t)(bn + n) * K + bk + c4) = o;
    }
}

// ---------------------------------------------------------------------------
// SwiGLU: g[s][f] = silu(t13[s][f]) * t13[s][f+5632]; t13 [2048][11264]
// ---------------------------------------------------------------------------
__global__ __launch_bounds__(256)
void silu_mul_kernel(const unsigned short* __restrict__ t13,
                     unsigned short* __restrict__ g)
{
    const int s  = blockIdx.y;
    const int c8 = (blockIdx.x * 256 + threadIdx.x) * 8;
    if (c8 >= 5632) return;
    const unsigned short* row = t13 + (size_t)s * 11264;
    const u16x8 va = *reinterpret_cast<const u16x8*>(row + c8);
    const u16x8 vb = *reinterpret_cast<const u16x8*>(row + 5632 + c8);
    u16x8 o;
#pragma unroll
    for (int e = 0; e < 8; ++e) {
        const float x = bf2f(va[e]);
        const float y = bf2f(vb[e]);
        const float sv = x / (1.0f + __expf(-x));
        o[e] = f2bf(sv * y);
    }
    *reinterpret_cast<u16x8*>(g + (size_t)s * 5632 + c8) = o;
}

// ---------------------------------------------------------------------------
// Causal flash attention, paired q-tiles for balance.
// Block = (pair i, head): waves 0-3 -> q-tile i, waves 4-7 -> q-tile 31-i.
// K/V double-buffered LDS; issue-early/write-late; ONE barrier per stage.
// ---------------------------------------------------------------------------
__global__ __launch_bounds__(512)
void flash_attn(const unsigned short* __restrict__ q,
                const unsigned short* __restrict__ k,
                const unsigned short* __restrict__ vT,
                unsigned short* __restrict__ attn)
{
    __shared__ alignas(16) unsigned short Ks[2][64][136];  // [buf][kv][hd]
    __shared__ alignas(16) unsigned short Vs[2][128][72];  // [buf][hd][kv]
    __shared__ alignas(16) unsigned short Ps[8][16][72];   // per-wave P

    const int hh = blockIdx.y;
    const int pi = blockIdx.x;              // 0..15
    const int tid = threadIdx.x;
    const int lane = tid & 63, wave = tid >> 6;
    const int qt = (wave >> 2) ? (31 - pi) : pi;
    const int lr = lane & 15, lg = lane >> 4;
    const int q0 = qt * 64 + (wave & 3) * 16;
    const int myNT = qt + 1;                // this group computes kt < myNT
    const int NT   = 32 - pi;               // stages = max(myNT over groups)

    const int kr0 = tid >> 4, kc0 = (tid & 15) * 8;
    const int vr0 = tid >> 3, vc0 = (tid & 7) * 8;

    bf16x8 qf[4];
#pragma unroll
    for (int c = 0; c < 4; ++c)
        qf[c] = *reinterpret_cast<const bf16x8*>(
            q + (size_t)(q0 + lr) * 6144 + hh * 128 + c * 32 + lg * 8);

    f32x4 oacc[8] = {};
    float m_r[4], l_r[4];
#pragma unroll
    for (int r = 0; r < 4; ++r) { m_r[r] = -INFINITY; l_r[r] = 0.0f; }
    const float scale = 0.08838834764831845f;   // 1/sqrt(128)

    u16x8 kreg0, kreg1, vreg0, vreg1;
    auto gload = [&](int kt) {
        const int kv0 = kt * 64;
        kreg0 = *reinterpret_cast<const u16x8*>(k + (size_t)(kv0 + kr0) * 6144 + hh * 128 + kc0);
        kreg1 = *reinterpret_cast<const u16x8*>(k + (size_t)(kv0 + kr0 + 32) * 6144 + hh * 128 + kc0);
        vreg0 = *reinterpret_cast<const u16x8*>(vT + (size_t)(hh * 128 + vr0) * 2048 + kv0 + vc0);
        vreg1 = *reinterpret_cast<const u16x8*>(vT + (size_t)(hh * 128 + vr0 + 64) * 2048 + kv0 + vc0);
    };
    auto lwrite = [&](int buf) {
        *reinterpret_cast<u16x8*>(&Ks[buf][kr0][kc0])      = kreg0;
        *reinterpret_cast<u16x8*>(&Ks[buf][kr0 + 32][kc0]) = kreg1;
        *reinterpret_cast<u16x8*>(&Vs[buf][vr0][vc0])      = vreg0;
        *reinterpret_cast<u16x8*>(&Vs[buf][vr0 + 64][vc0]) = vreg1;
    };

    gload(0); lwrite(0);
    __syncthreads();

    for (int kt = 0; kt < NT; ++kt) {
        const int buf = kt & 1;
        if (kt + 1 < NT) gload(kt + 1);         // issue early

        if (kt < myNT) {
            const int kv0 = kt * 64;
            const bool masked = (kt == myNT - 1);
            f32x4 s[4] = {};
            __builtin_amdgcn_s_setprio(1);
#pragma unroll
            for (int ct = 0; ct < 4; ++ct)
#pragma unroll
                for (int c = 0; c < 4; ++c) {
                    const bf16x8 kf = *reinterpret_cast<const bf16x8*>(
                        &Ks[buf][ct * 16 + lr][c * 32 + lg * 8]);
                    s[ct] = __builtin_amdgcn_mfma_f32_16x16x32_bf16(qf[c], kf, s[ct], 0, 0, 0);
                }
            __builtin_amdgcn_s_setprio(0);
#pragma unroll
            for (int ct = 0; ct < 4; ++ct)
#pragma unroll
                for (int r = 0; r < 4; ++r) {
                    float v = s[ct][r] * scale;
                    if (masked) {
                        const int kvg = kv0 + ct * 16 + lr;
                        const int qg  = q0 + lg * 4 + r;
                        if (kvg > qg) v = -INFINITY;
                    }
                    s[ct][r] = v;
                }
            float mn[4], alpha[4], rs[4];
#pragma unroll
            for (int r = 0; r < 4; ++r) {
                float v = fmaxf(fmaxf(s[0][r], s[1][r]), fmaxf(s[2][r], s[3][r]));
                v = fmaxf(v, __shfl_xor(v, 1));
                v = fmaxf(v, __shfl_xor(v, 2));
                v = fmaxf(v, __shfl_xor(v, 4));
                v = fmaxf(v, __shfl_xor(v, 8));
                mn[r] = fmaxf(m_r[r], v);
                alpha[r] = __expf(m_r[r] - mn[r]);
                m_r[r] = mn[r];
                rs[r] = 0.0f;
            }
#pragma unroll
            for (int ct = 0; ct < 4; ++ct)
#pragma unroll
                for (int r = 0; r < 4; ++r) {
                    const float p = __expf(s[ct][r] - mn[r]);
                    s[ct][r] = p;
                    rs[r] += p;
                }
#pragma unroll
            for (int r = 0; r < 4; ++r) {
                float t2 = rs[r];
                t2 += __shfl_xor(t2, 1);
                t2 += __shfl_xor(t2, 2);
                t2 += __shfl_xor(t2, 4);
                t2 += __shfl_xor(t2, 8);
                l_r[r] = l_r[r] * alpha[r] + t2;
            }
#pragma unroll
            for (int ot = 0; ot < 8; ++ot)
#pragma unroll
                for (int r = 0; r < 4; ++r) oacc[ot][r] *= alpha[r];

#pragma unroll
            for (int ct = 0; ct < 4; ++ct)
#pragma unroll
                for (int r = 0; r < 4; ++r)
                    Ps[wave][lg * 4 + r][ct * 16 + lr] = f2bf(s[ct][r]);

            __builtin_amdgcn_s_setprio(1);
#pragma unroll
            for (int c2 = 0; c2 < 2; ++c2) {
                const bf16x8 pf = *reinterpret_cast<const bf16x8*>(
                    &Ps[wave][lr][c2 * 32 + lg * 8]);
#pragma unroll
                for (int ot = 0; ot < 8; ++ot) {
                    const bf16x8 vf = *reinterpret_cast<const bf16x8*>(
                        &Vs[buf][ot * 16 + lr][c2 * 32 + lg * 8]);
                    oacc[ot] = __builtin_amdgcn_mfma_f32_16x16x32_bf16(pf, vf, oacc[ot], 0, 0, 0);
                }
            }
            __builtin_amdgcn_s_setprio(0);
        }

        if (kt + 1 < NT) lwrite(buf ^ 1);       // write late (other buffer)
        __syncthreads();
    }

#pragma unroll
    for (int ot = 0; ot < 8; ++ot)
#pragma unroll
        for (int r = 0; r < 4; ++r) {
            const float v = oacc[ot][r] / l_r[r];
            attn[(size_t)(q0 + lg * 4 + r) * 2048 + hh * 128 + ot * 16 + lr] = f2bf(v);
        }
}

// ---------------------------------------------------------------------------
extern "C" void kernel_launch(void* const* d_in, const int* in_sizes, int n_in,
                              void* d_out, int out_size, void* d_ws, size_t ws_size,
                              hipStream_t stream)
{
    const float* x    = (const float*)d_in[0];
    const float* fcos = (const float*)d_in[1];
    const float* fsin = (const float*)d_in[2];
    // d_in[3] = mask (causal, hardcoded)
    const float* wq  = (const float*)d_in[4];
    const float* wk  = (const float*)d_in[5];
    const float* wv  = (const float*)d_in[6];
    const float* wo  = (const float*)d_in[7];
    const float* w1  = (const float*)d_in[8];
    const float* w2  = (const float*)d_in[9];
    const float* w3  = (const float*)d_in[10];
    const float* anw = (const float*)d_in[11];
    const float* fnw = (const float*)d_in[12];
    float* out = (float*)d_out;

    char* ws = (char*)d_ws;
    size_t off = 0;
    auto alloc = [&](size_t bytes) { void* p = ws + off; off += bytes; return p; };
    const size_t SZ_DD = (size_t)2048 * 2048 * 2;   // 8 MiB
    const size_t SZ_DF = (size_t)2048 * 5632 * 2;   // 22 MiB

    unsigned short* wqT = (unsigned short*)alloc(SZ_DD);
    unsigned short* wkT = (unsigned short*)alloc(SZ_DD);
    unsigned short* wvT = (unsigned short*)alloc(SZ_DD);
    unsigned short* woT = (unsigned short*)alloc(SZ_DD);
    unsigned short* w1T = (unsigned short*)alloc(SZ_DF);
    unsigned short* w3T = (unsigned short*)alloc(SZ_DF);
    unsigned short* w2T = (unsigned short*)alloc(SZ_DF);

    // region1 (48 MiB), attn phase: xn | qkv | vT | ab ; also hosts the
    // 32 MiB fp32 split-K partials (pk, offsets 0-32 MiB) when those regions
    // are dead; FFN phase: t13 (44 MiB).
    char* reg1 = (char*)alloc((size_t)48 * 1024 * 1024);
    unsigned short* xn   = (unsigned short*)reg1;
    unsigned short* qkv  = (unsigned short*)(reg1 + SZ_DD);            // [2048][6144]
    unsigned short* vTb  = (unsigned short*)(reg1 + SZ_DD + 3 * SZ_DD);
    unsigned short* ab   = (unsigned short*)(reg1 + SZ_DD + 4 * SZ_DD);
    unsigned short* t13  = (unsigned short*)reg1;                      // [2048][11264]
    float*          pk   = (float*)reg1;                               // [2][2048][2048] f32

    char* reg2 = (char*)alloc(SZ_DF);
    unsigned short* hn = (unsigned short*)reg2;
    unsigned short* t1 = (unsigned short*)reg2;

    const int N4 = 2048 * 2048 / 4;

    // weight fp32 -> bf16 transposed
    convT_kernel<<<dim3(32, 32), 256, 0, stream>>>(wq, wqT, 2048, 2048);
    convT_kernel<<<dim3(32, 32), 256, 0, stream>>>(wk, wkT, 2048, 2048);
    convT_kernel<<<dim3(32, 32), 256, 0, stream>>>(wv, wvT, 2048, 2048);
    convT_kernel<<<dim3(32, 32), 256, 0, stream>>>(wo, woT, 2048, 2048);
    convT_kernel<<<dim3(88, 32), 256, 0, stream>>>(w1, w1T, 2048, 5632);
    convT_kernel<<<dim3(88, 32), 256, 0, stream>>>(w3, w3T, 2048, 5632);
    convT_kernel<<<dim3(32, 88), 256, 0, stream>>>(w2, w2T, 5632, 2048);

    // attention block
    rmsnorm_kernel<<<2048, 256, 0, stream>>>(x, anw, xn);
    gemm256_bt<<<dim3(24, 8), 512, 0, stream>>>(xn, wqT, qkv, 2048, 6144, 2048);
    rope_kernel<<<4096, 256, 0, stream>>>(qkv, fcos, fsin);
    transpose_bf16<<<dim3(32, 32), 256, 0, stream>>>(qkv + 4096, vTb, 2048, 2048, 6144);
    flash_attn<<<dim3(16, 16), 512, 0, stream>>>(qkv, qkv + 2048, vTb, ab);
    // Wo via split-K=2 (xn/qkv/vT dead -> pk overlays reg1[0..32MB], ab at +40MB safe)
    gemm256_splitk<<<dim3(8, 8, 2), 512, 0, stream>>>(ab, woT, pk, 2048, 2048, 2048);
    reduce2_add<<<2048, 256, 0, stream>>>(x, pk, out, N4);   // h = x + attn@Wo

    // FFN block
    rmsnorm_kernel<<<2048, 256, 0, stream>>>(out, fnw, hn);
    gemm256_bt<<<dim3(44, 8), 512, 0, stream>>>(hn, w1T, t13, 2048, 11264, 2048);
    silu_mul_kernel<<<dim3(3, 2048), 256, 0, stream>>>(t13, t1);
    // W2 via split-K=2 (t13 dead -> pk overlays reg1)
    gemm256_splitk<<<dim3(8, 8, 2), 512, 0, stream>>>(t1, w2T, pk, 2048, 2048, 5632);
    reduce2_add<<<2048, 256, 0, stream>>>(out, pk, out, N4); // out = h + ff
}

// Round 6
// 450.567 us; speedup vs baseline: 1.4991x; 1.0531x over previous
//
#include <hip/hip_runtime.h>
#include <hip/hip_bf16.h>

typedef __bf16 bf16x8 __attribute__((ext_vector_type(8)));
typedef float f32x4 __attribute__((ext_vector_type(4)));
typedef unsigned short u16x8 __attribute__((ext_vector_type(8)));
typedef unsigned short u16x4 __attribute__((ext_vector_type(4)));

#define DEV static __device__ __forceinline__

DEV unsigned short f2bf(float f) {
    unsigned u = __builtin_bit_cast(unsigned, f);
    u += 0x7fffu + ((u >> 16) & 1u);   // round-to-nearest-even
    return (unsigned short)(u >> 16);
}
DEV float bf2f(unsigned short h) {
    unsigned u = ((unsigned)h) << 16;
    return __builtin_bit_cast(float, u);
}

DEV void gl2lds16(const void* g, void* l) {
    __builtin_amdgcn_global_load_lds(
        (const __attribute__((address_space(1))) void*)g,
        (__attribute__((address_space(3))) void*)l, 16, 0, 0);
}

#define WAITV(N) asm volatile("s_waitcnt vmcnt(" #N ")" ::: "memory")
#define SBAR()   asm volatile("s_barrier" ::: "memory")

// ===========================================================================
// 256x256 8-phase counted-vmcnt GEMM (T1+T2+T3+T4+T5) — used for QKV.
// ===========================================================================
#define STAGE256(KT, SLOT, BUF)                                               \
    {                                                                         \
        const unsigned short* sbase = ((SLOT) & 1)                            \
            ? BT + (size_t)(bn + ((SLOT) >> 1) * 128) * K                     \
            : A  + (size_t)(bm + ((SLOT) >> 1) * 128) * K;                    \
        _Pragma("unroll")                                                     \
        for (int j = 0; j < 2; ++j) {                                         \
            const unsigned short* g = sbase + (size_t)(srow + j * 64) * K     \
                                      + (KT) * 64 + lc;                       \
            gl2lds16(g, &lds[BUF][SLOT][wave * 512 + j * 4096]);              \
        }                                                                     \
    }

#define COMPUTE256(BUF, MH, NH)                                               \
    {                                                                         \
        const char* Ab = (const char*)&lds[BUF][(MH) * 2][0];                 \
        const char* Bb = (const char*)&lds[BUF][(NH) * 2 + 1][0];             \
        bf16x8 a_[4][2], b_[2][2];                                            \
        _Pragma("unroll")                                                     \
        for (int m4 = 0; m4 < 4; ++m4) {                                      \
            _Pragma("unroll")                                                 \
            for (int kk = 0; kk < 2; ++kk)                                    \
                a_[m4][kk] = *(const bf16x8*)(Ab +                            \
                    (wm * 64 + m4 * 16 + lr) * 128 +                          \
                    ((kk * 64 + lg * 16) ^ xsw));                             \
        }                                                                     \
        _Pragma("unroll")                                                     \
        for (int n2 = 0; n2 < 2; ++n2) {                                      \
            _Pragma("unroll")                                                 \
            for (int kk = 0; kk < 2; ++kk)                                    \
                b_[n2][kk] = *(const bf16x8*)(Bb +                            \
                    (wn * 32 + n2 * 16 + lr) * 128 +                          \
                    ((kk * 64 + lg * 16) ^ xsw));                             \
        }                                                                     \
        __builtin_amdgcn_s_setprio(1);                                        \
        _Pragma("unroll")                                                     \
        for (int m4 = 0; m4 < 4; ++m4)                                        \
            _Pragma("unroll")                                                 \
            for (int n2 = 0; n2 < 2; ++n2)                                    \
                _Pragma("unroll")                                             \
                for (int kk = 0; kk < 2; ++kk)                                \
                    acc[(MH) * 4 + m4][(NH) * 2 + n2] =                       \
                        __builtin_amdgcn_mfma_f32_16x16x32_bf16(              \
                            a_[m4][kk], b_[n2][kk],                           \
                            acc[(MH) * 4 + m4][(NH) * 2 + n2], 0, 0, 0);      \
        __builtin_amdgcn_s_setprio(0);                                        \
    }

__global__ __launch_bounds__(512, 2)
void gemm256_bt(const unsigned short* __restrict__ A,
                const unsigned short* __restrict__ BT,
                unsigned short* __restrict__ outB,
                int M, int N, int K)
{
    __shared__ alignas(16) unsigned short lds[2][4][8192];   // 128 KiB
    const int tid  = threadIdx.x;
    const int lane = tid & 63;
    const int wave = tid >> 6;
    const int wm = wave >> 2;
    const int wn = wave & 3;
    const int lr = lane & 15;
    const int lg = lane >> 4;
    const int lin = blockIdx.y * gridDim.x + blockIdx.x;
    const int cpx = (gridDim.x * gridDim.y) >> 3;
    const int swz = (lin & 7) * cpx + (lin >> 3);
    const int bm = (swz & 7) * 256;      // gridDim.y == 8 (M = 2048)
    const int bn = (swz >> 3) * 256;
    const int xsw  = (lr & 7) << 4;
    const int srow = tid >> 3;
    const int lc   = ((tid & 7) ^ (srow & 7)) * 8;

    f32x4 acc[8][4] = {};
    const int NT = K >> 6;

    STAGE256(0, 0, 0); STAGE256(0, 1, 0); STAGE256(0, 2, 0); STAGE256(0, 3, 0);
    for (int kt = 0; kt < NT - 1; ++kt) {
        const int buf = kt & 1, nbuf = buf ^ 1;
        STAGE256(kt + 1, 0, nbuf);
        WAITV(6); SBAR();
        COMPUTE256(buf, 0, 0);
        STAGE256(kt + 1, 1, nbuf);
        WAITV(6); SBAR();
        COMPUTE256(buf, 1, 0);
        STAGE256(kt + 1, 2, nbuf);
        WAITV(6); SBAR();
        COMPUTE256(buf, 1, 1);
        STAGE256(kt + 1, 3, nbuf);
        COMPUTE256(buf, 0, 1);
        SBAR();
    }
    {
        const int buf = (NT - 1) & 1;
        WAITV(4); SBAR();
        COMPUTE256(buf, 0, 0);
        WAITV(2); SBAR();
        COMPUTE256(buf, 1, 0);
        WAITV(0); SBAR();
        COMPUTE256(buf, 1, 1);
        COMPUTE256(buf, 0, 1);
    }

#pragma unroll
    for (int m = 0; m < 8; ++m) {
        const int row = bm + (m >> 2) * 128 + wm * 64 + (m & 3) * 16 + lg * 4;
#pragma unroll
        for (int n = 0; n < 4; ++n) {
            const int col = bn + (n >> 1) * 128 + wn * 32 + (n & 1) * 16 + lr;
#pragma unroll
            for (int r = 0; r < 4; ++r)
                outB[(size_t)(row + r) * N + col] = f2bf(acc[m][n][r]);
        }
    }
}

// ===========================================================================
// 128x256 tile, same counted-vmcnt schedule, 2 phases/K-tile.
// 3 LDS slots/buf: [A(128x64), B0(128x64), B1(128x64)] = 96 KiB with dbuf.
// Per tile: stage A,B0(t+1); vmcnt(4) [retire all 6 of tile t]; s_barrier;
// 16 MFMA kk0; stage B1(t+1); 16 MFMA kk1; s_barrier.
// 8 waves 2Mx4N, wave tile 64x64, acc[4][4]. SPLITK: z halves K, fp32 out.
// ===========================================================================
#define STAGE128(KT, SLOT, BUF)                                               \
    {                                                                         \
        const unsigned short* sbase = ((SLOT) == 0)                           \
            ? A  + (size_t)bm * K                                             \
            : BT + (size_t)(bn + ((SLOT) - 1) * 128) * K;                     \
        _Pragma("unroll")                                                     \
        for (int j = 0; j < 2; ++j) {                                         \
            const unsigned short* g = sbase + (size_t)(srow + j * 64) * K     \
                                      + koff + (KT) * 64 + lc;                \
            gl2lds16(g, &lds[BUF][SLOT][wave * 512 + j * 4096]);              \
        }                                                                     \
    }

#define COMPUTE128(BUF, KK)                                                   \
    {                                                                         \
        const char* Ab = (const char*)&lds[BUF][0][0];                        \
        const char* Bb = (const char*)&lds[BUF][1 + (wn >> 1)][0];            \
        bf16x8 a_[4], b_[4];                                                  \
        _Pragma("unroll")                                                     \
        for (int m4 = 0; m4 < 4; ++m4)                                        \
            a_[m4] = *(const bf16x8*)(Ab + (wm * 64 + m4 * 16 + lr) * 128 +   \
                     (((KK) * 64 + lg * 16) ^ xsw));                          \
        _Pragma("unroll")                                                     \
        for (int n2 = 0; n2 < 4; ++n2)                                        \
            b_[n2] = *(const bf16x8*)(Bb +                                    \
                     ((wn & 1) * 64 + n2 * 16 + lr) * 128 +                   \
                     (((KK) * 64 + lg * 16) ^ xsw));                          \
        __builtin_amdgcn_s_setprio(1);                                        \
        _Pragma("unroll")                                                     \
        for (int m4 = 0; m4 < 4; ++m4)                                        \
            _Pragma("unroll")                                                 \
            for (int n2 = 0; n2 < 4; ++n2)                                    \
                acc[m4][n2] = __builtin_amdgcn_mfma_f32_16x16x32_bf16(        \
                    a_[m4], b_[n2], acc[m4][n2], 0, 0, 0);                    \
        __builtin_amdgcn_s_setprio(0);                                        \
    }

template <bool SPLITK>
__global__ __launch_bounds__(512, 2)
void gemm128_bt(const unsigned short* __restrict__ A,
                const unsigned short* __restrict__ BT,
                unsigned short* __restrict__ outB,
                float* __restrict__ outP,
                int M, int N, int K)
{
    __shared__ alignas(16) unsigned short lds[2][3][8192];   // 96 KiB
    const int tid  = threadIdx.x;
    const int lane = tid & 63;
    const int wave = tid >> 6;
    const int wm = wave >> 2;
    const int wn = wave & 3;
    const int lr = lane & 15;
    const int lg = lane >> 4;
    const int gy  = gridDim.y;
    const int lin = blockIdx.y * gridDim.x + blockIdx.x;
    const int cpx = (gridDim.x * gy) >> 3;   // grid (x*y) % 8 == 0 required
    const int swz = (lin & 7) * cpx + (lin >> 3);
    const int bm = (swz % gy) * 128;
    const int bn = (swz / gy) * 256;
    const int xsw  = (lr & 7) << 4;
    const int srow = tid >> 3;
    const int lc   = ((tid & 7) ^ (srow & 7)) * 8;
    int koff, NT;
    if constexpr (SPLITK) { const int Kh = K >> 1; koff = blockIdx.z * Kh; NT = Kh >> 6; }
    else                  { koff = 0;              NT = K >> 6; }

    f32x4 acc[4][4] = {};

    STAGE128(0, 0, 0); STAGE128(0, 1, 0); STAGE128(0, 2, 0);
    for (int kt = 0; kt < NT - 1; ++kt) {
        const int buf = kt & 1, nbuf = buf ^ 1;
        STAGE128(kt + 1, 0, nbuf);
        STAGE128(kt + 1, 1, nbuf);
        WAITV(4); SBAR();
        COMPUTE128(buf, 0);
        STAGE128(kt + 1, 2, nbuf);
        COMPUTE128(buf, 1);
        SBAR();
    }
    {
        const int buf = (NT - 1) & 1;
        WAITV(0); SBAR();
        COMPUTE128(buf, 0);
        COMPUTE128(buf, 1);
    }

#pragma unroll
    for (int m4 = 0; m4 < 4; ++m4) {
        const int row = bm + wm * 64 + m4 * 16 + lg * 4;
#pragma unroll
        for (int n2 = 0; n2 < 4; ++n2) {
            const int col = bn + wn * 64 + n2 * 16 + lr;
#pragma unroll
            for (int r = 0; r < 4; ++r) {
                if constexpr (SPLITK)
                    outP[(size_t)blockIdx.z * M * N + (size_t)(row + r) * N + col] = acc[m4][n2][r];
                else
                    outB[(size_t)(row + r) * N + col] = f2bf(acc[m4][n2][r]);
            }
        }
    }
}

// out = res + p[0] + p[1]   (all fp32, n4 float4 elements)
__global__ __launch_bounds__(256)
void reduce2_add(const float* res, const float* p, float* out, int n4)
{
    const float4* r4 = (const float4*)res;
    const float4* a4 = (const float4*)p;
    const float4* b4 = (const float4*)(p + (size_t)2048 * 2048);
    float4* o4 = (float4*)out;
    for (int i = blockIdx.x * 256 + threadIdx.x; i < n4; i += gridDim.x * 256) {
        const float4 r = r4[i], a = a4[i], b = b4[i];
        o4[i] = make_float4(r.x + a.x + b.x, r.y + a.y + b.y,
                            r.z + a.z + b.z, r.w + a.w + b.w);
    }
}

// h = res + p[0] + p[1]; hout = h; nout = rmsnorm(h)*w  — one block per row.
__global__ __launch_bounds__(256)
void reduce2_norm(const float* __restrict__ res, const float* __restrict__ p,
                  const float* __restrict__ w, float* __restrict__ hout,
                  unsigned short* __restrict__ nout)
{
    const int row = blockIdx.x, tid = threadIdx.x;
    const float4* r4 = (const float4*)(res + (size_t)row * 2048);
    const float4* a4 = (const float4*)(p   + (size_t)row * 2048);
    const float4* b4 = (const float4*)(p + (size_t)2048 * 2048 + (size_t)row * 2048);
    float4* h4 = (float4*)(hout + (size_t)row * 2048);
    float4 h[2];
    float ss = 0.f;
#pragma unroll
    for (int i = 0; i < 2; ++i) {
        const int idx = i * 256 + tid;
        const float4 r = r4[idx], a = a4[idx], b = b4[idx];
        float4 v = make_float4(r.x + a.x + b.x, r.y + a.y + b.y,
                               r.z + a.z + b.z, r.w + a.w + b.w);
        h[i] = v; h4[idx] = v;
        ss += v.x * v.x + v.y * v.y + v.z * v.z + v.w * v.w;
    }
#pragma unroll
    for (int off = 32; off; off >>= 1) ss += __shfl_xor(ss, off);
    __shared__ float red[4];
    if ((tid & 63) == 0) red[tid >> 6] = ss;
    __syncthreads();
    const float tot = red[0] + red[1] + red[2] + red[3];
    const float sc = rsqrtf(tot * (1.0f / 2048.0f) + 1e-5f);
#pragma unroll
    for (int i = 0; i < 2; ++i) {
        const int idx = i * 256 + tid;
        const float4 wv = ((const float4*)w)[idx];
        u16x4 o;
        o[0] = f2bf(h[i].x * sc * wv.x); o[1] = f2bf(h[i].y * sc * wv.y);
        o[2] = f2bf(h[i].z * sc * wv.z); o[3] = f2bf(h[i].w * sc * wv.w);
        *(u16x4*)(nout + (size_t)row * 2048 + idx * 4) = o;
    }
}

// ---------------------------------------------------------------------------
// RMSNorm: fp32 in [2048][2048] -> bf16 out, weight fp32. One block per row.
// ---------------------------------------------------------------------------
__global__ __launch_bounds__(256)
void rmsnorm_kernel(const float* __restrict__ x, const float* __restrict__ w,
                    unsigned short* __restrict__ out)
{
    const int row = blockIdx.x;
    const int tid = threadIdx.x;
    const float* xr = x + (size_t)row * 2048;
    const float4 a = *reinterpret_cast<const float4*>(xr + tid * 8);
    const float4 b = *reinterpret_cast<const float4*>(xr + tid * 8 + 4);
    float ss = a.x * a.x + a.y * a.y + a.z * a.z + a.w * a.w
             + b.x * b.x + b.y * b.y + b.z * b.z + b.w * b.w;
#pragma unroll
    for (int off = 32; off; off >>= 1) ss += __shfl_xor(ss, off);
    __shared__ float red[4];
    if ((tid & 63) == 0) red[tid >> 6] = ss;
    __syncthreads();
    const float tot = red[0] + red[1] + red[2] + red[3];
    const float sc = rsqrtf(tot * (1.0f / 2048.0f) + 1e-5f);
    const float4 wa = *reinterpret_cast<const float4*>(w + tid * 8);
    const float4 wb = *reinterpret_cast<const float4*>(w + tid * 8 + 4);
    u16x8 o;
    o[0] = f2bf(a.x * sc * wa.x); o[1] = f2bf(a.y * sc * wa.y);
    o[2] = f2bf(a.z * sc * wa.z); o[3] = f2bf(a.w * sc * wa.w);
    o[4] = f2bf(b.x * sc * wb.x); o[5] = f2bf(b.y * sc * wb.y);
    o[6] = f2bf(b.z * sc * wb.z); o[7] = f2bf(b.w * sc * wb.w);
    *reinterpret_cast<u16x8*>(out + (size_t)row * 2048 + tid * 8) = o;
}

// ---------------------------------------------------------------------------
// RoPE in-place on bf16 qkv[2048][6144], first 4096 cols (q and k regions).
// ---------------------------------------------------------------------------
__global__ __launch_bounds__(256)
void rope_kernel(unsigned short* __restrict__ t, const float* __restrict__ cs,
                 const float* __restrict__ sn)
{
    const int idx = blockIdx.x * 256 + threadIdx.x;   // S * 4096 / 8
    const int s   = idx >> 9;
    const int col = (idx & 511) * 8;
    const int i0  = (col & 127) >> 1;
    u16x8 v = *reinterpret_cast<const u16x8*>(t + (size_t)s * 6144 + col);
    const float4 c  = *reinterpret_cast<const float4*>(cs + s * 64 + i0);
    const float4 sv = *reinterpret_cast<const float4*>(sn + s * 64 + i0);
    const float cc[4] = {c.x, c.y, c.z, c.w};
    const float ns[4] = {sv.x, sv.y, sv.z, sv.w};
#pragma unroll
    for (int p = 0; p < 4; ++p) {
        const float re = bf2f(v[2 * p]), im = bf2f(v[2 * p + 1]);
        v[2 * p]     = f2bf(re * cc[p] - im * ns[p]);
        v[2 * p + 1] = f2bf(re * ns[p] + im * cc[p]);
    }
    *reinterpret_cast<u16x8*>(t + (size_t)s * 6144 + col) = v;
}

// ---------------------------------------------------------------------------
// bf16 transpose: out[N][M] = in[M][N]^T (row stride ldin), 64x64 tiles
// ---------------------------------------------------------------------------
__global__ __launch_bounds__(256)
void transpose_bf16(const unsigned short* __restrict__ in,
                    unsigned short* __restrict__ out, int M, int N, int ldin)
{
    __shared__ unsigned short t[64][66];
    const int bm = blockIdx.y * 64, bn = blockIdx.x * 64;
    const int tid = threadIdx.x;
    const int r = tid >> 3, c8 = (tid & 7) * 8;
#pragma unroll
    for (int i = 0; i < 2; ++i) {
        const int row = r + i * 32;
        u16x8 v = *reinterpret_cast<const u16x8*>(in + (size_t)(bm + row) * ldin + bn + c8);
#pragma unroll
        for (int e = 0; e < 8; ++e) t[row][c8 + e] = v[e];
    }
    __syncthreads();
#pragma unroll
    for (int i = 0; i < 2; ++i) {
        const int orow = r + i * 32;
        u16x8 v;
#pragma unroll
        for (int e = 0; e < 8; ++e) v[e] = t[c8 + e][orow];
        *reinterpret_cast<u16x8*>(out + (size_t)(bn + orow) * M + bm + c8) = v;
    }
}

// ---------------------------------------------------------------------------
// Weight convert + transpose: w[K][N] fp32 -> wT[N][K] bf16, 64x64 tiles
// ---------------------------------------------------------------------------
__global__ __launch_bounds__(256)
void convT_kernel(const float* __restrict__ w, unsigned short* __restrict__ wT,
                  int K, int N)
{
    __shared__ unsigned short t[64][66];
    const int bk = blockIdx.y * 64, bn = blockIdx.x * 64;
    const int tid = threadIdx.x;
    const int r = tid >> 4, c4 = (tid & 15) * 4;
#pragma unroll
    for (int i = 0; i < 4; ++i) {
        const int row = r + i * 16;
        const float4 v = *reinterpret_cast<const float4*>(w + (size_t)(bk + row) * N + bn + c4);
        t[row][c4 + 0] = f2bf(v.x); t[row][c4 + 1] = f2bf(v.y);
        t[row][c4 + 2] = f2bf(v.z); t[row][c4 + 3] = f2bf(v.w);
    }
    __syncthreads();
#pragma unroll
    for (int i = 0; i < 4; ++i) {
        const int n = r + i * 16;
        u16x4 o;
#pragma unroll
        for (int e = 0; e < 4; ++e) o[e] = t[c4 + e][n];
        *reinterpret_cast<u16x4*>(wT + (size_t)(bn + n) * K + bk + c4) = o;
    }
}

// ---------------------------------------------------------------------------
// SwiGLU: g[s][f] = silu(t13[s][f]) * t13[s][f+5632]; t13 [2048][11264]
// ---------------------------------------------------------------------------
__global__ __launch_bounds__(256)
void silu_mul_kernel(const unsigned short* __restrict__ t13,
                     unsigned short* __restrict__ g)
{
    const int s  = blockIdx.y;
    const int c8 = (blockIdx.x * 256 + threadIdx.x) * 8;
    if (c8 >= 5632) return;
    const unsigned short* row = t13 + (size_t)s * 11264;
    const u16x8 va = *reinterpret_cast<const u16x8*>(row + c8);
    const u16x8 vb = *reinterpret_cast<const u16x8*>(row + 5632 + c8);
    u16x8 o;
#pragma unroll
    for (int e = 0; e < 8; ++e) {
        const float x = bf2f(va[e]);
        const float y = bf2f(vb[e]);
        const float sv = x / (1.0f + __expf(-x));
        o[e] = f2bf(sv * y);
    }
    *reinterpret_cast<u16x8*>(g + (size_t)s * 5632 + c8) = o;
}

// ---------------------------------------------------------------------------
// Causal flash attention, paired q-tiles for balance.
// ---------------------------------------------------------------------------
__global__ __launch_bounds__(512)
void flash_attn(const unsigned short* __restrict__ q,
                const unsigned short* __restrict__ k,
                const unsigned short* __restrict__ vT,
                unsigned short* __restrict__ attn)
{
    __shared__ alignas(16) unsigned short Ks[2][64][136];  // [buf][kv][hd]
    __shared__ alignas(16) unsigned short Vs[2][128][72];  // [buf][hd][kv]
    __shared__ alignas(16) unsigned short Ps[8][16][72];   // per-wave P

    const int hh = blockIdx.y;
    const int pi = blockIdx.x;              // 0..15
    const int tid = threadIdx.x;
    const int lane = tid & 63, wave = tid >> 6;
    const int qt = (wave >> 2) ? (31 - pi) : pi;
    const int lr = lane & 15, lg = lane >> 4;
    const int q0 = qt * 64 + (wave & 3) * 16;
    const int myNT = qt + 1;
    const int NT   = 32 - pi;

    const int kr0 = tid >> 4, kc0 = (tid & 15) * 8;
    const int vr0 = tid >> 3, vc0 = (tid & 7) * 8;

    bf16x8 qf[4];
#pragma unroll
    for (int c = 0; c < 4; ++c)
        qf[c] = *reinterpret_cast<const bf16x8*>(
            q + (size_t)(q0 + lr) * 6144 + hh * 128 + c * 32 + lg * 8);

    f32x4 oacc[8] = {};
    float m_r[4], l_r[4];
#pragma unroll
    for (int r = 0; r < 4; ++r) { m_r[r] = -INFINITY; l_r[r] = 0.0f; }
    const float scale = 0.08838834764831845f;   // 1/sqrt(128)

    u16x8 kreg0, kreg1, vreg0, vreg1;
    auto gload = [&](int kt) {
        const int kv0 = kt * 64;
        kreg0 = *reinterpret_cast<const u16x8*>(k + (size_t)(kv0 + kr0) * 6144 + hh * 128 + kc0);
        kreg1 = *reinterpret_cast<const u16x8*>(k + (size_t)(kv0 + kr0 + 32) * 6144 + hh * 128 + kc0);
        vreg0 = *reinterpret_cast<const u16x8*>(vT + (size_t)(hh * 128 + vr0) * 2048 + kv0 + vc0);
        vreg1 = *reinterpret_cast<const u16x8*>(vT + (size_t)(hh * 128 + vr0 + 64) * 2048 + kv0 + vc0);
    };
    auto lwrite = [&](int buf) {
        *reinterpret_cast<u16x8*>(&Ks[buf][kr0][kc0])      = kreg0;
        *reinterpret_cast<u16x8*>(&Ks[buf][kr0 + 32][kc0]) = kreg1;
        *reinterpret_cast<u16x8*>(&Vs[buf][vr0][vc0])      = vreg0;
        *reinterpret_cast<u16x8*>(&Vs[buf][vr0 + 64][vc0]) = vreg1;
    };

    gload(0); lwrite(0);
    __syncthreads();

    for (int kt = 0; kt < NT; ++kt) {
        const int buf = kt & 1;
        if (kt + 1 < NT) gload(kt + 1);

        if (kt < myNT) {
            const int kv0 = kt * 64;
            const bool masked = (kt == myNT - 1);
            f32x4 s[4] = {};
            __builtin_amdgcn_s_setprio(1);
#pragma unroll
            for (int ct = 0; ct < 4; ++ct)
#pragma unroll
                for (int c = 0; c < 4; ++c) {
                    const bf16x8 kf = *reinterpret_cast<const bf16x8*>(
                        &Ks[buf][ct * 16 + lr][c * 32 + lg * 8]);
                    s[ct] = __builtin_amdgcn_mfma_f32_16x16x32_bf16(qf[c], kf, s[ct], 0, 0, 0);
                }
            __builtin_amdgcn_s_setprio(0);
#pragma unroll
            for (int ct = 0; ct < 4; ++ct)
#pragma unroll
                for (int r = 0; r < 4; ++r) {
                    float v = s[ct][r] * scale;
                    if (masked) {
                        const int kvg = kv0 + ct * 16 + lr;
                        const int qg  = q0 + lg * 4 + r;
                        if (kvg > qg) v = -INFINITY;
                    }
                    s[ct][r] = v;
                }
            float mn[4], alpha[4], rs[4];
#pragma unroll
            for (int r = 0; r < 4; ++r) {
                float v = fmaxf(fmaxf(s[0][r], s[1][r]), fmaxf(s[2][r], s[3][r]));
                v = fmaxf(v, __shfl_xor(v, 1));
                v = fmaxf(v, __shfl_xor(v, 2));
                v = fmaxf(v, __shfl_xor(v, 4));
                v = fmaxf(v, __shfl_xor(v, 8));
                mn[r] = fmaxf(m_r[r], v);
                alpha[r] = __expf(m_r[r] - mn[r]);
                m_r[r] = mn[r];
                rs[r] = 0.0f;
            }
#pragma unroll
            for (int ct = 0; ct < 4; ++ct)
#pragma unroll
                for (int r = 0; r < 4; ++r) {
                    const float p = __expf(s[ct][r] - mn[r]);
                    s[ct][r] = p;
                    rs[r] += p;
                }
#pragma unroll
            for (int r = 0; r < 4; ++r) {
                float t2 = rs[r];
                t2 += __shfl_xor(t2, 1);
                t2 += __shfl_xor(t2, 2);
                t2 += __shfl_xor(t2, 4);
                t2 += __shfl_xor(t2, 8);
                l_r[r] = l_r[r] * alpha[r] + t2;
            }
#pragma unroll
            for (int ot = 0; ot < 8; ++ot)
#pragma unroll
                for (int r = 0; r < 4; ++r) oacc[ot][r] *= alpha[r];

#pragma unroll
            for (int ct = 0; ct < 4; ++ct)
#pragma unroll
                for (int r = 0; r < 4; ++r)
                    Ps[wave][lg * 4 + r][ct * 16 + lr] = f2bf(s[ct][r]);

            __builtin_amdgcn_s_setprio(1);
#pragma unroll
            for (int c2 = 0; c2 < 2; ++c2) {
                const bf16x8 pf = *reinterpret_cast<const bf16x8*>(
                    &Ps[wave][lr][c2 * 32 + lg * 8]);
#pragma unroll
                for (int ot = 0; ot < 8; ++ot) {
                    const bf16x8 vf = *reinterpret_cast<const bf16x8*>(
                        &Vs[buf][ot * 16 + lr][c2 * 32 + lg * 8]);
                    oacc[ot] = __builtin_amdgcn_mfma_f32_16x16x32_bf16(pf, vf, oacc[ot], 0, 0, 0);
                }
            }
            __builtin_amdgcn_s_setprio(0);
        }

        if (kt + 1 < NT) lwrite(buf ^ 1);
        __syncthreads();
    }

#pragma unroll
    for (int ot = 0; ot < 8; ++ot)
#pragma unroll
        for (int r = 0; r < 4; ++r) {
            const float v = oacc[ot][r] / l_r[r];
            attn[(size_t)(q0 + lg * 4 + r) * 2048 + hh * 128 + ot * 16 + lr] = f2bf(v);
        }
}

// ---------------------------------------------------------------------------
extern "C" void kernel_launch(void* const* d_in, const int* in_sizes, int n_in,
                              void* d_out, int out_size, void* d_ws, size_t ws_size,
                              hipStream_t stream)
{
    const float* x    = (const float*)d_in[0];
    const float* fcos = (const float*)d_in[1];
    const float* fsin = (const float*)d_in[2];
    // d_in[3] = mask (causal, hardcoded)
    const float* wq  = (const float*)d_in[4];
    const float* wk  = (const float*)d_in[5];
    const float* wv  = (const float*)d_in[6];
    const float* wo  = (const float*)d_in[7];
    const float* w1  = (const float*)d_in[8];
    const float* w2  = (const float*)d_in[9];
    const float* w3  = (const float*)d_in[10];
    const float* anw = (const float*)d_in[11];
    const float* fnw = (const float*)d_in[12];
    float* out = (float*)d_out;

    char* ws = (char*)d_ws;
    size_t off = 0;
    auto alloc = [&](size_t bytes) { void* p = ws + off; off += bytes; return p; };
    const size_t SZ_DD = (size_t)2048 * 2048 * 2;   // 8 MiB
    const size_t SZ_DF = (size_t)2048 * 5632 * 2;   // 22 MiB

    unsigned short* wqT = (unsigned short*)alloc(SZ_DD);
    unsigned short* wkT = (unsigned short*)alloc(SZ_DD);
    unsigned short* wvT = (unsigned short*)alloc(SZ_DD);
    unsigned short* woT = (unsigned short*)alloc(SZ_DD);
    unsigned short* w1T = (unsigned short*)alloc(SZ_DF);
    unsigned short* w3T = (unsigned short*)alloc(SZ_DF);
    unsigned short* w2T = (unsigned short*)alloc(SZ_DF);

    // region1 (48 MiB), attn phase: xn | qkv | vT | ab ; pk (32 MiB fp32
    // split-K partials) overlays the dead regions; FFN phase: t13 (44 MiB).
    char* reg1 = (char*)alloc((size_t)48 * 1024 * 1024);
    unsigned short* xn   = (unsigned short*)reg1;
    unsigned short* qkv  = (unsigned short*)(reg1 + SZ_DD);            // [2048][6144]
    unsigned short* vTb  = (unsigned short*)(reg1 + SZ_DD + 3 * SZ_DD);
    unsigned short* ab   = (unsigned short*)(reg1 + SZ_DD + 4 * SZ_DD);
    unsigned short* t13  = (unsigned short*)reg1;                      // [2048][11264]
    float*          pk   = (float*)reg1;                               // [2][2048][2048] f32

    char* reg2 = (char*)alloc(SZ_DF);
    unsigned short* hn = (unsigned short*)reg2;
    unsigned short* t1 = (unsigned short*)reg2;

    const int N4 = 2048 * 2048 / 4;

    // weight fp32 -> bf16 transposed
    convT_kernel<<<dim3(32, 32), 256, 0, stream>>>(wq, wqT, 2048, 2048);
    convT_kernel<<<dim3(32, 32), 256, 0, stream>>>(wk, wkT, 2048, 2048);
    convT_kernel<<<dim3(32, 32), 256, 0, stream>>>(wv, wvT, 2048, 2048);
    convT_kernel<<<dim3(32, 32), 256, 0, stream>>>(wo, woT, 2048, 2048);
    convT_kernel<<<dim3(88, 32), 256, 0, stream>>>(w1, w1T, 2048, 5632);
    convT_kernel<<<dim3(88, 32), 256, 0, stream>>>(w3, w3T, 2048, 5632);
    convT_kernel<<<dim3(32, 88), 256, 0, stream>>>(w2, w2T, 5632, 2048);

    // attention block
    rmsnorm_kernel<<<2048, 256, 0, stream>>>(x, anw, xn);
    gemm256_bt<<<dim3(24, 8), 512, 0, stream>>>(xn, wqT, qkv, 2048, 6144, 2048);
    rope_kernel<<<4096, 256, 0, stream>>>(qkv, fcos, fsin);
    transpose_bf16<<<dim3(32, 32), 256, 0, stream>>>(qkv + 4096, vTb, 2048, 2048, 6144);
    flash_attn<<<dim3(16, 16), 512, 0, stream>>>(qkv, qkv + 2048, vTb, ab);
    // Wo split-K=2: 256 blocks = 100% CU fill (xn/qkv/vT dead -> pk overlay)
    gemm128_bt<true><<<dim3(8, 16, 2), 512, 0, stream>>>(ab, woT, nullptr, pk, 2048, 2048, 2048);
    // fused: out = x + Wo-partials; hn = rmsnorm(out) * fnw
    reduce2_norm<<<2048, 256, 0, stream>>>(x, pk, fnw, out, hn);

    // FFN block
    // W13: 704 blocks = 92% CU fill
    gemm128_bt<false><<<dim3(44, 16), 512, 0, stream>>>(hn, w1T, t13, nullptr, 2048, 11264, 2048);
    silu_mul_kernel<<<dim3(3, 2048), 256, 0, stream>>>(t13, t1);
    // W2 split-K=2: 256 blocks (t13 dead -> pk overlay)
    gemm128_bt<true><<<dim3(8, 16, 2), 512, 0, stream>>>(t1, w2T, nullptr, pk, 2048, 2048, 5632);
    reduce2_add<<<2048, 256, 0, stream>>>(out, pk, out, N4);
}

// Round 7
// 439.344 us; speedup vs baseline: 1.5374x; 1.0255x over previous
//
#include <hip/hip_runtime.h>
#include <hip/hip_bf16.h>

typedef __bf16 bf16x8 __attribute__((ext_vector_type(8)));
typedef float f32x4 __attribute__((ext_vector_type(4)));
typedef unsigned short u16x8 __attribute__((ext_vector_type(8)));
typedef unsigned short u16x4 __attribute__((ext_vector_type(4)));

#define DEV static __device__ __forceinline__

DEV unsigned short f2bf(float f) {
    unsigned u = __builtin_bit_cast(unsigned, f);
    u += 0x7fffu + ((u >> 16) & 1u);   // round-to-nearest-even
    return (unsigned short)(u >> 16);
}
DEV float bf2f(unsigned short h) {
    unsigned u = ((unsigned)h) << 16;
    return __builtin_bit_cast(float, u);
}

DEV void gl2lds16(const void* g, void* l) {
    __builtin_amdgcn_global_load_lds(
        (const __attribute__((address_space(1))) void*)g,
        (__attribute__((address_space(3))) void*)l, 16, 0, 0);
}

#define WAITV(N) asm volatile("s_waitcnt vmcnt(" #N ")" ::: "memory")
#define SBAR()   asm volatile("s_barrier" ::: "memory")

// ===========================================================================
// 256x256 8-phase counted-vmcnt GEMM — QKV only (A/B reference vs gemm128d).
// ===========================================================================
#define STAGE256(KT, SLOT, BUF)                                               \
    {                                                                         \
        const unsigned short* sbase = ((SLOT) & 1)                            \
            ? BT + (size_t)(bn + ((SLOT) >> 1) * 128) * K                     \
            : A  + (size_t)(bm + ((SLOT) >> 1) * 128) * K;                    \
        _Pragma("unroll")                                                     \
        for (int j = 0; j < 2; ++j) {                                         \
            const unsigned short* g = sbase + (size_t)(srow + j * 64) * K     \
                                      + (KT) * 64 + lc;                       \
            gl2lds16(g, &lds[BUF][SLOT][wave * 512 + j * 4096]);              \
        }                                                                     \
    }

#define COMPUTE256(BUF, MH, NH)                                               \
    {                                                                         \
        const char* Ab = (const char*)&lds[BUF][(MH) * 2][0];                 \
        const char* Bb = (const char*)&lds[BUF][(NH) * 2 + 1][0];             \
        bf16x8 a_[4][2], b_[2][2];                                            \
        _Pragma("unroll")                                                     \
        for (int m4 = 0; m4 < 4; ++m4) {                                      \
            _Pragma("unroll")                                                 \
            for (int kk = 0; kk < 2; ++kk)                                    \
                a_[m4][kk] = *(const bf16x8*)(Ab +                            \
                    (wm * 64 + m4 * 16 + lr) * 128 +                          \
                    ((kk * 64 + lg * 16) ^ xsw));                             \
        }                                                                     \
        _Pragma("unroll")                                                     \
        for (int n2 = 0; n2 < 2; ++n2) {                                      \
            _Pragma("unroll")                                                 \
            for (int kk = 0; kk < 2; ++kk)                                    \
                b_[n2][kk] = *(const bf16x8*)(Bb +                            \
                    (wn * 32 + n2 * 16 + lr) * 128 +                          \
                    ((kk * 64 + lg * 16) ^ xsw));                             \
        }                                                                     \
        __builtin_amdgcn_s_setprio(1);                                        \
        _Pragma("unroll")                                                     \
        for (int m4 = 0; m4 < 4; ++m4)                                        \
            _Pragma("unroll")                                                 \
            for (int n2 = 0; n2 < 2; ++n2)                                    \
                _Pragma("unroll")                                             \
                for (int kk = 0; kk < 2; ++kk)                                \
                    acc[(MH) * 4 + m4][(NH) * 2 + n2] =                       \
                        __builtin_amdgcn_mfma_f32_16x16x32_bf16(              \
                            a_[m4][kk], b_[n2][kk],                           \
                            acc[(MH) * 4 + m4][(NH) * 2 + n2], 0, 0, 0);      \
        __builtin_amdgcn_s_setprio(0);                                        \
    }

__global__ __launch_bounds__(512, 2)
void gemm256_bt(const unsigned short* __restrict__ A,
                const unsigned short* __restrict__ BT,
                unsigned short* __restrict__ outB,
                int M, int N, int K)
{
    __shared__ alignas(16) unsigned short lds[2][4][8192];   // 128 KiB
    const int tid  = threadIdx.x;
    const int lane = tid & 63;
    const int wave = tid >> 6;
    const int wm = wave >> 2;
    const int wn = wave & 3;
    const int lr = lane & 15;
    const int lg = lane >> 4;
    const int lin = blockIdx.y * gridDim.x + blockIdx.x;
    const int cpx = (gridDim.x * gridDim.y) >> 3;
    const int swz = (lin & 7) * cpx + (lin >> 3);
    const int bm = (swz & 7) * 256;      // gridDim.y == 8 (M = 2048)
    const int bn = (swz >> 3) * 256;
    const int xsw  = (lr & 7) << 4;
    const int srow = tid >> 3;
    const int lc   = ((tid & 7) ^ (srow & 7)) * 8;

    f32x4 acc[8][4] = {};
    const int NT = K >> 6;

    STAGE256(0, 0, 0); STAGE256(0, 1, 0); STAGE256(0, 2, 0); STAGE256(0, 3, 0);
    for (int kt = 0; kt < NT - 1; ++kt) {
        const int buf = kt & 1, nbuf = buf ^ 1;
        STAGE256(kt + 1, 0, nbuf);
        WAITV(6); SBAR();
        COMPUTE256(buf, 0, 0);
        STAGE256(kt + 1, 1, nbuf);
        WAITV(6); SBAR();
        COMPUTE256(buf, 1, 0);
        STAGE256(kt + 1, 2, nbuf);
        WAITV(6); SBAR();
        COMPUTE256(buf, 1, 1);
        STAGE256(kt + 1, 3, nbuf);
        COMPUTE256(buf, 0, 1);
        SBAR();
    }
    {
        const int buf = (NT - 1) & 1;
        WAITV(4); SBAR();
        COMPUTE256(buf, 0, 0);
        WAITV(2); SBAR();
        COMPUTE256(buf, 1, 0);
        WAITV(0); SBAR();
        COMPUTE256(buf, 1, 1);
        COMPUTE256(buf, 0, 1);
    }

#pragma unroll
    for (int m = 0; m < 8; ++m) {
        const int row = bm + (m >> 2) * 128 + wm * 64 + (m & 3) * 16 + lg * 4;
#pragma unroll
        for (int n = 0; n < 4; ++n) {
            const int col = bn + (n >> 1) * 128 + wn * 32 + (n & 1) * 16 + lr;
#pragma unroll
            for (int r = 0; r < 4; ++r)
                outB[(size_t)(row + r) * N + col] = f2bf(acc[m][n][r]);
        }
    }
}

// ===========================================================================
// gemm128d: 128x256 tile, DEEP pipeline — 3 LDS buffers (144 KiB), 2-tile
// lookahead, all 6 loads issued at tile start, 32-MFMA cluster per tile.
// Retirement: iter kt stages T(kt+2) -> 18 outstanding; vmcnt(12) leaves
// {T(kt+1),T(kt+2)} => T(kt) landed, cover = 2 tiles. Drain 6 -> 0.
// Buffer rotation mod 3: stage target (kt+2)%3 was last read at iter kt-1
// (trailing s_barrier protects). 8 waves 2Mx4N, wave 64x64, acc[4][4].
// EPI 0: bf16 C.  EPI 1: split-K=2 fp32 partials (blockIdx.z).
// EPI 2: fused SwiGLU — interleaved cols (2j=w1,2j+1=w3), even lanes write
//        silu(x1)*x3 to [M][N/2] bf16.
// ===========================================================================
#define STAGE128D(KT, BUF)                                                    \
    _Pragma("unroll")                                                         \
    for (int sl = 0; sl < 3; ++sl) {                                          \
        const unsigned short* sbase = (sl == 0)                               \
            ? A  + (size_t)bm * K                                             \
            : BT + (size_t)(bn + (sl - 1) * 128) * K;                         \
        _Pragma("unroll")                                                     \
        for (int j = 0; j < 2; ++j) {                                         \
            const unsigned short* g = sbase + (size_t)(srow + j * 64) * K     \
                                      + koff + (KT) * 64 + lc;                \
            gl2lds16(g, &lds[BUF][sl][wave * 512 + j * 4096]);                \
        }                                                                     \
    }

#define COMPUTE128D(BUF)                                                      \
    {                                                                         \
        const char* Ab = (const char*)&lds[BUF][0][0];                        \
        const char* Bb = (const char*)&lds[BUF][1 + (wn >> 1)][0];            \
        bf16x8 a_[4][2], b_[4][2];                                            \
        _Pragma("unroll")                                                     \
        for (int m4 = 0; m4 < 4; ++m4)                                        \
            _Pragma("unroll")                                                 \
            for (int kk = 0; kk < 2; ++kk)                                    \
                a_[m4][kk] = *(const bf16x8*)(Ab +                            \
                    (wm * 64 + m4 * 16 + lr) * 128 +                          \
                    ((kk * 64 + lg * 16) ^ xsw));                             \
        _Pragma("unroll")                                                     \
        for (int n2 = 0; n2 < 4; ++n2)                                        \
            _Pragma("unroll")                                                 \
            for (int kk = 0; kk < 2; ++kk)                                    \
                b_[n2][kk] = *(const bf16x8*)(Bb +                            \
                    ((wn & 1) * 64 + n2 * 16 + lr) * 128 +                    \
                    ((kk * 64 + lg * 16) ^ xsw));                             \
        __builtin_amdgcn_s_setprio(1);                                        \
        _Pragma("unroll")                                                     \
        for (int m4 = 0; m4 < 4; ++m4)                                        \
            _Pragma("unroll")                                                 \
            for (int n2 = 0; n2 < 4; ++n2)                                    \
                _Pragma("unroll")                                             \
                for (int kk = 0; kk < 2; ++kk)                                \
                    acc[m4][n2] = __builtin_amdgcn_mfma_f32_16x16x32_bf16(    \
                        a_[m4][kk], b_[n2][kk], acc[m4][n2], 0, 0, 0);        \
        __builtin_amdgcn_s_setprio(0);                                        \
    }

template <int EPI>
__global__ __launch_bounds__(512, 2)
void gemm128d(const unsigned short* __restrict__ A,
              const unsigned short* __restrict__ BT,
              unsigned short* __restrict__ outB,
              float* __restrict__ outP,
              int M, int N, int K)
{
    __shared__ alignas(16) unsigned short lds[3][3][8192];   // 144 KiB
    const int tid  = threadIdx.x;
    const int lane = tid & 63;
    const int wave = tid >> 6;
    const int wm = wave >> 2;
    const int wn = wave & 3;
    const int lr = lane & 15;
    const int lg = lane >> 4;
    const int gy  = gridDim.y;
    const int lin = blockIdx.y * gridDim.x + blockIdx.x;
    const int cpx = (gridDim.x * gy) >> 3;   // grid (x*y) % 8 == 0 required
    const int swz = (lin & 7) * cpx + (lin >> 3);
    const int bm = (swz % gy) * 128;
    const int bn = (swz / gy) * 256;
    const int xsw  = (lr & 7) << 4;
    const int srow = tid >> 3;
    const int lc   = ((tid & 7) ^ (srow & 7)) * 8;
    int koff, NT;
    if constexpr (EPI == 1) { const int Kh = K >> 1; koff = blockIdx.z * Kh; NT = Kh >> 6; }
    else                    { koff = 0;              NT = K >> 6; }

    f32x4 acc[4][4] = {};

    STAGE128D(0, 0);
    STAGE128D(1, 1);
    int bc = 0;
    for (int kt = 0; kt + 2 < NT; ++kt) {
        const int nb = (bc == 0) ? 2 : bc - 1;   // (bc+2)%3
        STAGE128D(kt + 2, nb);
        WAITV(12); SBAR();
        COMPUTE128D(bc);
        SBAR();
        bc = (bc == 2) ? 0 : bc + 1;
    }
    WAITV(6); SBAR();
    COMPUTE128D(bc);
    SBAR();
    bc = (bc == 2) ? 0 : bc + 1;
    WAITV(0); SBAR();
    COMPUTE128D(bc);

#pragma unroll
    for (int m4 = 0; m4 < 4; ++m4) {
        const int row = bm + wm * 64 + m4 * 16 + lg * 4;
#pragma unroll
        for (int n2 = 0; n2 < 4; ++n2) {
            const int col = bn + wn * 64 + n2 * 16 + lr;
#pragma unroll
            for (int r = 0; r < 4; ++r) {
                if constexpr (EPI == 0) {
                    outB[(size_t)(row + r) * N + col] = f2bf(acc[m4][n2][r]);
                } else if constexpr (EPI == 1) {
                    outP[(size_t)blockIdx.z * M * N + (size_t)(row + r) * N + col] = acc[m4][n2][r];
                } else {
                    const float v  = acc[m4][n2][r];
                    const float vo = __shfl_xor(v, 1);
                    const float x1 = (lr & 1) ? vo : v;
                    const float x3 = (lr & 1) ? v : vo;
                    const float g  = x1 / (1.0f + __expf(-x1)) * x3;
                    if (!(lr & 1))
                        outB[(size_t)(row + r) * (N >> 1) + (col >> 1)] = f2bf(g);
                }
            }
        }
    }
}

// out = res + p[0] + p[1]   (all fp32, n4 float4 elements)
__global__ __launch_bounds__(256)
void reduce2_add(const float* res, const float* p, float* out, int n4)
{
    const float4* r4 = (const float4*)res;
    const float4* a4 = (const float4*)p;
    const float4* b4 = (const float4*)(p + (size_t)2048 * 2048);
    float4* o4 = (float4*)out;
    for (int i = blockIdx.x * 256 + threadIdx.x; i < n4; i += gridDim.x * 256) {
        const float4 r = r4[i], a = a4[i], b = b4[i];
        o4[i] = make_float4(r.x + a.x + b.x, r.y + a.y + b.y,
                            r.z + a.z + b.z, r.w + a.w + b.w);
    }
}

// h = res + p[0] + p[1]; hout = h; nout = rmsnorm(h)*w  — one block per row.
__global__ __launch_bounds__(256)
void reduce2_norm(const float* __restrict__ res, const float* __restrict__ p,
                  const float* __restrict__ w, float* __restrict__ hout,
                  unsigned short* __restrict__ nout)
{
    const int row = blockIdx.x, tid = threadIdx.x;
    const float4* r4 = (const float4*)(res + (size_t)row * 2048);
    const float4* a4 = (const float4*)(p   + (size_t)row * 2048);
    const float4* b4 = (const float4*)(p + (size_t)2048 * 2048 + (size_t)row * 2048);
    float4* h4 = (float4*)(hout + (size_t)row * 2048);
    float4 h[2];
    float ss = 0.f;
#pragma unroll
    for (int i = 0; i < 2; ++i) {
        const int idx = i * 256 + tid;
        const float4 r = r4[idx], a = a4[idx], b = b4[idx];
        float4 v = make_float4(r.x + a.x + b.x, r.y + a.y + b.y,
                               r.z + a.z + b.z, r.w + a.w + b.w);
        h[i] = v; h4[idx] = v;
        ss += v.x * v.x + v.y * v.y + v.z * v.z + v.w * v.w;
    }
#pragma unroll
    for (int off = 32; off; off >>= 1) ss += __shfl_xor(ss, off);
    __shared__ float red[4];
    if ((tid & 63) == 0) red[tid >> 6] = ss;
    __syncthreads();
    const float tot = red[0] + red[1] + red[2] + red[3];
    const float sc = rsqrtf(tot * (1.0f / 2048.0f) + 1e-5f);
#pragma unroll
    for (int i = 0; i < 2; ++i) {
        const int idx = i * 256 + tid;
        const float4 wv = ((const float4*)w)[idx];
        u16x4 o;
        o[0] = f2bf(h[i].x * sc * wv.x); o[1] = f2bf(h[i].y * sc * wv.y);
        o[2] = f2bf(h[i].z * sc * wv.z); o[3] = f2bf(h[i].w * sc * wv.w);
        *(u16x4*)(nout + (size_t)row * 2048 + idx * 4) = o;
    }
}

// ---------------------------------------------------------------------------
// RMSNorm: fp32 in [2048][2048] -> bf16 out, weight fp32. One block per row.
// ---------------------------------------------------------------------------
__global__ __launch_bounds__(256)
void rmsnorm_kernel(const float* __restrict__ x, const float* __restrict__ w,
                    unsigned short* __restrict__ out)
{
    const int row = blockIdx.x;
    const int tid = threadIdx.x;
    const float* xr = x + (size_t)row * 2048;
    const float4 a = *reinterpret_cast<const float4*>(xr + tid * 8);
    const float4 b = *reinterpret_cast<const float4*>(xr + tid * 8 + 4);
    float ss = a.x * a.x + a.y * a.y + a.z * a.z + a.w * a.w
             + b.x * b.x + b.y * b.y + b.z * b.z + b.w * b.w;
#pragma unroll
    for (int off = 32; off; off >>= 1) ss += __shfl_xor(ss, off);
    __shared__ float red[4];
    if ((tid & 63) == 0) red[tid >> 6] = ss;
    __syncthreads();
    const float tot = red[0] + red[1] + red[2] + red[3];
    const float sc = rsqrtf(tot * (1.0f / 2048.0f) + 1e-5f);
    const float4 wa = *reinterpret_cast<const float4*>(w + tid * 8);
    const float4 wb = *reinterpret_cast<const float4*>(w + tid * 8 + 4);
    u16x8 o;
    o[0] = f2bf(a.x * sc * wa.x); o[1] = f2bf(a.y * sc * wa.y);
    o[2] = f2bf(a.z * sc * wa.z); o[3] = f2bf(a.w * sc * wa.w);
    o[4] = f2bf(b.x * sc * wb.x); o[5] = f2bf(b.y * sc * wb.y);
    o[6] = f2bf(b.z * sc * wb.z); o[7] = f2bf(b.w * sc * wb.w);
    *reinterpret_cast<u16x8*>(out + (size_t)row * 2048 + tid * 8) = o;
}

// ---------------------------------------------------------------------------
// RoPE in-place on bf16 qkv[2048][6144], first 4096 cols (q and k regions).
// ---------------------------------------------------------------------------
__global__ __launch_bounds__(256)
void rope_kernel(unsigned short* __restrict__ t, const float* __restrict__ cs,
                 const float* __restrict__ sn)
{
    const int idx = blockIdx.x * 256 + threadIdx.x;   // S * 4096 / 8
    const int s   = idx >> 9;
    const int col = (idx & 511) * 8;
    const int i0  = (col & 127) >> 1;
    u16x8 v = *reinterpret_cast<const u16x8*>(t + (size_t)s * 6144 + col);
    const float4 c  = *reinterpret_cast<const float4*>(cs + s * 64 + i0);
    const float4 sv = *reinterpret_cast<const float4*>(sn + s * 64 + i0);
    const float cc[4] = {c.x, c.y, c.z, c.w};
    const float ns[4] = {sv.x, sv.y, sv.z, sv.w};
#pragma unroll
    for (int p = 0; p < 4; ++p) {
        const float re = bf2f(v[2 * p]), im = bf2f(v[2 * p + 1]);
        v[2 * p]     = f2bf(re * cc[p] - im * ns[p]);
        v[2 * p + 1] = f2bf(re * ns[p] + im * cc[p]);
    }
    *reinterpret_cast<u16x8*>(t + (size_t)s * 6144 + col) = v;
}

// ---------------------------------------------------------------------------
// bf16 transpose: out[N][M] = in[M][N]^T (row stride ldin), 64x64 tiles
// ---------------------------------------------------------------------------
__global__ __launch_bounds__(256)
void transpose_bf16(const unsigned short* __restrict__ in,
                    unsigned short* __restrict__ out, int M, int N, int ldin)
{
    __shared__ unsigned short t[64][66];
    const int bm = blockIdx.y * 64, bn = blockIdx.x * 64;
    const int tid = threadIdx.x;
    const int r = tid >> 3, c8 = (tid & 7) * 8;
#pragma unroll
    for (int i = 0; i < 2; ++i) {
        const int row = r + i * 32;
        u16x8 v = *reinterpret_cast<const u16x8*>(in + (size_t)(bm + row) * ldin + bn + c8);
#pragma unroll
        for (int e = 0; e < 8; ++e) t[row][c8 + e] = v[e];
    }
    __syncthreads();
#pragma unroll
    for (int i = 0; i < 2; ++i) {
        const int orow = r + i * 32;
        u16x8 v;
#pragma unroll
        for (int e = 0; e < 8; ++e) v[e] = t[c8 + e][orow];
        *reinterpret_cast<u16x8*>(out + (size_t)(bn + orow) * M + bm + c8) = v;
    }
}

// ---------------------------------------------------------------------------
// Weight convert + transpose: w[K][N] fp32 -> wT[rmul*n+radd][K] bf16.
// rmul=2/radd=0|1 builds the interleaved w13T (row 2j = w1_j, 2j+1 = w3_j).
// ---------------------------------------------------------------------------
__global__ __launch_bounds__(256)
void convT_kernel(const float* __restrict__ w, unsigned short* __restrict__ wT,
                  int K, int N, int rmul, int radd)
{
    __shared__ unsigned short t[64][66];
    const int bk = blockIdx.y * 64, bn = blockIdx.x * 64;
    const int tid = threadIdx.x;
    const int r = tid >> 4, c4 = (tid & 15) * 4;
#pragma unroll
    for (int i = 0; i < 4; ++i) {
        const int row = r + i * 16;
        const float4 v = *reinterpret_cast<const float4*>(w + (size_t)(bk + row) * N + bn + c4);
        t[row][c4 + 0] = f2bf(v.x); t[row][c4 + 1] = f2bf(v.y);
        t[row][c4 + 2] = f2bf(v.z); t[row][c4 + 3] = f2bf(v.w);
    }
    __syncthreads();
#pragma unroll
    for (int i = 0; i < 4; ++i) {
        const int n = r + i * 16;
        u16x4 o;
#pragma unroll
        for (int e = 0; e < 4; ++e) o[e] = t[c4 + e][n];
        *reinterpret_cast<u16x4*>(wT + (size_t)(rmul * (bn + n) + radd) * K + bk + c4) = o;
    }
}

// ---------------------------------------------------------------------------
// Causal flash attention, paired q-tiles for balance.
// ---------------------------------------------------------------------------
__global__ __launch_bounds__(512)
void flash_attn(const unsigned short* __restrict__ q,
                const unsigned short* __restrict__ k,
                const unsigned short* __restrict__ vT,
                unsigned short* __restrict__ attn)
{
    __shared__ alignas(16) unsigned short Ks[2][64][136];  // [buf][kv][hd]
    __shared__ alignas(16) unsigned short Vs[2][128][72];  // [buf][hd][kv]
    __shared__ alignas(16) unsigned short Ps[8][16][72];   // per-wave P

    const int hh = blockIdx.y;
    const int pi = blockIdx.x;              // 0..15
    const int tid = threadIdx.x;
    const int lane = tid & 63, wave = tid >> 6;
    const int qt = (wave >> 2) ? (31 - pi) : pi;
    const int lr = lane & 15, lg = lane >> 4;
    const int q0 = qt * 64 + (wave & 3) * 16;
    const int myNT = qt + 1;
    const int NT   = 32 - pi;

    const int kr0 = tid >> 4, kc0 = (tid & 15) * 8;
    const int vr0 = tid >> 3, vc0 = (tid & 7) * 8;

    bf16x8 qf[4];
#pragma unroll
    for (int c = 0; c < 4; ++c)
        qf[c] = *reinterpret_cast<const bf16x8*>(
            q + (size_t)(q0 + lr) * 6144 + hh * 128 + c * 32 + lg * 8);

    f32x4 oacc[8] = {};
    float m_r[4], l_r[4];
#pragma unroll
    for (int r = 0; r < 4; ++r) { m_r[r] = -INFINITY; l_r[r] = 0.0f; }
    const float scale = 0.08838834764831845f;   // 1/sqrt(128)

    u16x8 kreg0, kreg1, vreg0, vreg1;
    auto gload = [&](int kt) {
        const int kv0 = kt * 64;
        kreg0 = *reinterpret_cast<const u16x8*>(k + (size_t)(kv0 + kr0) * 6144 + hh * 128 + kc0);
        kreg1 = *reinterpret_cast<const u16x8*>(k + (size_t)(kv0 + kr0 + 32) * 6144 + hh * 128 + kc0);
        vreg0 = *reinterpret_cast<const u16x8*>(vT + (size_t)(hh * 128 + vr0) * 2048 + kv0 + vc0);
        vreg1 = *reinterpret_cast<const u16x8*>(vT + (size_t)(hh * 128 + vr0 + 64) * 2048 + kv0 + vc0);
    };
    auto lwrite = [&](int buf) {
        *reinterpret_cast<u16x8*>(&Ks[buf][kr0][kc0])      = kreg0;
        *reinterpret_cast<u16x8*>(&Ks[buf][kr0 + 32][kc0]) = kreg1;
        *reinterpret_cast<u16x8*>(&Vs[buf][vr0][vc0])      = vreg0;
        *reinterpret_cast<u16x8*>(&Vs[buf][vr0 + 64][vc0]) = vreg1;
    };

    gload(0); lwrite(0);
    __syncthreads();

    for (int kt = 0; kt < NT; ++kt) {
        const int buf = kt & 1;
        if (kt + 1 < NT) gload(kt + 1);

        if (kt < myNT) {
            const int kv0 = kt * 64;
            const bool masked = (kt == myNT - 1);
            f32x4 s[4] = {};
            __builtin_amdgcn_s_setprio(1);
#pragma unroll
            for (int ct = 0; ct < 4; ++ct)
#pragma unroll
                for (int c = 0; c < 4; ++c) {
                    const bf16x8 kf = *reinterpret_cast<const bf16x8*>(
                        &Ks[buf][ct * 16 + lr][c * 32 + lg * 8]);
                    s[ct] = __builtin_amdgcn_mfma_f32_16x16x32_bf16(qf[c], kf, s[ct], 0, 0, 0);
                }
            __builtin_amdgcn_s_setprio(0);
#pragma unroll
            for (int ct = 0; ct < 4; ++ct)
#pragma unroll
                for (int r = 0; r < 4; ++r) {
                    float v = s[ct][r] * scale;
                    if (masked) {
                        const int kvg = kv0 + ct * 16 + lr;
                        const int qg  = q0 + lg * 4 + r;
                        if (kvg > qg) v = -INFINITY;
                    }
                    s[ct][r] = v;
                }
            float mn[4], alpha[4], rs[4];
#pragma unroll
            for (int r = 0; r < 4; ++r) {
                float v = fmaxf(fmaxf(s[0][r], s[1][r]), fmaxf(s[2][r], s[3][r]));
                v = fmaxf(v, __shfl_xor(v, 1));
                v = fmaxf(v, __shfl_xor(v, 2));
                v = fmaxf(v, __shfl_xor(v, 4));
                v = fmaxf(v, __shfl_xor(v, 8));
                mn[r] = fmaxf(m_r[r], v);
                alpha[r] = __expf(m_r[r] - mn[r]);
                m_r[r] = mn[r];
                rs[r] = 0.0f;
            }
#pragma unroll
            for (int ct = 0; ct < 4; ++ct)
#pragma unroll
                for (int r = 0; r < 4; ++r) {
                    const float p = __expf(s[ct][r] - mn[r]);
                    s[ct][r] = p;
                    rs[r] += p;
                }
#pragma unroll
            for (int r = 0; r < 4; ++r) {
                float t2 = rs[r];
                t2 += __shfl_xor(t2, 1);
                t2 += __shfl_xor(t2, 2);
                t2 += __shfl_xor(t2, 4);
                t2 += __shfl_xor(t2, 8);
                l_r[r] = l_r[r] * alpha[r] + t2;
            }
#pragma unroll
            for (int ot = 0; ot < 8; ++ot)
#pragma unroll
                for (int r = 0; r < 4; ++r) oacc[ot][r] *= alpha[r];

#pragma unroll
            for (int ct = 0; ct < 4; ++ct)
#pragma unroll
                for (int r = 0; r < 4; ++r)
                    Ps[wave][lg * 4 + r][ct * 16 + lr] = f2bf(s[ct][r]);

            __builtin_amdgcn_s_setprio(1);
#pragma unroll
            for (int c2 = 0; c2 < 2; ++c2) {
                const bf16x8 pf = *reinterpret_cast<const bf16x8*>(
                    &Ps[wave][lr][c2 * 32 + lg * 8]);
#pragma unroll
                for (int ot = 0; ot < 8; ++ot) {
                    const bf16x8 vf = *reinterpret_cast<const bf16x8*>(
                        &Vs[buf][ot * 16 + lr][c2 * 32 + lg * 8]);
                    oacc[ot] = __builtin_amdgcn_mfma_f32_16x16x32_bf16(pf, vf, oacc[ot], 0, 0, 0);
                }
            }
            __builtin_amdgcn_s_setprio(0);
        }

        if (kt + 1 < NT) lwrite(buf ^ 1);
        __syncthreads();
    }

#pragma unroll
    for (int ot = 0; ot < 8; ++ot)
#pragma unroll
        for (int r = 0; r < 4; ++r) {
            const float v = oacc[ot][r] / l_r[r];
            attn[(size_t)(q0 + lg * 4 + r) * 2048 + hh * 128 + ot * 16 + lr] = f2bf(v);
        }
}

// ---------------------------------------------------------------------------
extern "C" void kernel_launch(void* const* d_in, const int* in_sizes, int n_in,
                              void* d_out, int out_size, void* d_ws, size_t ws_size,
                              hipStream_t stream)
{
    const float* x    = (const float*)d_in[0];
    const float* fcos = (const float*)d_in[1];
    const float* fsin = (const float*)d_in[2];
    // d_in[3] = mask (causal, hardcoded)
    const float* wq  = (const float*)d_in[4];
    const float* wk  = (const float*)d_in[5];
    const float* wv  = (const float*)d_in[6];
    const float* wo  = (const float*)d_in[7];
    const float* w1  = (const float*)d_in[8];
    const float* w2  = (const float*)d_in[9];
    const float* w3  = (const float*)d_in[10];
    const float* anw = (const float*)d_in[11];
    const float* fnw = (const float*)d_in[12];
    float* out = (float*)d_out;

    char* ws = (char*)d_ws;
    size_t off = 0;
    auto alloc = [&](size_t bytes) { void* p = ws + off; off += bytes; return p; };
    const size_t SZ_DD = (size_t)2048 * 2048 * 2;   // 8 MiB
    const size_t SZ_DF = (size_t)2048 * 5632 * 2;   // 22 MiB

    unsigned short* wqT  = (unsigned short*)alloc(SZ_DD);
    unsigned short* wkT  = (unsigned short*)alloc(SZ_DD);
    unsigned short* wvT  = (unsigned short*)alloc(SZ_DD);
    unsigned short* woT  = (unsigned short*)alloc(SZ_DD);
    unsigned short* w13T = (unsigned short*)alloc(2 * SZ_DF);  // interleaved [11264][2048]
    unsigned short* w2T  = (unsigned short*)alloc(SZ_DF);

    // region1 (48 MiB), attn phase: xn[0:8) | qkv[8:32) | vTb[32:40) | ab[40:48)
    // pk (32 MiB fp32 split-K partials) overlays [0:32) when those are dead;
    // hn overlays vTb's region [32:40) (vTb dead after flash).
    char* reg1 = (char*)alloc((size_t)48 * 1024 * 1024);
    unsigned short* xn   = (unsigned short*)reg1;
    unsigned short* qkv  = (unsigned short*)(reg1 + SZ_DD);            // [2048][6144]
    unsigned short* vTb  = (unsigned short*)(reg1 + SZ_DD + 3 * SZ_DD);
    unsigned short* ab   = (unsigned short*)(reg1 + SZ_DD + 4 * SZ_DD);
    float*          pk   = (float*)reg1;                               // [2][2048][2048] f32
    unsigned short* hn   = (unsigned short*)(reg1 + 4 * SZ_DD);        // [2048][2048]

    char* reg2 = (char*)alloc(SZ_DF);
    unsigned short* t1 = (unsigned short*)reg2;                        // [2048][5632]

    const int N4 = 2048 * 2048 / 4;

    // weight fp32 -> bf16 transposed (w1/w3 interleaved into w13T)
    convT_kernel<<<dim3(32, 32), 256, 0, stream>>>(wq, wqT, 2048, 2048, 1, 0);
    convT_kernel<<<dim3(32, 32), 256, 0, stream>>>(wk, wkT, 2048, 2048, 1, 0);
    convT_kernel<<<dim3(32, 32), 256, 0, stream>>>(wv, wvT, 2048, 2048, 1, 0);
    convT_kernel<<<dim3(32, 32), 256, 0, stream>>>(wo, woT, 2048, 2048, 1, 0);
    convT_kernel<<<dim3(88, 32), 256, 0, stream>>>(w1, w13T, 2048, 5632, 2, 0);
    convT_kernel<<<dim3(88, 32), 256, 0, stream>>>(w3, w13T, 2048, 5632, 2, 1);
    convT_kernel<<<dim3(32, 88), 256, 0, stream>>>(w2, w2T, 5632, 2048, 1, 0);

    // attention block
    rmsnorm_kernel<<<2048, 256, 0, stream>>>(x, anw, xn);
    gemm256_bt<<<dim3(24, 8), 512, 0, stream>>>(xn, wqT, qkv, 2048, 6144, 2048);
    rope_kernel<<<4096, 256, 0, stream>>>(qkv, fcos, fsin);
    transpose_bf16<<<dim3(32, 32), 256, 0, stream>>>(qkv + 4096, vTb, 2048, 2048, 6144);
    flash_attn<<<dim3(16, 16), 512, 0, stream>>>(qkv, qkv + 2048, vTb, ab);
    // Wo split-K=2 (deep pipeline): 256 blocks = 100% CU fill
    gemm128d<1><<<dim3(8, 16, 2), 512, 0, stream>>>(ab, woT, nullptr, pk, 2048, 2048, 2048);
    // fused: out = x + Wo-partials; hn = rmsnorm(out) * fnw
    reduce2_norm<<<2048, 256, 0, stream>>>(x, pk, fnw, out, hn);

    // FFN block
    // W13 deep + fused SwiGLU epilogue: t1 = silu(hn@w1) * (hn@w3), 704 blocks
    gemm128d<2><<<dim3(44, 16), 512, 0, stream>>>(hn, w13T, t1, nullptr, 2048, 11264, 2048);
    // W2 split-K=2 (deep): 256 blocks
    gemm128d<1><<<dim3(8, 16, 2), 512, 0, stream>>>(t1, w2T, nullptr, pk, 2048, 2048, 5632);
    reduce2_add<<<2048, 256, 0, stream>>>(out, pk, out, N4);
}

// Round 8
// 434.721 us; speedup vs baseline: 1.5537x; 1.0106x over previous
//
#include <hip/hip_runtime.h>
#include <hip/hip_bf16.h>

typedef __bf16 bf16x8 __attribute__((ext_vector_type(8)));
typedef float f32x4 __attribute__((ext_vector_type(4)));
typedef unsigned short u16x8 __attribute__((ext_vector_type(8)));
typedef unsigned short u16x4 __attribute__((ext_vector_type(4)));

#define DEV static __device__ __forceinline__

DEV unsigned short f2bf(float f) {
    unsigned u = __builtin_bit_cast(unsigned, f);
    u += 0x7fffu + ((u >> 16) & 1u);   // round-to-nearest-even
    return (unsigned short)(u >> 16);
}
DEV float bf2f(unsigned short h) {
    unsigned u = ((unsigned)h) << 16;
    return __builtin_bit_cast(float, u);
}

DEV void gl2lds16(const void* g, void* l) {
    __builtin_amdgcn_global_load_lds(
        (const __attribute__((address_space(1))) void*)g,
        (__attribute__((address_space(3))) void*)l, 16, 0, 0);
}

#define WAITV(N) asm volatile("s_waitcnt vmcnt(" #N ")" ::: "memory")
#define SBAR()   asm volatile("s_barrier" ::: "memory")

// ===========================================================================
// gemm128d v2: 128x256 tile, deep pipeline + m201-style ds_read/MFMA overlap.
// 3 LDS buffers (144 KiB); per iter:
//   STAGE T(t+2) -> buf[(t+2)%3]           (6 global_load_lds, 16B)
//   MFMA x32 on tile t fragments (read last iter, held in VGPRs)
//   WAITV(6)  -> own T(t+1) loads landed (only T(t+2) still in flight)
//   SBAR      -> ALL waves' T(t+1) landed; also fences buffer reuse
//   ds_read 16 frags of tile t+1          (overlaps next iter's stage+MFMA drain)
// Race audit: reads of buf b complete before that wave's MFMA (SSA dep) ->
// before that iter's SBAR; stage into b happens 2 iters later, after that SBAR.
// Swizzle: phys_byte = log_byte ^ ((row&7)<<4), both-sides. Bank-conflict 0.
// 8 waves 2Mx4N, wave 64x64, acc[4][4].
// EPI 0: bf16 C. EPI 1: split-K=2 fp32 partials. EPI 2: fused SwiGLU
//   (interleaved cols 2j=w1,2j+1=w3; even lanes write silu(x1)*x3, [M][N/2]).
// ===========================================================================
#define STAGE128D(KT, BUF)                                                    \
    _Pragma("unroll")                                                         \
    for (int sl = 0; sl < 3; ++sl) {                                          \
        const unsigned short* sbase = (sl == 0)                               \
            ? A  + (size_t)bm * K                                             \
            : BT + (size_t)(bn + (sl - 1) * 128) * K;                         \
        _Pragma("unroll")                                                     \
        for (int j = 0; j < 2; ++j) {                                         \
            const unsigned short* g = sbase + (size_t)(srow + j * 64) * K     \
                                      + koff + (KT) * 64 + lc;                \
            gl2lds16(g, &lds[BUF][sl][wave * 512 + j * 4096]);                \
        }                                                                     \
    }

#define DSREAD128(BUF)                                                        \
    {                                                                         \
        const char* Ab = (const char*)&lds[BUF][0][0];                        \
        const char* Bb = (const char*)&lds[BUF][1 + (wn >> 1)][0];            \
        _Pragma("unroll")                                                     \
        for (int m4 = 0; m4 < 4; ++m4)                                        \
            _Pragma("unroll")                                                 \
            for (int kk = 0; kk < 2; ++kk)                                    \
                a_[m4][kk] = *(const bf16x8*)(Ab +                            \
                    (wm * 64 + m4 * 16 + lr) * 128 +                          \
                    ((kk * 64 + lg * 16) ^ xsw));                             \
        _Pragma("unroll")                                                     \
        for (int n2 = 0; n2 < 4; ++n2)                                        \
            _Pragma("unroll")                                                 \
            for (int kk = 0; kk < 2; ++kk)                                    \
                b_[n2][kk] = *(const bf16x8*)(Bb +                            \
                    ((wn & 1) * 64 + n2 * 16 + lr) * 128 +                    \
                    ((kk * 64 + lg * 16) ^ xsw));                             \
    }

#define MFMA128                                                               \
    __builtin_amdgcn_s_setprio(1);                                            \
    _Pragma("unroll")                                                         \
    for (int m4 = 0; m4 < 4; ++m4)                                            \
        _Pragma("unroll")                                                     \
        for (int n2 = 0; n2 < 4; ++n2)                                        \
            _Pragma("unroll")                                                 \
            for (int kk = 0; kk < 2; ++kk)                                    \
                acc[m4][n2] = __builtin_amdgcn_mfma_f32_16x16x32_bf16(        \
                    a_[m4][kk], b_[n2][kk], acc[m4][n2], 0, 0, 0);            \
    __builtin_amdgcn_s_setprio(0);

template <int EPI>
__global__ __launch_bounds__(512, 2)
void gemm128d(const unsigned short* __restrict__ A,
              const unsigned short* __restrict__ BT,
              unsigned short* __restrict__ outB,
              float* __restrict__ outP,
              int M, int N, int K)
{
    __shared__ alignas(16) unsigned short lds[3][3][8192];   // 144 KiB
    const int tid  = threadIdx.x;
    const int lane = tid & 63;
    const int wave = tid >> 6;
    const int wm = wave >> 2;
    const int wn = wave & 3;
    const int lr = lane & 15;
    const int lg = lane >> 4;
    const int gy  = gridDim.y;
    const int lin = blockIdx.y * gridDim.x + blockIdx.x;
    const int cpx = (gridDim.x * gy) >> 3;   // grid (x*y) % 8 == 0 required
    const int swz = (lin & 7) * cpx + (lin >> 3);
    const int bm = (swz % gy) * 128;
    const int bn = (swz / gy) * 256;
    const int xsw  = (lr & 7) << 4;
    const int srow = tid >> 3;
    const int lc   = ((tid & 7) ^ (srow & 7)) * 8;
    int koff, NT;
    if constexpr (EPI == 1) { const int Kh = K >> 1; koff = blockIdx.z * Kh; NT = Kh >> 6; }
    else                    { koff = 0;              NT = K >> 6; }

    f32x4 acc[4][4] = {};
    bf16x8 a_[4][2], b_[4][2];

    // prologue: stage T0,T1; wait T0; read T0 fragments
    STAGE128D(0, 0);
    STAGE128D(1, 1);
    WAITV(6); SBAR();
    DSREAD128(0);

    int bc = 0;
    for (int kt = 0; kt < NT - 2; ++kt) {
        const int nb = (bc == 0) ? 2 : bc - 1;     // (bc+2)%3
        STAGE128D(kt + 2, nb);
        MFMA128;                                   // tile kt (regs)
        WAITV(6); SBAR();                          // T(kt+1) landed everywhere
        const int rb = (bc == 2) ? 0 : bc + 1;     // (bc+1)%3
        DSREAD128(rb);                             // frags tile kt+1
        bc = rb;
    }
    // kt = NT-2
    MFMA128;
    WAITV(0); SBAR();                              // T(NT-1) landed
    {
        const int rb = (bc == 2) ? 0 : bc + 1;
        DSREAD128(rb);
    }
    // kt = NT-1
    MFMA128;

#pragma unroll
    for (int m4 = 0; m4 < 4; ++m4) {
        const int row = bm + wm * 64 + m4 * 16 + lg * 4;
#pragma unroll
        for (int n2 = 0; n2 < 4; ++n2) {
            const int col = bn + wn * 64 + n2 * 16 + lr;
#pragma unroll
            for (int r = 0; r < 4; ++r) {
                if constexpr (EPI == 0) {
                    outB[(size_t)(row + r) * N + col] = f2bf(acc[m4][n2][r]);
                } else if constexpr (EPI == 1) {
                    outP[(size_t)blockIdx.z * M * N + (size_t)(row + r) * N + col] = acc[m4][n2][r];
                } else {
                    const float v  = acc[m4][n2][r];
                    const float vo = __shfl_xor(v, 1);
                    const float x1 = (lr & 1) ? vo : v;
                    const float x3 = (lr & 1) ? v : vo;
                    const float g  = x1 / (1.0f + __expf(-x1)) * x3;
                    if (!(lr & 1))
                        outB[(size_t)(row + r) * (N >> 1) + (col >> 1)] = f2bf(g);
                }
            }
        }
    }
}

// out = res + p[0] + p[1]   (all fp32, n4 float4 elements)
__global__ __launch_bounds__(256)
void reduce2_add(const float* res, const float* p, float* out, int n4)
{
    const float4* r4 = (const float4*)res;
    const float4* a4 = (const float4*)p;
    const float4* b4 = (const float4*)(p + (size_t)2048 * 2048);
    float4* o4 = (float4*)out;
    for (int i = blockIdx.x * 256 + threadIdx.x; i < n4; i += gridDim.x * 256) {
        const float4 r = r4[i], a = a4[i], b = b4[i];
        o4[i] = make_float4(r.x + a.x + b.x, r.y + a.y + b.y,
                            r.z + a.z + b.z, r.w + a.w + b.w);
    }
}

// h = res + p[0] + p[1]; hout = h; nout = rmsnorm(h)*w  — one block per row.
__global__ __launch_bounds__(256)
void reduce2_norm(const float* __restrict__ res, const float* __restrict__ p,
                  const float* __restrict__ w, float* __restrict__ hout,
                  unsigned short* __restrict__ nout)
{
    const int row = blockIdx.x, tid = threadIdx.x;
    const float4* r4 = (const float4*)(res + (size_t)row * 2048);
    const float4* a4 = (const float4*)(p   + (size_t)row * 2048);
    const float4* b4 = (const float4*)(p + (size_t)2048 * 2048 + (size_t)row * 2048);
    float4* h4 = (float4*)(hout + (size_t)row * 2048);
    float4 h[2];
    float ss = 0.f;
#pragma unroll
    for (int i = 0; i < 2; ++i) {
        const int idx = i * 256 + tid;
        const float4 r = r4[idx], a = a4[idx], b = b4[idx];
        float4 v = make_float4(r.x + a.x + b.x, r.y + a.y + b.y,
                               r.z + a.z + b.z, r.w + a.w + b.w);
        h[i] = v; h4[idx] = v;
        ss += v.x * v.x + v.y * v.y + v.z * v.z + v.w * v.w;
    }
#pragma unroll
    for (int off = 32; off; off >>= 1) ss += __shfl_xor(ss, off);
    __shared__ float red[4];
    if ((tid & 63) == 0) red[tid >> 6] = ss;
    __syncthreads();
    const float tot = red[0] + red[1] + red[2] + red[3];
    const float sc = rsqrtf(tot * (1.0f / 2048.0f) + 1e-5f);
#pragma unroll
    for (int i = 0; i < 2; ++i) {
        const int idx = i * 256 + tid;
        const float4 wv = ((const float4*)w)[idx];
        u16x4 o;
        o[0] = f2bf(h[i].x * sc * wv.x); o[1] = f2bf(h[i].y * sc * wv.y);
        o[2] = f2bf(h[i].z * sc * wv.z); o[3] = f2bf(h[i].w * sc * wv.w);
        *(u16x4*)(nout + (size_t)row * 2048 + idx * 4) = o;
    }
}

// ---------------------------------------------------------------------------
// RMSNorm: fp32 in [2048][2048] -> bf16 out, weight fp32. One block per row.
// ---------------------------------------------------------------------------
__global__ __launch_bounds__(256)
void rmsnorm_kernel(const float* __restrict__ x, const float* __restrict__ w,
                    unsigned short* __restrict__ out)
{
    const int row = blockIdx.x;
    const int tid = threadIdx.x;
    const float* xr = x + (size_t)row * 2048;
    const float4 a = *reinterpret_cast<const float4*>(xr + tid * 8);
    const float4 b = *reinterpret_cast<const float4*>(xr + tid * 8 + 4);
    float ss = a.x * a.x + a.y * a.y + a.z * a.z + a.w * a.w
             + b.x * b.x + b.y * b.y + b.z * b.z + b.w * b.w;
#pragma unroll
    for (int off = 32; off; off >>= 1) ss += __shfl_xor(ss, off);
    __shared__ float red[4];
    if ((tid & 63) == 0) red[tid >> 6] = ss;
    __syncthreads();
    const float tot = red[0] + red[1] + red[2] + red[3];
    const float sc = rsqrtf(tot * (1.0f / 2048.0f) + 1e-5f);
    const float4 wa = *reinterpret_cast<const float4*>(w + tid * 8);
    const float4 wb = *reinterpret_cast<const float4*>(w + tid * 8 + 4);
    u16x8 o;
    o[0] = f2bf(a.x * sc * wa.x); o[1] = f2bf(a.y * sc * wa.y);
    o[2] = f2bf(a.z * sc * wa.z); o[3] = f2bf(a.w * sc * wa.w);
    o[4] = f2bf(b.x * sc * wb.x); o[5] = f2bf(b.y * sc * wb.y);
    o[6] = f2bf(b.z * sc * wb.z); o[7] = f2bf(b.w * sc * wb.w);
    *reinterpret_cast<u16x8*>(out + (size_t)row * 2048 + tid * 8) = o;
}

// ---------------------------------------------------------------------------
// RoPE in-place on bf16 qkv[2048][6144], first 4096 cols (q and k regions).
// ---------------------------------------------------------------------------
__global__ __launch_bounds__(256)
void rope_kernel(unsigned short* __restrict__ t, const float* __restrict__ cs,
                 const float* __restrict__ sn)
{
    const int idx = blockIdx.x * 256 + threadIdx.x;   // S * 4096 / 8
    const int s   = idx >> 9;
    const int col = (idx & 511) * 8;
    const int i0  = (col & 127) >> 1;
    u16x8 v = *reinterpret_cast<const u16x8*>(t + (size_t)s * 6144 + col);
    const float4 c  = *reinterpret_cast<const float4*>(cs + s * 64 + i0);
    const float4 sv = *reinterpret_cast<const float4*>(sn + s * 64 + i0);
    const float cc[4] = {c.x, c.y, c.z, c.w};
    const float ns[4] = {sv.x, sv.y, sv.z, sv.w};
#pragma unroll
    for (int p = 0; p < 4; ++p) {
        const float re = bf2f(v[2 * p]), im = bf2f(v[2 * p + 1]);
        v[2 * p]     = f2bf(re * cc[p] - im * ns[p]);
        v[2 * p + 1] = f2bf(re * ns[p] + im * cc[p]);
    }
    *reinterpret_cast<u16x8*>(t + (size_t)s * 6144 + col) = v;
}

// ---------------------------------------------------------------------------
// bf16 transpose: out[N][M] = in[M][N]^T (row stride ldin), 64x64 tiles
// ---------------------------------------------------------------------------
__global__ __launch_bounds__(256)
void transpose_bf16(const unsigned short* __restrict__ in,
                    unsigned short* __restrict__ out, int M, int N, int ldin)
{
    __shared__ unsigned short t[64][66];
    const int bm = blockIdx.y * 64, bn = blockIdx.x * 64;
    const int tid = threadIdx.x;
    const int r = tid >> 3, c8 = (tid & 7) * 8;
#pragma unroll
    for (int i = 0; i < 2; ++i) {
        const int row = r + i * 32;
        u16x8 v = *reinterpret_cast<const u16x8*>(in + (size_t)(bm + row) * ldin + bn + c8);
#pragma unroll
        for (int e = 0; e < 8; ++e) t[row][c8 + e] = v[e];
    }
    __syncthreads();
#pragma unroll
    for (int i = 0; i < 2; ++i) {
        const int orow = r + i * 32;
        u16x8 v;
#pragma unroll
        for (int e = 0; e < 8; ++e) v[e] = t[c8 + e][orow];
        *reinterpret_cast<u16x8*>(out + (size_t)(bn + orow) * M + bm + c8) = v;
    }
}

// ---------------------------------------------------------------------------
// Weight convert + transpose: w[K][N] fp32 -> wT[rmul*n+radd][K] bf16.
// rmul=2/radd=0|1 builds the interleaved w13T (row 2j = w1_j, 2j+1 = w3_j).
// ---------------------------------------------------------------------------
__global__ __launch_bounds__(256)
void convT_kernel(const float* __restrict__ w, unsigned short* __restrict__ wT,
                  int K, int N, int rmul, int radd)
{
    __shared__ unsigned short t[64][66];
    const int bk = blockIdx.y * 64, bn = blockIdx.x * 64;
    const int tid = threadIdx.x;
    const int r = tid >> 4, c4 = (tid & 15) * 4;
#pragma unroll
    for (int i = 0; i < 4; ++i) {
        const int row = r + i * 16;
        const float4 v = *reinterpret_cast<const float4*>(w + (size_t)(bk + row) * N + bn + c4);
        t[row][c4 + 0] = f2bf(v.x); t[row][c4 + 1] = f2bf(v.y);
        t[row][c4 + 2] = f2bf(v.z); t[row][c4 + 3] = f2bf(v.w);
    }
    __syncthreads();
#pragma unroll
    for (int i = 0; i < 4; ++i) {
        const int n = r + i * 16;
        u16x4 o;
#pragma unroll
        for (int e = 0; e < 4; ++e) o[e] = t[c4 + e][n];
        *reinterpret_cast<u16x4*>(wT + (size_t)(rmul * (bn + n) + radd) * K + bk + c4) = o;
    }
}

// ---------------------------------------------------------------------------
// Causal flash attention, paired q-tiles for balance.
// ---------------------------------------------------------------------------
__global__ __launch_bounds__(512)
void flash_attn(const unsigned short* __restrict__ q,
                const unsigned short* __restrict__ k,
                const unsigned short* __restrict__ vT,
                unsigned short* __restrict__ attn)
{
    __shared__ alignas(16) unsigned short Ks[2][64][136];  // [buf][kv][hd]
    __shared__ alignas(16) unsigned short Vs[2][128][72];  // [buf][hd][kv]
    __shared__ alignas(16) unsigned short Ps[8][16][72];   // per-wave P

    const int hh = blockIdx.y;
    const int pi = blockIdx.x;              // 0..15
    const int tid = threadIdx.x;
    const int lane = tid & 63, wave = tid >> 6;
    const int qt = (wave >> 2) ? (31 - pi) : pi;
    const int lr = lane & 15, lg = lane >> 4;
    const int q0 = qt * 64 + (wave & 3) * 16;
    const int myNT = qt + 1;
    const int NT   = 32 - pi;

    const int kr0 = tid >> 4, kc0 = (tid & 15) * 8;
    const int vr0 = tid >> 3, vc0 = (tid & 7) * 8;

    bf16x8 qf[4];
#pragma unroll
    for (int c = 0; c < 4; ++c)
        qf[c] = *reinterpret_cast<const bf16x8*>(
            q + (size_t)(q0 + lr) * 6144 + hh * 128 + c * 32 + lg * 8);

    f32x4 oacc[8] = {};
    float m_r[4], l_r[4];
#pragma unroll
    for (int r = 0; r < 4; ++r) { m_r[r] = -INFINITY; l_r[r] = 0.0f; }
    const float scale = 0.08838834764831845f;   // 1/sqrt(128)

    u16x8 kreg0, kreg1, vreg0, vreg1;
    auto gload = [&](int kt) {
        const int kv0 = kt * 64;
        kreg0 = *reinterpret_cast<const u16x8*>(k + (size_t)(kv0 + kr0) * 6144 + hh * 128 + kc0);
        kreg1 = *reinterpret_cast<const u16x8*>(k + (size_t)(kv0 + kr0 + 32) * 6144 + hh * 128 + kc0);
        vreg0 = *reinterpret_cast<const u16x8*>(vT + (size_t)(hh * 128 + vr0) * 2048 + kv0 + vc0);
        vreg1 = *reinterpret_cast<const u16x8*>(vT + (size_t)(hh * 128 + vr0 + 64) * 2048 + kv0 + vc0);
    };
    auto lwrite = [&](int buf) {
        *reinterpret_cast<u16x8*>(&Ks[buf][kr0][kc0])      = kreg0;
        *reinterpret_cast<u16x8*>(&Ks[buf][kr0 + 32][kc0]) = kreg1;
        *reinterpret_cast<u16x8*>(&Vs[buf][vr0][vc0])      = vreg0;
        *reinterpret_cast<u16x8*>(&Vs[buf][vr0 + 64][vc0]) = vreg1;
    };

    gload(0); lwrite(0);
    __syncthreads();

    for (int kt = 0; kt < NT; ++kt) {
        const int buf = kt & 1;
        if (kt + 1 < NT) gload(kt + 1);

        if (kt < myNT) {
            const int kv0 = kt * 64;
            const bool masked = (kt == myNT - 1);
            f32x4 s[4] = {};
            __builtin_amdgcn_s_setprio(1);
#pragma unroll
            for (int ct = 0; ct < 4; ++ct)
#pragma unroll
                for (int c = 0; c < 4; ++c) {
                    const bf16x8 kf = *reinterpret_cast<const bf16x8*>(
                        &Ks[buf][ct * 16 + lr][c * 32 + lg * 8]);
                    s[ct] = __builtin_amdgcn_mfma_f32_16x16x32_bf16(qf[c], kf, s[ct], 0, 0, 0);
                }
            __builtin_amdgcn_s_setprio(0);
#pragma unroll
            for (int ct = 0; ct < 4; ++ct)
#pragma unroll
                for (int r = 0; r < 4; ++r) {
                    float v = s[ct][r] * scale;
                    if (masked) {
                        const int kvg = kv0 + ct * 16 + lr;
                        const int qg  = q0 + lg * 4 + r;
                        if (kvg > qg) v = -INFINITY;
                    }
                    s[ct][r] = v;
                }
            float mn[4], alpha[4], rs[4];
#pragma unroll
            for (int r = 0; r < 4; ++r) {
                float v = fmaxf(fmaxf(s[0][r], s[1][r]), fmaxf(s[2][r], s[3][r]));
                v = fmaxf(v, __shfl_xor(v, 1));
                v = fmaxf(v, __shfl_xor(v, 2));
                v = fmaxf(v, __shfl_xor(v, 4));
                v = fmaxf(v, __shfl_xor(v, 8));
                mn[r] = fmaxf(m_r[r], v);
                alpha[r] = __expf(m_r[r] - mn[r]);
                m_r[r] = mn[r];
                rs[r] = 0.0f;
            }
#pragma unroll
            for (int ct = 0; ct < 4; ++ct)
#pragma unroll
                for (int r = 0; r < 4; ++r) {
                    const float p = __expf(s[ct][r] - mn[r]);
                    s[ct][r] = p;
                    rs[r] += p;
                }
#pragma unroll
            for (int r = 0; r < 4; ++r) {
                float t2 = rs[r];
                t2 += __shfl_xor(t2, 1);
                t2 += __shfl_xor(t2, 2);
                t2 += __shfl_xor(t2, 4);
                t2 += __shfl_xor(t2, 8);
                l_r[r] = l_r[r] * alpha[r] + t2;
            }
#pragma unroll
            for (int ot = 0; ot < 8; ++ot)
#pragma unroll
                for (int r = 0; r < 4; ++r) oacc[ot][r] *= alpha[r];

#pragma unroll
            for (int ct = 0; ct < 4; ++ct)
#pragma unroll
                for (int r = 0; r < 4; ++r)
                    Ps[wave][lg * 4 + r][ct * 16 + lr] = f2bf(s[ct][r]);

            __builtin_amdgcn_s_setprio(1);
#pragma unroll
            for (int c2 = 0; c2 < 2; ++c2) {
                const bf16x8 pf = *reinterpret_cast<const bf16x8*>(
                    &Ps[wave][lr][c2 * 32 + lg * 8]);
#pragma unroll
                for (int ot = 0; ot < 8; ++ot) {
                    const bf16x8 vf = *reinterpret_cast<const bf16x8*>(
                        &Vs[buf][ot * 16 + lr][c2 * 32 + lg * 8]);
                    oacc[ot] = __builtin_amdgcn_mfma_f32_16x16x32_bf16(pf, vf, oacc[ot], 0, 0, 0);
                }
            }
            __builtin_amdgcn_s_setprio(0);
        }

        if (kt + 1 < NT) lwrite(buf ^ 1);
        __syncthreads();
    }

#pragma unroll
    for (int ot = 0; ot < 8; ++ot)
#pragma unroll
        for (int r = 0; r < 4; ++r) {
            const float v = oacc[ot][r] / l_r[r];
            attn[(size_t)(q0 + lg * 4 + r) * 2048 + hh * 128 + ot * 16 + lr] = f2bf(v);
        }
}

// ---------------------------------------------------------------------------
extern "C" void kernel_launch(void* const* d_in, const int* in_sizes, int n_in,
                              void* d_out, int out_size, void* d_ws, size_t ws_size,
                              hipStream_t stream)
{
    const float* x    = (const float*)d_in[0];
    const float* fcos = (const float*)d_in[1];
    const float* fsin = (const float*)d_in[2];
    // d_in[3] = mask (causal, hardcoded)
    const float* wq  = (const float*)d_in[4];
    const float* wk  = (const float*)d_in[5];
    const float* wv  = (const float*)d_in[6];
    const float* wo  = (const float*)d_in[7];
    const float* w1  = (const float*)d_in[8];
    const float* w2  = (const float*)d_in[9];
    const float* w3  = (const float*)d_in[10];
    const float* anw = (const float*)d_in[11];
    const float* fnw = (const float*)d_in[12];
    float* out = (float*)d_out;

    char* ws = (char*)d_ws;
    size_t off = 0;
    auto alloc = [&](size_t bytes) { void* p = ws + off; off += bytes; return p; };
    const size_t SZ_DD = (size_t)2048 * 2048 * 2;   // 8 MiB
    const size_t SZ_DF = (size_t)2048 * 5632 * 2;   // 22 MiB

    unsigned short* wqT  = (unsigned short*)alloc(SZ_DD);
    unsigned short* wkT  = (unsigned short*)alloc(SZ_DD);
    unsigned short* wvT  = (unsigned short*)alloc(SZ_DD);
    unsigned short* woT  = (unsigned short*)alloc(SZ_DD);
    unsigned short* w13T = (unsigned short*)alloc(2 * SZ_DF);  // interleaved [11264][2048]
    unsigned short* w2T  = (unsigned short*)alloc(SZ_DF);

    // region1 (48 MiB), attn phase: xn[0:8) | qkv[8:32) | vTb[32:40) | ab[40:48)
    // pk (32 MiB fp32 split-K partials) overlays [0:32) when those are dead;
    // hn overlays vTb's region [32:40) (vTb dead after flash).
    char* reg1 = (char*)alloc((size_t)48 * 1024 * 1024);
    unsigned short* xn   = (unsigned short*)reg1;
    unsigned short* qkv  = (unsigned short*)(reg1 + SZ_DD);            // [2048][6144]
    unsigned short* vTb  = (unsigned short*)(reg1 + SZ_DD + 3 * SZ_DD);
    unsigned short* ab   = (unsigned short*)(reg1 + SZ_DD + 4 * SZ_DD);
    float*          pk   = (float*)reg1;                               // [2][2048][2048] f32
    unsigned short* hn   = (unsigned short*)(reg1 + 4 * SZ_DD);        // [2048][2048]

    char* reg2 = (char*)alloc(SZ_DF);
    unsigned short* t1 = (unsigned short*)reg2;                        // [2048][5632]

    const int N4 = 2048 * 2048 / 4;

    // weight fp32 -> bf16 transposed (w1/w3 interleaved into w13T)
    convT_kernel<<<dim3(32, 32), 256, 0, stream>>>(wq, wqT, 2048, 2048, 1, 0);
    convT_kernel<<<dim3(32, 32), 256, 0, stream>>>(wk, wkT, 2048, 2048, 1, 0);
    convT_kernel<<<dim3(32, 32), 256, 0, stream>>>(wv, wvT, 2048, 2048, 1, 0);
    convT_kernel<<<dim3(32, 32), 256, 0, stream>>>(wo, woT, 2048, 2048, 1, 0);
    convT_kernel<<<dim3(88, 32), 256, 0, stream>>>(w1, w13T, 2048, 5632, 2, 0);
    convT_kernel<<<dim3(88, 32), 256, 0, stream>>>(w3, w13T, 2048, 5632, 2, 1);
    convT_kernel<<<dim3(32, 88), 256, 0, stream>>>(w2, w2T, 5632, 2048, 1, 0);

    // attention block
    rmsnorm_kernel<<<2048, 256, 0, stream>>>(x, anw, xn);
    // QKV: [2048][6144] = xn @ qkvT^T  (384 blocks)
    gemm128d<0><<<dim3(24, 16), 512, 0, stream>>>(xn, wqT, qkv, nullptr, 2048, 6144, 2048);
    rope_kernel<<<4096, 256, 0, stream>>>(qkv, fcos, fsin);
    transpose_bf16<<<dim3(32, 32), 256, 0, stream>>>(qkv + 4096, vTb, 2048, 2048, 6144);
    flash_attn<<<dim3(16, 16), 512, 0, stream>>>(qkv, qkv + 2048, vTb, ab);
    // Wo split-K=2: 256 blocks = 100% CU fill
    gemm128d<1><<<dim3(8, 16, 2), 512, 0, stream>>>(ab, woT, nullptr, pk, 2048, 2048, 2048);
    // fused: out = x + Wo-partials; hn = rmsnorm(out) * fnw
    reduce2_norm<<<2048, 256, 0, stream>>>(x, pk, fnw, out, hn);

    // FFN block
    // W13 + fused SwiGLU epilogue: t1 = silu(hn@w1) * (hn@w3), 704 blocks
    gemm128d<2><<<dim3(44, 16), 512, 0, stream>>>(hn, w13T, t1, nullptr, 2048, 11264, 2048);
    // W2 split-K=2: 256 blocks
    gemm128d<1><<<dim3(8, 16, 2), 512, 0, stream>>>(t1, w2T, nullptr, pk, 2048, 2048, 5632);
    reduce2_add<<<2048, 256, 0, stream>>>(out, pk, out, N4);
}